// Round 1
// baseline (1286.357 us; speedup 1.0000x reference)
//
#include <hip/hip_runtime.h>

#define N_NODESC 50000
#define N_EDGESC 640000
#define N_GRAPHSC 64
#define HIDC 128
#define LN_EPSF 1e-5f

// ---------- helpers ----------
static __device__ __forceinline__ unsigned ord_enc(float f) {
  unsigned u = __float_as_uint(f);
  return (u & 0x80000000u) ? ~u : (u | 0x80000000u);
}
static __device__ __forceinline__ float ord_dec(unsigned u) {
  return __uint_as_float((u & 0x80000000u) ? (u ^ 0x80000000u) : ~u);
}
static __device__ __forceinline__ void f4add(float4& a, const float4 b) {
  a.x += b.x; a.y += b.y; a.z += b.z; a.w += b.w;
}

// small 3->16 relu LN 16->16 MLP (encoder preprocessing), one thread per node
static __device__ __forceinline__ void mlp16(float in0, float in1, float in2,
    const float* __restrict__ W1, const float* __restrict__ b1,
    const float* __restrict__ g, const float* __restrict__ be,
    const float* __restrict__ W2, const float* __restrict__ b2,
    float* __restrict__ out) {
  float h[16];
  float s1 = 0.f, s2 = 0.f;
#pragma unroll
  for (int j = 0; j < 16; ++j) {
    float v = b1[j] + W1[j*3+0]*in0 + W1[j*3+1]*in1 + W1[j*3+2]*in2;
    v = fmaxf(v, 0.f);
    h[j] = v; s1 += v; s2 += v*v;
  }
  float mu = s1 * (1.f/16.f);
  float var = fmaxf(s2 * (1.f/16.f) - mu*mu, 0.f);
  float rs = rsqrtf(var + LN_EPSF);
  float z[16];
#pragma unroll
  for (int j = 0; j < 16; ++j) z[j] = (h[j]-mu)*rs*g[j] + be[j];
#pragma unroll
  for (int j = 0; j < 16; ++j) {
    float v = b2[j];
#pragma unroll
    for (int k = 0; k < 16; ++k) v += W2[j*16+k]*z[k];
    out[j] = v;
  }
}

// ---------- CSR build ----------
__global__ __launch_bounds__(256) void hist_kernel(const int* __restrict__ ei, int* __restrict__ deg) {
  int e = blockIdx.x * 256 + threadIdx.x;
  if (e < N_EDGESC) atomicAdd(&deg[ei[N_EDGESC + e]], 1);
}

__global__ __launch_bounds__(1024) void scan_kernel(const int* __restrict__ deg,
                                                    int* __restrict__ rowptr,
                                                    int* __restrict__ cursor) {
  __shared__ int ps[1024];
  const int t = threadIdx.x;
  const int CH = 49;  // ceil(50000/1024)
  int start = t * CH;
  int end = start + CH; if (end > N_NODESC) end = N_NODESC;
  int s = 0;
  for (int i = start; i < end; ++i) s += deg[i];
  ps[t] = s;
  __syncthreads();
  for (int off = 1; off < 1024; off <<= 1) {
    int v = (t >= off) ? ps[t - off] : 0;
    __syncthreads();
    ps[t] += v;
    __syncthreads();
  }
  int run = ps[t] - s;  // exclusive prefix
  for (int i = start; i < end; ++i) {
    rowptr[i] = run; cursor[i] = run;
    run += deg[i];
  }
  if (t == 1023) rowptr[N_NODESC] = run;
}

__global__ __launch_bounds__(256) void scatter_kernel(const int* __restrict__ ei,
                                                      int* __restrict__ cursor,
                                                      int* __restrict__ esrc) {
  int e = blockIdx.x * 256 + threadIdx.x;
  if (e < N_EDGESC) {
    int d = ei[N_EDGESC + e];
    int slot = atomicAdd(&cursor[d], 1);
    esrc[slot] = ei[e];
  }
}

// ---------- encoder: small MLPs + 45->128 projection ----------
__global__ __launch_bounds__(128) void enc_kernel(
    const float* __restrict__ x,
    const float* __restrict__ aW1, const float* __restrict__ ab1,
    const float* __restrict__ ag,  const float* __restrict__ abe,
    const float* __restrict__ aW2, const float* __restrict__ ab2,
    const float* __restrict__ oW1, const float* __restrict__ ob1,
    const float* __restrict__ og,  const float* __restrict__ obe,
    const float* __restrict__ oW2, const float* __restrict__ ob2,
    const float* __restrict__ ninW, const float* __restrict__ ninb,
    float* __restrict__ H) {
  __shared__ float sa[48*68];   // [k][n], n<64 pad 68
  __shared__ float sw[48*132];  // [k][f], f<128 pad 132
  const int t = threadIdx.x;
  const int lane = t & 63, w = t >> 6;
  const int nb = blockIdx.x * 64;

  if (t < 64) {
    float in45[45];
    const int gn = nb + t;
    if (gn < N_NODESC) {
      const float* xr = x + gn * 19;
#pragma unroll
      for (int k = 0; k < 9; ++k) in45[k] = xr[k];
#pragma unroll
      for (int k = 0; k < 4; ++k) in45[9+k] = xr[15+k];
      mlp16(xr[9], xr[10], xr[11], aW1, ab1, ag, abe, aW2, ab2, &in45[13]);
      mlp16(xr[12], xr[13], xr[14], oW1, ob1, og, obe, oW2, ob2, &in45[29]);
    } else {
#pragma unroll
      for (int k = 0; k < 45; ++k) in45[k] = 0.f;
    }
#pragma unroll
    for (int k = 0; k < 45; ++k) sa[k*68 + t] = in45[k];
#pragma unroll
    for (int k = 45; k < 48; ++k) sa[k*68 + t] = 0.f;
  }
  for (int idx = t; idx < 48*128; idx += 128) {
    int k = idx >> 7, f = idx & 127;
    sw[k*132 + f] = (k < 45) ? ninW[f*45 + k] : 0.f;
  }
  __syncthreads();

  const int n0 = (lane & 7) * 8;
  const int f0 = ((lane >> 3) << 3) + w * 64;
  float acc[8][8];
#pragma unroll
  for (int i = 0; i < 8; ++i)
#pragma unroll
    for (int j = 0; j < 8; ++j) acc[i][j] = 0.f;

#pragma unroll 4
  for (int k = 0; k < 48; ++k) {
    float av[8], wv[8];
    float4 a0 = *(const float4*)&sa[k*68 + n0];
    float4 a1 = *(const float4*)&sa[k*68 + n0 + 4];
    float4 w0 = *(const float4*)&sw[k*132 + f0];
    float4 w1 = *(const float4*)&sw[k*132 + f0 + 4];
    av[0]=a0.x; av[1]=a0.y; av[2]=a0.z; av[3]=a0.w;
    av[4]=a1.x; av[5]=a1.y; av[6]=a1.z; av[7]=a1.w;
    wv[0]=w0.x; wv[1]=w0.y; wv[2]=w0.z; wv[3]=w0.w;
    wv[4]=w1.x; wv[5]=w1.y; wv[6]=w1.z; wv[7]=w1.w;
#pragma unroll
    for (int i = 0; i < 8; ++i)
#pragma unroll
      for (int j = 0; j < 8; ++j) acc[i][j] += av[i]*wv[j];
  }
  float bb[8];
#pragma unroll
  for (int j = 0; j < 8; ++j) bb[j] = ninb[f0+j];
#pragma unroll
  for (int i = 0; i < 8; ++i) {
    int gn = nb + n0 + i;
    if (gn < N_NODESC) {
      float o[8];
#pragma unroll
      for (int j = 0; j < 8; ++j) o[j] = acc[i][j] + bb[j];
      *(float4*)&H[gn*HIDC + f0]     = make_float4(o[0],o[1],o[2],o[3]);
      *(float4*)&H[gn*HIDC + f0 + 4] = make_float4(o[4],o[5],o[6],o[7]);
    }
  }
}

// ---------- aggregation: M = (1+eps)*H + sum_{src in bucket(dst)} H[src] ----------
__global__ __launch_bounds__(128) void agg_kernel(const float* __restrict__ H,
    const int* __restrict__ rowptr, const int* __restrict__ esrc,
    const float* __restrict__ epsp, float* __restrict__ M) {
  const int t = threadIdx.x;
  const int c = t & 31;    // float4 column (128 floats = 32 float4)
  const int v = t >> 5;    // node sub-index 0..3
  const int node = blockIdx.x * 4 + v;
  if (node >= N_NODESC) return;
  const float4* H4 = (const float4*)H;
  float4 h = H4[node*32 + c];
  const float e1 = 1.0f + epsp[0];
  float4 a0 = make_float4(0,0,0,0), a1 = a0, a2 = a0, a3 = a0;
  int s = rowptr[node];
  const int e = rowptr[node+1];
  for (; s + 4 <= e; s += 4) {
    int i0 = esrc[s], i1 = esrc[s+1], i2 = esrc[s+2], i3 = esrc[s+3];
    float4 x0 = H4[i0*32+c], x1 = H4[i1*32+c], x2 = H4[i2*32+c], x3 = H4[i3*32+c];
    f4add(a0,x0); f4add(a1,x1); f4add(a2,x2); f4add(a3,x3);
  }
  for (; s < e; ++s) f4add(a0, H4[esrc[s]*32+c]);
  float4 m;
  m.x = e1*h.x + a0.x+a1.x+a2.x+a3.x;
  m.y = e1*h.y + a0.y+a1.y+a2.y+a3.y;
  m.z = e1*h.z + a0.z+a1.z+a2.z+a3.z;
  m.w = e1*h.w + a0.w+a1.w+a2.w+a3.w;
  ((float4*)M)[node*32 + c] = m;
}

// ---------- fp32 GEMM 128x128 + bias + relu + LN (+optional residual) ----------
__global__ __launch_bounds__(128) void gemm128_kernel(
    const float* __restrict__ IN, const float* __restrict__ W,
    const float* __restrict__ bias, const float* __restrict__ lng,
    const float* __restrict__ lnb, const float* __restrict__ resid,
    float* __restrict__ OUT) {
  __shared__ float sa[32*68];
  __shared__ float sw[32*132];
  __shared__ float red1[64][16];
  __shared__ float red2[64][16];
  __shared__ float stat[64][2];
  const int t = threadIdx.x, lane = t & 63, w = t >> 6;
  const int nb = blockIdx.x * 64;
  const int n0 = (lane & 7) * 8;
  const int f0 = ((lane >> 3) << 3) + w * 64;
  float acc[8][8];
#pragma unroll
  for (int i = 0; i < 8; ++i)
#pragma unroll
    for (int j = 0; j < 8; ++j) acc[i][j] = 0.f;

  for (int kc = 0; kc < 4; ++kc) {
    const int k0 = kc * 32;
#pragma unroll
    for (int i = 0; i < 4; ++i) {
      int q = t + i*128;
      int n = q >> 3, kk = (q & 7) * 4;
      int gn = nb + n;
      float4 v = make_float4(0,0,0,0);
      if (gn < N_NODESC) v = *(const float4*)&IN[gn*HIDC + k0 + kk];
      sa[(kk+0)*68+n]=v.x; sa[(kk+1)*68+n]=v.y; sa[(kk+2)*68+n]=v.z; sa[(kk+3)*68+n]=v.w;
    }
#pragma unroll
    for (int i = 0; i < 8; ++i) {
      int q = t + i*128;
      int f = q >> 3, kk = (q & 7) * 4;
      float4 v = *(const float4*)&W[f*HIDC + k0 + kk];
      sw[(kk+0)*132+f]=v.x; sw[(kk+1)*132+f]=v.y; sw[(kk+2)*132+f]=v.z; sw[(kk+3)*132+f]=v.w;
    }
    __syncthreads();
#pragma unroll 4
    for (int k = 0; k < 32; ++k) {
      float av[8], wv[8];
      float4 a0 = *(const float4*)&sa[k*68 + n0];
      float4 a1 = *(const float4*)&sa[k*68 + n0 + 4];
      float4 w0 = *(const float4*)&sw[k*132 + f0];
      float4 w1 = *(const float4*)&sw[k*132 + f0 + 4];
      av[0]=a0.x; av[1]=a0.y; av[2]=a0.z; av[3]=a0.w;
      av[4]=a1.x; av[5]=a1.y; av[6]=a1.z; av[7]=a1.w;
      wv[0]=w0.x; wv[1]=w0.y; wv[2]=w0.z; wv[3]=w0.w;
      wv[4]=w1.x; wv[5]=w1.y; wv[6]=w1.z; wv[7]=w1.w;
#pragma unroll
      for (int i = 0; i < 8; ++i)
#pragma unroll
        for (int j = 0; j < 8; ++j) acc[i][j] += av[i]*wv[j];
    }
    __syncthreads();
  }

  float bb[8], gg[8], be[8];
#pragma unroll
  for (int j = 0; j < 8; ++j) { bb[j] = bias[f0+j]; gg[j] = lng[f0+j]; be[j] = lnb[f0+j]; }
#pragma unroll
  for (int i = 0; i < 8; ++i) {
    float s1 = 0.f, s2 = 0.f;
#pragma unroll
    for (int j = 0; j < 8; ++j) {
      float v = fmaxf(acc[i][j] + bb[j], 0.f);
      acc[i][j] = v; s1 += v; s2 += v*v;
    }
    red1[n0+i][(lane>>3) + 8*w] = s1;
    red2[n0+i][(lane>>3) + 8*w] = s2;
  }
  __syncthreads();
  if (t < 64) {
    float s1 = 0.f, s2 = 0.f;
#pragma unroll
    for (int g = 0; g < 16; ++g) { s1 += red1[t][g]; s2 += red2[t][g]; }
    float mu = s1 * (1.f/128.f);
    float var = fmaxf(s2 * (1.f/128.f) - mu*mu, 0.f);
    stat[t][0] = mu; stat[t][1] = rsqrtf(var + LN_EPSF);
  }
  __syncthreads();
#pragma unroll
  for (int i = 0; i < 8; ++i) {
    int gn = nb + n0 + i;
    if (gn >= N_NODESC) continue;
    float mu = stat[n0+i][0], rs = stat[n0+i][1];
    float o[8];
#pragma unroll
    for (int j = 0; j < 8; ++j) o[j] = (acc[i][j]-mu)*rs*gg[j] + be[j];
    if (resid) {
      float4 r0 = *(const float4*)&resid[gn*HIDC + f0];
      float4 r1 = *(const float4*)&resid[gn*HIDC + f0 + 4];
      o[0]+=r0.x; o[1]+=r0.y; o[2]+=r0.z; o[3]+=r0.w;
      o[4]+=r1.x; o[5]+=r1.y; o[6]+=r1.z; o[7]+=r1.w;
    }
    *(float4*)&OUT[gn*HIDC + f0]     = make_float4(o[0],o[1],o[2],o[3]);
    *(float4*)&OUT[gn*HIDC + f0 + 4] = make_float4(o[4],o[5],o[6],o[7]);
  }
}

// ---------- gate: 128->64 + relu + LN + dot(W2) -> scalar, atomicMax per graph ----------
__global__ __launch_bounds__(128) void gate_kernel(
    const float* __restrict__ H, const float* __restrict__ W1,
    const float* __restrict__ b1, const float* __restrict__ lng,
    const float* __restrict__ lnb, const float* __restrict__ W2,
    const float* __restrict__ b2, const int* __restrict__ batch,
    float* __restrict__ gateb, unsigned* __restrict__ gmaxu) {
  __shared__ float sa[32*132];  // [k][n], n<128 pad 132
  __shared__ float sw[32*68];   // [k][f], f<64 pad 68
  __shared__ float red1[128][8];
  __shared__ float red2[128][8];
  __shared__ float stat[128][2];
  const int t = threadIdx.x, lane = t & 63, w = t >> 6;
  const int nb = blockIdx.x * 128;
  const int n0 = (lane & 7) * 8 + w * 64;
  const int f0 = (lane >> 3) * 8;
  float acc[8][8];
#pragma unroll
  for (int i = 0; i < 8; ++i)
#pragma unroll
    for (int j = 0; j < 8; ++j) acc[i][j] = 0.f;

  for (int kc = 0; kc < 4; ++kc) {
    const int k0 = kc * 32;
#pragma unroll
    for (int i = 0; i < 8; ++i) {
      int q = t + i*128;
      int n = q >> 3, kk = (q & 7) * 4;
      int gn = nb + n;
      float4 v = make_float4(0,0,0,0);
      if (gn < N_NODESC) v = *(const float4*)&H[gn*HIDC + k0 + kk];
      sa[(kk+0)*132+n]=v.x; sa[(kk+1)*132+n]=v.y; sa[(kk+2)*132+n]=v.z; sa[(kk+3)*132+n]=v.w;
    }
#pragma unroll
    for (int i = 0; i < 4; ++i) {
      int q = t + i*128;
      int f = q >> 3, kk = (q & 7) * 4;
      float4 v = *(const float4*)&W1[f*HIDC + k0 + kk];
      sw[(kk+0)*68+f]=v.x; sw[(kk+1)*68+f]=v.y; sw[(kk+2)*68+f]=v.z; sw[(kk+3)*68+f]=v.w;
    }
    __syncthreads();
#pragma unroll 4
    for (int k = 0; k < 32; ++k) {
      float av[8], wv[8];
      float4 a0 = *(const float4*)&sa[k*132 + n0];
      float4 a1 = *(const float4*)&sa[k*132 + n0 + 4];
      float4 w0 = *(const float4*)&sw[k*68 + f0];
      float4 w1 = *(const float4*)&sw[k*68 + f0 + 4];
      av[0]=a0.x; av[1]=a0.y; av[2]=a0.z; av[3]=a0.w;
      av[4]=a1.x; av[5]=a1.y; av[6]=a1.z; av[7]=a1.w;
      wv[0]=w0.x; wv[1]=w0.y; wv[2]=w0.z; wv[3]=w0.w;
      wv[4]=w1.x; wv[5]=w1.y; wv[6]=w1.z; wv[7]=w1.w;
#pragma unroll
      for (int i = 0; i < 8; ++i)
#pragma unroll
        for (int j = 0; j < 8; ++j) acc[i][j] += av[i]*wv[j];
    }
    __syncthreads();
  }

  float bb[8], gg[8], be[8], w2v[8];
#pragma unroll
  for (int j = 0; j < 8; ++j) { bb[j]=b1[f0+j]; gg[j]=lng[f0+j]; be[j]=lnb[f0+j]; w2v[j]=W2[f0+j]; }
#pragma unroll
  for (int i = 0; i < 8; ++i) {
    float s1 = 0.f, s2 = 0.f;
#pragma unroll
    for (int j = 0; j < 8; ++j) {
      float v = fmaxf(acc[i][j] + bb[j], 0.f);
      acc[i][j] = v; s1 += v; s2 += v*v;
    }
    red1[n0+i][lane>>3] = s1;
    red2[n0+i][lane>>3] = s2;
  }
  __syncthreads();
  if (t < 128) {
    float s1 = 0.f, s2 = 0.f;
#pragma unroll
    for (int g = 0; g < 8; ++g) { s1 += red1[t][g]; s2 += red2[t][g]; }
    float mu = s1 * (1.f/64.f);
    float var = fmaxf(s2 * (1.f/64.f) - mu*mu, 0.f);
    stat[t][0] = mu; stat[t][1] = rsqrtf(var + LN_EPSF);
  }
  __syncthreads();
#pragma unroll
  for (int i = 0; i < 8; ++i) {
    int ni = n0 + i;
    float mu = stat[ni][0], rs = stat[ni][1];
    float pd = 0.f;
#pragma unroll
    for (int j = 0; j < 8; ++j) pd += ((acc[i][j]-mu)*rs*gg[j] + be[j]) * w2v[j];
    red1[ni][lane>>3] = pd;
  }
  __syncthreads();
  {
    int gn = nb + t;
    if (gn < N_NODESC) {
      float gv = b2[0];
#pragma unroll
      for (int g = 0; g < 8; ++g) gv += red1[t][g];
      gateb[gn] = gv;
      atomicMax(&gmaxu[batch[gn]], ord_enc(gv));
    }
  }
}

// ---------- exp + weighted accumulation into per-graph sums ----------
__global__ __launch_bounds__(256) void expacc_kernel(const float* __restrict__ H,
    const float* __restrict__ gateb, const int* __restrict__ batch,
    const unsigned* __restrict__ gmaxu, float* __restrict__ S,
    float* __restrict__ denom) {
  const int t = threadIdx.x;
  const int j = t & 127, v = t >> 7;
  const int node = blockIdx.x * 2 + v;
  if (node >= N_NODESC) return;
  const int g = batch[node];
  const float gm = ord_dec(gmaxu[g]);
  const float e = expf(gateb[node] - gm);
  atomicAdd(&S[g*HIDC + j], e * H[node*HIDC + j]);
  if (j == 0) atomicAdd(&denom[g], e);
}

// ---------- head MLP per graph ----------
__global__ __launch_bounds__(64) void head_kernel(const float* __restrict__ S,
    const float* __restrict__ denom, const float* __restrict__ W1,
    const float* __restrict__ b1, const float* __restrict__ g,
    const float* __restrict__ be, const float* __restrict__ W2,
    const float* __restrict__ b2, float* __restrict__ out) {
  const int gr = blockIdx.x;
  const int j = threadIdx.x;
  const float inv = 1.0f / denom[gr];
  float v = b1[j];
  for (int k = 0; k < HIDC; ++k) v += (S[gr*HIDC + k] * inv) * W1[j*HIDC + k];
  v = fmaxf(v, 0.f);
  float s1 = v, s2 = v*v;
  for (int off = 32; off; off >>= 1) { s1 += __shfl_xor(s1, off); s2 += __shfl_xor(s2, off); }
  float mu = s1 * (1.f/64.f);
  float var = fmaxf(s2 * (1.f/64.f) - mu*mu, 0.f);
  float rs = rsqrtf(var + LN_EPSF);
  float z = (v-mu)*rs*g[j] + be[j];
  float p = z * W2[j];
  for (int off = 32; off; off >>= 1) p += __shfl_xor(p, off);
  if (j == 0) out[gr] = p + b2[0];
}

// ---------- launch ----------
extern "C" void kernel_launch(void* const* d_in, const int* in_sizes, int n_in,
                              void* d_out, int out_size, void* d_ws, size_t ws_size,
                              hipStream_t stream) {
  (void)in_sizes; (void)n_in; (void)out_size; (void)ws_size;
  const float* x     = (const float*)d_in[0];
  const int*   ei    = (const int*)d_in[1];
  const int*   batch = (const int*)d_in[2];
  const float* aW1 = (const float*)d_in[3];
  const float* ab1 = (const float*)d_in[4];
  const float* ag  = (const float*)d_in[5];
  const float* abe = (const float*)d_in[6];
  const float* aW2 = (const float*)d_in[7];
  const float* ab2 = (const float*)d_in[8];
  const float* oW1 = (const float*)d_in[9];
  const float* ob1 = (const float*)d_in[10];
  const float* og  = (const float*)d_in[11];
  const float* obe = (const float*)d_in[12];
  const float* oW2 = (const float*)d_in[13];
  const float* ob2 = (const float*)d_in[14];
  const float* ninW = (const float*)d_in[15];
  const float* ninb = (const float*)d_in[16];
  const float* cW1 = (const float*)d_in[17];
  const float* cb1 = (const float*)d_in[18];
  const float* cg  = (const float*)d_in[19];
  const float* cbe = (const float*)d_in[20];
  const float* cW2 = (const float*)d_in[21];
  const float* cb2 = (const float*)d_in[22];
  const float* eps = (const float*)d_in[23];
  const float* lng = (const float*)d_in[24];
  const float* lnb = (const float*)d_in[25];
  const float* gW1 = (const float*)d_in[26];
  const float* gb1 = (const float*)d_in[27];
  const float* gg  = (const float*)d_in[28];
  const float* gbe = (const float*)d_in[29];
  const float* gW2 = (const float*)d_in[30];
  const float* gb2 = (const float*)d_in[31];
  const float* hW1 = (const float*)d_in[32];
  const float* hb1 = (const float*)d_in[33];
  const float* hg  = (const float*)d_in[34];
  const float* hbe = (const float*)d_in[35];
  const float* hW2 = (const float*)d_in[36];
  const float* hb2 = (const float*)d_in[37];

  char* ws = (char*)d_ws;
  float* H     = (float*)(ws + 0);            // 50000*128 f = 25,600,000 B
  float* T     = (float*)(ws + 25600000);     // 25,600,000 B
  float* M     = (float*)(ws + 51200000);     // 25,600,000 B
  float* gateb = (float*)(ws + 76800000);     // 200,000 B
  float* S     = (float*)(ws + 77000000);     // 32,768 B
  float* denom = (float*)(ws + 77032768);     // 256 B
  unsigned* gmaxu = (unsigned*)(ws + 77033024); // 256 B
  int* deg     = (int*)(ws + 77033280);       // 200,000 B
  int* rowptr  = (int*)(ws + 77233280);       // 200,004 B
  int* cursor  = (int*)(ws + 77433284);       // 200,000 B
  int* esrc    = (int*)(ws + 77633284);       // 2,560,000 B

  hipMemsetAsync(deg, 0, 200000, stream);
  hipMemsetAsync(S, 0, 33280, stream);  // S + denom + gmaxu contiguous

  const int egrid = (N_EDGESC + 255) / 256;
  hist_kernel<<<egrid, 256, 0, stream>>>(ei, deg);
  scan_kernel<<<1, 1024, 0, stream>>>(deg, rowptr, cursor);
  scatter_kernel<<<egrid, 256, 0, stream>>>(ei, cursor, esrc);

  const int ngrid64 = (N_NODESC + 63) / 64;
  enc_kernel<<<ngrid64, 128, 0, stream>>>(x, aW1, ab1, ag, abe, aW2, ab2,
                                          oW1, ob1, og, obe, oW2, ob2,
                                          ninW, ninb, H);
  for (int l = 0; l < 3; ++l) {
    agg_kernel<<<(N_NODESC + 3) / 4, 128, 0, stream>>>(H, rowptr, esrc, eps + l, M);
    gemm128_kernel<<<ngrid64, 128, 0, stream>>>(M, cW1 + l*HIDC*HIDC, cb1 + l*HIDC,
                                                cg + l*HIDC, cbe + l*HIDC, nullptr, T);
    gemm128_kernel<<<ngrid64, 128, 0, stream>>>(T, cW2 + l*HIDC*HIDC, cb2 + l*HIDC,
                                                lng + l*HIDC, lnb + l*HIDC, H, H);
  }
  gate_kernel<<<(N_NODESC + 127) / 128, 128, 0, stream>>>(H, gW1, gb1, gg, gbe, gW2, gb2,
                                                          batch, gateb, gmaxu);
  expacc_kernel<<<(N_NODESC + 1) / 2, 256, 0, stream>>>(H, gateb, batch, gmaxu, S, denom);
  head_kernel<<<N_GRAPHSC, 64, 0, stream>>>(S, denom, hW1, hb1, hg, hbe, hW2, hb2,
                                            (float*)d_out);
}

// Round 2
// 974.011 us; speedup vs baseline: 1.3207x; 1.3207x over previous
//
#include <hip/hip_runtime.h>

#define N_NODESC 50000
#define N_EDGESC 640000
#define N_GRAPHSC 64
#define HIDC 128
#define LN_EPSF 1e-5f
#define POOL_SPLIT 16

// ---------- helpers ----------
static __device__ __forceinline__ unsigned ord_enc(float f) {
  unsigned u = __float_as_uint(f);
  return (u & 0x80000000u) ? ~u : (u | 0x80000000u);
}
static __device__ __forceinline__ float ord_dec(unsigned u) {
  return __uint_as_float((u & 0x80000000u) ? (u ^ 0x80000000u) : ~u);
}
static __device__ __forceinline__ void f4add(float4& a, const float4 b) {
  a.x += b.x; a.y += b.y; a.z += b.z; a.w += b.w;
}

// small 3->16 relu LN 16->16 MLP (encoder preprocessing), one thread per node
static __device__ __forceinline__ void mlp16(float in0, float in1, float in2,
    const float* __restrict__ W1, const float* __restrict__ b1,
    const float* __restrict__ g, const float* __restrict__ be,
    const float* __restrict__ W2, const float* __restrict__ b2,
    float* __restrict__ out) {
  float h[16];
  float s1 = 0.f, s2 = 0.f;
#pragma unroll
  for (int j = 0; j < 16; ++j) {
    float v = b1[j] + W1[j*3+0]*in0 + W1[j*3+1]*in1 + W1[j*3+2]*in2;
    v = fmaxf(v, 0.f);
    h[j] = v; s1 += v; s2 += v*v;
  }
  float mu = s1 * (1.f/16.f);
  float var = fmaxf(s2 * (1.f/16.f) - mu*mu, 0.f);
  float rs = rsqrtf(var + LN_EPSF);
  float z[16];
#pragma unroll
  for (int j = 0; j < 16; ++j) z[j] = (h[j]-mu)*rs*g[j] + be[j];
#pragma unroll
  for (int j = 0; j < 16; ++j) {
    float v = b2[j];
#pragma unroll
    for (int k = 0; k < 16; ++k) v += W2[j*16+k]*z[k];
    out[j] = v;
  }
}

// ---------- CSR build ----------
__global__ __launch_bounds__(256) void hist_kernel(const int* __restrict__ ei, int* __restrict__ deg) {
  int e = blockIdx.x * 256 + threadIdx.x;
  if (e < N_EDGESC) atomicAdd(&deg[ei[N_EDGESC + e]], 1);
}

__global__ __launch_bounds__(1024) void scan_kernel(const int* __restrict__ deg,
                                                    int* __restrict__ rowptr,
                                                    int* __restrict__ cursor) {
  __shared__ int ps[1024];
  const int t = threadIdx.x;
  const int CH = 49;  // ceil(50000/1024)
  int start = t * CH;
  int end = start + CH; if (end > N_NODESC) end = N_NODESC;
  int s = 0;
  for (int i = start; i < end; ++i) s += deg[i];
  ps[t] = s;
  __syncthreads();
  for (int off = 1; off < 1024; off <<= 1) {
    int v = (t >= off) ? ps[t - off] : 0;
    __syncthreads();
    ps[t] += v;
    __syncthreads();
  }
  int run = ps[t] - s;  // exclusive prefix
  for (int i = start; i < end; ++i) {
    rowptr[i] = run; cursor[i] = run;
    run += deg[i];
  }
  if (t == 1023) rowptr[N_NODESC] = run;
}

__global__ __launch_bounds__(256) void scatter_kernel(const int* __restrict__ ei,
                                                      int* __restrict__ cursor,
                                                      int* __restrict__ esrc) {
  int e = blockIdx.x * 256 + threadIdx.x;
  if (e < N_EDGESC) {
    int d = ei[N_EDGESC + e];
    int slot = atomicAdd(&cursor[d], 1);
    esrc[slot] = ei[e];
  }
}

// ---------- graph boundary detection (batch is sorted) ----------
__global__ __launch_bounds__(256) void gbound_kernel(const int* __restrict__ batch,
                                                     int* __restrict__ gstart) {
  int i = blockIdx.x * 256 + threadIdx.x;
  if (i >= N_NODESC) return;
  int b = batch[i];
  int prev = (i == 0) ? -1 : batch[i-1];
  for (int g = prev + 1; g <= b; ++g) gstart[g] = i;
  if (i == N_NODESC - 1) {
    for (int g = b + 1; g <= N_GRAPHSC; ++g) gstart[g] = N_NODESC;
  }
}

// ---------- encoder: small MLPs + 45->128 projection ----------
__global__ __launch_bounds__(128) void enc_kernel(
    const float* __restrict__ x,
    const float* __restrict__ aW1, const float* __restrict__ ab1,
    const float* __restrict__ ag,  const float* __restrict__ abe,
    const float* __restrict__ aW2, const float* __restrict__ ab2,
    const float* __restrict__ oW1, const float* __restrict__ ob1,
    const float* __restrict__ og,  const float* __restrict__ obe,
    const float* __restrict__ oW2, const float* __restrict__ ob2,
    const float* __restrict__ ninW, const float* __restrict__ ninb,
    float* __restrict__ H) {
  __shared__ float sa[48*68];   // [k][n], n<64 pad 68
  __shared__ float sw[48*132];  // [k][f], f<128 pad 132
  const int t = threadIdx.x;
  const int lane = t & 63, w = t >> 6;
  const int nb = blockIdx.x * 64;

  if (t < 64) {
    float in45[45];
    const int gn = nb + t;
    if (gn < N_NODESC) {
      const float* xr = x + gn * 19;
#pragma unroll
      for (int k = 0; k < 9; ++k) in45[k] = xr[k];
#pragma unroll
      for (int k = 0; k < 4; ++k) in45[9+k] = xr[15+k];
      mlp16(xr[9], xr[10], xr[11], aW1, ab1, ag, abe, aW2, ab2, &in45[13]);
      mlp16(xr[12], xr[13], xr[14], oW1, ob1, og, obe, oW2, ob2, &in45[29]);
    } else {
#pragma unroll
      for (int k = 0; k < 45; ++k) in45[k] = 0.f;
    }
#pragma unroll
    for (int k = 0; k < 45; ++k) sa[k*68 + t] = in45[k];
#pragma unroll
    for (int k = 45; k < 48; ++k) sa[k*68 + t] = 0.f;
  }
  for (int idx = t; idx < 48*128; idx += 128) {
    int k = idx >> 7, f = idx & 127;
    sw[k*132 + f] = (k < 45) ? ninW[f*45 + k] : 0.f;
  }
  __syncthreads();

  const int n0 = (lane & 7) * 8;
  const int f0 = ((lane >> 3) << 3) + w * 64;
  float acc[8][8];
#pragma unroll
  for (int i = 0; i < 8; ++i)
#pragma unroll
    for (int j = 0; j < 8; ++j) acc[i][j] = 0.f;

#pragma unroll 4
  for (int k = 0; k < 48; ++k) {
    float av[8], wv[8];
    float4 a0 = *(const float4*)&sa[k*68 + n0];
    float4 a1 = *(const float4*)&sa[k*68 + n0 + 4];
    float4 w0 = *(const float4*)&sw[k*132 + f0];
    float4 w1 = *(const float4*)&sw[k*132 + f0 + 4];
    av[0]=a0.x; av[1]=a0.y; av[2]=a0.z; av[3]=a0.w;
    av[4]=a1.x; av[5]=a1.y; av[6]=a1.z; av[7]=a1.w;
    wv[0]=w0.x; wv[1]=w0.y; wv[2]=w0.z; wv[3]=w0.w;
    wv[4]=w1.x; wv[5]=w1.y; wv[6]=w1.z; wv[7]=w1.w;
#pragma unroll
    for (int i = 0; i < 8; ++i)
#pragma unroll
      for (int j = 0; j < 8; ++j) acc[i][j] += av[i]*wv[j];
  }
  float bb[8];
#pragma unroll
  for (int j = 0; j < 8; ++j) bb[j] = ninb[f0+j];
#pragma unroll
  for (int i = 0; i < 8; ++i) {
    int gn = nb + n0 + i;
    if (gn < N_NODESC) {
      float o[8];
#pragma unroll
      for (int j = 0; j < 8; ++j) o[j] = acc[i][j] + bb[j];
      *(float4*)&H[gn*HIDC + f0]     = make_float4(o[0],o[1],o[2],o[3]);
      *(float4*)&H[gn*HIDC + f0 + 4] = make_float4(o[4],o[5],o[6],o[7]);
    }
  }
}

// ---------- aggregation: M = (1+eps)*H + sum_{src in bucket(dst)} H[src] ----------
__global__ __launch_bounds__(128) void agg_kernel(const float* __restrict__ H,
    const int* __restrict__ rowptr, const int* __restrict__ esrc,
    const float* __restrict__ epsp, float* __restrict__ M) {
  const int t = threadIdx.x;
  const int c = t & 31;    // float4 column (128 floats = 32 float4)
  const int v = t >> 5;    // node sub-index 0..3
  const int node = blockIdx.x * 4 + v;
  if (node >= N_NODESC) return;
  const float4* H4 = (const float4*)H;
  float4 h = H4[node*32 + c];
  const float e1 = 1.0f + epsp[0];
  float4 a0 = make_float4(0,0,0,0), a1 = a0, a2 = a0, a3 = a0;
  int s = rowptr[node];
  const int e = rowptr[node+1];
  for (; s + 4 <= e; s += 4) {
    int i0 = esrc[s], i1 = esrc[s+1], i2 = esrc[s+2], i3 = esrc[s+3];
    float4 x0 = H4[i0*32+c], x1 = H4[i1*32+c], x2 = H4[i2*32+c], x3 = H4[i3*32+c];
    f4add(a0,x0); f4add(a1,x1); f4add(a2,x2); f4add(a3,x3);
  }
  for (; s < e; ++s) f4add(a0, H4[esrc[s]*32+c]);
  float4 m;
  m.x = e1*h.x + a0.x+a1.x+a2.x+a3.x;
  m.y = e1*h.y + a0.y+a1.y+a2.y+a3.y;
  m.z = e1*h.z + a0.z+a1.z+a2.z+a3.z;
  m.w = e1*h.w + a0.w+a1.w+a2.w+a3.w;
  ((float4*)M)[node*32 + c] = m;
}

// ---------- fp32 GEMM 128x128 + bias + relu + LN (+optional residual) ----------
__global__ __launch_bounds__(128) void gemm128_kernel(
    const float* __restrict__ IN, const float* __restrict__ W,
    const float* __restrict__ bias, const float* __restrict__ lng,
    const float* __restrict__ lnb, const float* __restrict__ resid,
    float* __restrict__ OUT) {
  __shared__ float sa[32*68];
  __shared__ float sw[32*132];
  __shared__ float red1[64][16];
  __shared__ float red2[64][16];
  __shared__ float stat[64][2];
  const int t = threadIdx.x, lane = t & 63, w = t >> 6;
  const int nb = blockIdx.x * 64;
  const int n0 = (lane & 7) * 8;
  const int f0 = ((lane >> 3) << 3) + w * 64;
  float acc[8][8];
#pragma unroll
  for (int i = 0; i < 8; ++i)
#pragma unroll
    for (int j = 0; j < 8; ++j) acc[i][j] = 0.f;

  for (int kc = 0; kc < 4; ++kc) {
    const int k0 = kc * 32;
#pragma unroll
    for (int i = 0; i < 4; ++i) {
      int q = t + i*128;
      int n = q >> 3, kk = (q & 7) * 4;
      int gn = nb + n;
      float4 v = make_float4(0,0,0,0);
      if (gn < N_NODESC) v = *(const float4*)&IN[gn*HIDC + k0 + kk];
      sa[(kk+0)*68+n]=v.x; sa[(kk+1)*68+n]=v.y; sa[(kk+2)*68+n]=v.z; sa[(kk+3)*68+n]=v.w;
    }
#pragma unroll
    for (int i = 0; i < 8; ++i) {
      int q = t + i*128;
      int f = q >> 3, kk = (q & 7) * 4;
      float4 v = *(const float4*)&W[f*HIDC + k0 + kk];
      sw[(kk+0)*132+f]=v.x; sw[(kk+1)*132+f]=v.y; sw[(kk+2)*132+f]=v.z; sw[(kk+3)*132+f]=v.w;
    }
    __syncthreads();
#pragma unroll 4
    for (int k = 0; k < 32; ++k) {
      float av[8], wv[8];
      float4 a0 = *(const float4*)&sa[k*68 + n0];
      float4 a1 = *(const float4*)&sa[k*68 + n0 + 4];
      float4 w0 = *(const float4*)&sw[k*132 + f0];
      float4 w1 = *(const float4*)&sw[k*132 + f0 + 4];
      av[0]=a0.x; av[1]=a0.y; av[2]=a0.z; av[3]=a0.w;
      av[4]=a1.x; av[5]=a1.y; av[6]=a1.z; av[7]=a1.w;
      wv[0]=w0.x; wv[1]=w0.y; wv[2]=w0.z; wv[3]=w0.w;
      wv[4]=w1.x; wv[5]=w1.y; wv[6]=w1.z; wv[7]=w1.w;
#pragma unroll
      for (int i = 0; i < 8; ++i)
#pragma unroll
        for (int j = 0; j < 8; ++j) acc[i][j] += av[i]*wv[j];
    }
    __syncthreads();
  }

  float bb[8], gg[8], be[8];
#pragma unroll
  for (int j = 0; j < 8; ++j) { bb[j] = bias[f0+j]; gg[j] = lng[f0+j]; be[j] = lnb[f0+j]; }
#pragma unroll
  for (int i = 0; i < 8; ++i) {
    float s1 = 0.f, s2 = 0.f;
#pragma unroll
    for (int j = 0; j < 8; ++j) {
      float v = fmaxf(acc[i][j] + bb[j], 0.f);
      acc[i][j] = v; s1 += v; s2 += v*v;
    }
    red1[n0+i][(lane>>3) + 8*w] = s1;
    red2[n0+i][(lane>>3) + 8*w] = s2;
  }
  __syncthreads();
  if (t < 64) {
    float s1 = 0.f, s2 = 0.f;
#pragma unroll
    for (int g = 0; g < 16; ++g) { s1 += red1[t][g]; s2 += red2[t][g]; }
    float mu = s1 * (1.f/128.f);
    float var = fmaxf(s2 * (1.f/128.f) - mu*mu, 0.f);
    stat[t][0] = mu; stat[t][1] = rsqrtf(var + LN_EPSF);
  }
  __syncthreads();
#pragma unroll
  for (int i = 0; i < 8; ++i) {
    int gn = nb + n0 + i;
    if (gn >= N_NODESC) continue;
    float mu = stat[n0+i][0], rs = stat[n0+i][1];
    float o[8];
#pragma unroll
    for (int j = 0; j < 8; ++j) o[j] = (acc[i][j]-mu)*rs*gg[j] + be[j];
    if (resid) {
      float4 r0 = *(const float4*)&resid[gn*HIDC + f0];
      float4 r1 = *(const float4*)&resid[gn*HIDC + f0 + 4];
      o[0]+=r0.x; o[1]+=r0.y; o[2]+=r0.z; o[3]+=r0.w;
      o[4]+=r1.x; o[5]+=r1.y; o[6]+=r1.z; o[7]+=r1.w;
    }
    *(float4*)&OUT[gn*HIDC + f0]     = make_float4(o[0],o[1],o[2],o[3]);
    *(float4*)&OUT[gn*HIDC + f0 + 4] = make_float4(o[4],o[5],o[6],o[7]);
  }
}

// ---------- gate: 128->64 + relu + LN + dot(W2) -> scalar, atomicMax per graph ----------
__global__ __launch_bounds__(128) void gate_kernel(
    const float* __restrict__ H, const float* __restrict__ W1,
    const float* __restrict__ b1, const float* __restrict__ lng,
    const float* __restrict__ lnb, const float* __restrict__ W2,
    const float* __restrict__ b2, const int* __restrict__ batch,
    float* __restrict__ gateb, unsigned* __restrict__ gmaxu) {
  __shared__ float sa[32*132];  // [k][n], n<128 pad 132
  __shared__ float sw[32*68];   // [k][f], f<64 pad 68
  __shared__ float red1[128][8];
  __shared__ float red2[128][8];
  __shared__ float stat[128][2];
  const int t = threadIdx.x, lane = t & 63, w = t >> 6;
  const int nb = blockIdx.x * 128;
  const int n0 = (lane & 7) * 8 + w * 64;
  const int f0 = (lane >> 3) * 8;
  float acc[8][8];
#pragma unroll
  for (int i = 0; i < 8; ++i)
#pragma unroll
    for (int j = 0; j < 8; ++j) acc[i][j] = 0.f;

  for (int kc = 0; kc < 4; ++kc) {
    const int k0 = kc * 32;
#pragma unroll
    for (int i = 0; i < 8; ++i) {
      int q = t + i*128;
      int n = q >> 3, kk = (q & 7) * 4;
      int gn = nb + n;
      float4 v = make_float4(0,0,0,0);
      if (gn < N_NODESC) v = *(const float4*)&H[gn*HIDC + k0 + kk];
      sa[(kk+0)*132+n]=v.x; sa[(kk+1)*132+n]=v.y; sa[(kk+2)*132+n]=v.z; sa[(kk+3)*132+n]=v.w;
    }
#pragma unroll
    for (int i = 0; i < 4; ++i) {
      int q = t + i*128;
      int f = q >> 3, kk = (q & 7) * 4;
      float4 v = *(const float4*)&W1[f*HIDC + k0 + kk];
      sw[(kk+0)*68+f]=v.x; sw[(kk+1)*68+f]=v.y; sw[(kk+2)*68+f]=v.z; sw[(kk+3)*68+f]=v.w;
    }
    __syncthreads();
#pragma unroll 4
    for (int k = 0; k < 32; ++k) {
      float av[8], wv[8];
      float4 a0 = *(const float4*)&sa[k*132 + n0];
      float4 a1 = *(const float4*)&sa[k*132 + n0 + 4];
      float4 w0 = *(const float4*)&sw[k*68 + f0];
      float4 w1 = *(const float4*)&sw[k*68 + f0 + 4];
      av[0]=a0.x; av[1]=a0.y; av[2]=a0.z; av[3]=a0.w;
      av[4]=a1.x; av[5]=a1.y; av[6]=a1.z; av[7]=a1.w;
      wv[0]=w0.x; wv[1]=w0.y; wv[2]=w0.z; wv[3]=w0.w;
      wv[4]=w1.x; wv[5]=w1.y; wv[6]=w1.z; wv[7]=w1.w;
#pragma unroll
      for (int i = 0; i < 8; ++i)
#pragma unroll
        for (int j = 0; j < 8; ++j) acc[i][j] += av[i]*wv[j];
    }
    __syncthreads();
  }

  float bb[8], gg[8], be[8], w2v[8];
#pragma unroll
  for (int j = 0; j < 8; ++j) { bb[j]=b1[f0+j]; gg[j]=lng[f0+j]; be[j]=lnb[f0+j]; w2v[j]=W2[f0+j]; }
#pragma unroll
  for (int i = 0; i < 8; ++i) {
    float s1 = 0.f, s2 = 0.f;
#pragma unroll
    for (int j = 0; j < 8; ++j) {
      float v = fmaxf(acc[i][j] + bb[j], 0.f);
      acc[i][j] = v; s1 += v; s2 += v*v;
    }
    red1[n0+i][lane>>3] = s1;
    red2[n0+i][lane>>3] = s2;
  }
  __syncthreads();
  if (t < 128) {
    float s1 = 0.f, s2 = 0.f;
#pragma unroll
    for (int g = 0; g < 8; ++g) { s1 += red1[t][g]; s2 += red2[t][g]; }
    float mu = s1 * (1.f/64.f);
    float var = fmaxf(s2 * (1.f/64.f) - mu*mu, 0.f);
    stat[t][0] = mu; stat[t][1] = rsqrtf(var + LN_EPSF);
  }
  __syncthreads();
#pragma unroll
  for (int i = 0; i < 8; ++i) {
    int ni = n0 + i;
    float mu = stat[ni][0], rs = stat[ni][1];
    float pd = 0.f;
#pragma unroll
    for (int j = 0; j < 8; ++j) pd += ((acc[i][j]-mu)*rs*gg[j] + be[j]) * w2v[j];
    red1[ni][lane>>3] = pd;
  }
  __syncthreads();
  {
    int gn = nb + t;
    if (gn < N_NODESC) {
      float gv = b2[0];
#pragma unroll
      for (int g = 0; g < 8; ++g) gv += red1[t][g];
      gateb[gn] = gv;
      atomicMax(&gmaxu[batch[gn]], ord_enc(gv));
    }
  }
}

// ---------- segmented softmax-weighted pooling (replaces atomic-heavy expacc) ----------
__global__ __launch_bounds__(256) void pool_kernel(const float* __restrict__ H,
    const float* __restrict__ gateb, const int* __restrict__ gstart,
    const unsigned* __restrict__ gmaxu, float* __restrict__ S,
    float* __restrict__ denom) {
  const int g    = blockIdx.x / POOL_SPLIT;
  const int part = blockIdx.x % POOL_SPLIT;
  const int s0 = gstart[g], s1 = gstart[g+1];
  const int cnt = s1 - s0;
  const int chunk = (cnt + POOL_SPLIT - 1) / POOL_SPLIT;
  int lo = s0 + part * chunk;
  int hi = lo + chunk; if (hi > s1) hi = s1;
  const int t = threadIdx.x;
  const int j = t & 127;   // feature
  const int v = t >> 7;    // node subgroup 0..1
  const float gm = ord_dec(gmaxu[g]);
  float acc = 0.f, de = 0.f;
  for (int n = lo + v; n < hi; n += 2) {
    float e = expf(gateb[n] - gm);
    acc += e * H[n*HIDC + j];
    if (j == 0) de += e;
  }
  __shared__ float sacc[256];
  __shared__ float sden[2];
  sacc[t] = acc;
  if (j == 0) sden[v] = de;
  __syncthreads();
  if (t < 128) {
    float s = sacc[t] + sacc[t+128];
    atomicAdd(&S[g*HIDC + t], s);
  }
  if (t == 0) atomicAdd(&denom[g], sden[0] + sden[1]);
}

// ---------- head MLP per graph ----------
__global__ __launch_bounds__(64) void head_kernel(const float* __restrict__ S,
    const float* __restrict__ denom, const float* __restrict__ W1,
    const float* __restrict__ b1, const float* __restrict__ g,
    const float* __restrict__ be, const float* __restrict__ W2,
    const float* __restrict__ b2, float* __restrict__ out) {
  const int gr = blockIdx.x;
  const int j = threadIdx.x;
  const float inv = 1.0f / denom[gr];
  float v = b1[j];
  for (int k = 0; k < HIDC; ++k) v += (S[gr*HIDC + k] * inv) * W1[j*HIDC + k];
  v = fmaxf(v, 0.f);
  float s1 = v, s2 = v*v;
  for (int off = 32; off; off >>= 1) { s1 += __shfl_xor(s1, off); s2 += __shfl_xor(s2, off); }
  float mu = s1 * (1.f/64.f);
  float var = fmaxf(s2 * (1.f/64.f) - mu*mu, 0.f);
  float rs = rsqrtf(var + LN_EPSF);
  float z = (v-mu)*rs*g[j] + be[j];
  float p = z * W2[j];
  for (int off = 32; off; off >>= 1) p += __shfl_xor(p, off);
  if (j == 0) out[gr] = p + b2[0];
}

// ---------- launch ----------
extern "C" void kernel_launch(void* const* d_in, const int* in_sizes, int n_in,
                              void* d_out, int out_size, void* d_ws, size_t ws_size,
                              hipStream_t stream) {
  (void)in_sizes; (void)n_in; (void)out_size; (void)ws_size;
  const float* x     = (const float*)d_in[0];
  const int*   ei    = (const int*)d_in[1];
  const int*   batch = (const int*)d_in[2];
  const float* aW1 = (const float*)d_in[3];
  const float* ab1 = (const float*)d_in[4];
  const float* ag  = (const float*)d_in[5];
  const float* abe = (const float*)d_in[6];
  const float* aW2 = (const float*)d_in[7];
  const float* ab2 = (const float*)d_in[8];
  const float* oW1 = (const float*)d_in[9];
  const float* ob1 = (const float*)d_in[10];
  const float* og  = (const float*)d_in[11];
  const float* obe = (const float*)d_in[12];
  const float* oW2 = (const float*)d_in[13];
  const float* ob2 = (const float*)d_in[14];
  const float* ninW = (const float*)d_in[15];
  const float* ninb = (const float*)d_in[16];
  const float* cW1 = (const float*)d_in[17];
  const float* cb1 = (const float*)d_in[18];
  const float* cg  = (const float*)d_in[19];
  const float* cbe = (const float*)d_in[20];
  const float* cW2 = (const float*)d_in[21];
  const float* cb2 = (const float*)d_in[22];
  const float* eps = (const float*)d_in[23];
  const float* lng = (const float*)d_in[24];
  const float* lnb = (const float*)d_in[25];
  const float* gW1 = (const float*)d_in[26];
  const float* gb1 = (const float*)d_in[27];
  const float* gg  = (const float*)d_in[28];
  const float* gbe = (const float*)d_in[29];
  const float* gW2 = (const float*)d_in[30];
  const float* gb2 = (const float*)d_in[31];
  const float* hW1 = (const float*)d_in[32];
  const float* hb1 = (const float*)d_in[33];
  const float* hg  = (const float*)d_in[34];
  const float* hbe = (const float*)d_in[35];
  const float* hW2 = (const float*)d_in[36];
  const float* hb2 = (const float*)d_in[37];

  char* ws = (char*)d_ws;
  float* H     = (float*)(ws + 0);            // 25,600,000 B
  float* T     = (float*)(ws + 25600000);     // 25,600,000 B
  float* M     = (float*)(ws + 51200000);     // 25,600,000 B
  float* gateb = (float*)(ws + 76800000);     // 200,000 B
  float* S     = (float*)(ws + 77000000);     // 32,768 B
  float* denom = (float*)(ws + 77032768);     // 256 B
  unsigned* gmaxu = (unsigned*)(ws + 77033024); // 256 B
  int* deg     = (int*)(ws + 77033280);       // 200,000 B
  int* rowptr  = (int*)(ws + 77233280);       // 200,004 B
  int* cursor  = (int*)(ws + 77433284);       // 200,000 B (reused as gstart after scatter)
  int* esrc    = (int*)(ws + 77633284);       // 2,560,000 B
  int* gstart  = cursor;  // alias: cursor is dead after scatter_kernel

  hipMemsetAsync(deg, 0, 200000, stream);
  hipMemsetAsync(S, 0, 33280, stream);  // S + denom + gmaxu contiguous

  const int egrid = (N_EDGESC + 255) / 256;
  hist_kernel<<<egrid, 256, 0, stream>>>(ei, deg);
  scan_kernel<<<1, 1024, 0, stream>>>(deg, rowptr, cursor);
  scatter_kernel<<<egrid, 256, 0, stream>>>(ei, cursor, esrc);
  gbound_kernel<<<(N_NODESC + 255) / 256, 256, 0, stream>>>(batch, gstart);

  const int ngrid64 = (N_NODESC + 63) / 64;
  enc_kernel<<<ngrid64, 128, 0, stream>>>(x, aW1, ab1, ag, abe, aW2, ab2,
                                          oW1, ob1, og, obe, oW2, ob2,
                                          ninW, ninb, H);
  for (int l = 0; l < 3; ++l) {
    agg_kernel<<<(N_NODESC + 3) / 4, 128, 0, stream>>>(H, rowptr, esrc, eps + l, M);
    gemm128_kernel<<<ngrid64, 128, 0, stream>>>(M, cW1 + l*HIDC*HIDC, cb1 + l*HIDC,
                                                cg + l*HIDC, cbe + l*HIDC, nullptr, T);
    gemm128_kernel<<<ngrid64, 128, 0, stream>>>(T, cW2 + l*HIDC*HIDC, cb2 + l*HIDC,
                                                lng + l*HIDC, lnb + l*HIDC, H, H);
  }
  gate_kernel<<<(N_NODESC + 127) / 128, 128, 0, stream>>>(H, gW1, gb1, gg, gbe, gW2, gb2,
                                                          batch, gateb, gmaxu);
  pool_kernel<<<N_GRAPHSC * POOL_SPLIT, 256, 0, stream>>>(H, gateb, gstart, gmaxu, S, denom);
  head_kernel<<<N_GRAPHSC, 64, 0, stream>>>(S, denom, hW1, hb1, hg, hbe, hW2, hb2,
                                            (float*)d_out);
}

// Round 3
// 850.320 us; speedup vs baseline: 1.5128x; 1.1455x over previous
//
#include <hip/hip_runtime.h>

#define N_NODESC 50000
#define N_EDGESC 640000
#define N_GRAPHSC 64
#define HIDC 128
#define LN_EPSF 1e-5f
#define POOL_SPLIT 16

typedef short bf16x8 __attribute__((ext_vector_type(8)));
typedef float f32x4 __attribute__((ext_vector_type(4)));

// ---------- helpers ----------
static __device__ __forceinline__ unsigned ord_enc(float f) {
  unsigned u = __float_as_uint(f);
  return (u & 0x80000000u) ? ~u : (u | 0x80000000u);
}
static __device__ __forceinline__ float ord_dec(unsigned u) {
  return __uint_as_float((u & 0x80000000u) ? (u ^ 0x80000000u) : ~u);
}
static __device__ __forceinline__ void f4add(float4& a, const float4 b) {
  a.x += b.x; a.y += b.y; a.z += b.z; a.w += b.w;
}
// fp32 -> bf16 bits, round-to-nearest-even
static __device__ __forceinline__ unsigned short f2bf(float x) {
  unsigned u = __float_as_uint(x);
  u += 0x7fffu + ((u >> 16) & 1u);
  return (unsigned short)(u >> 16);
}
static __device__ __forceinline__ float bf2f(unsigned short b) {
  return __uint_as_float(((unsigned)b) << 16);
}

// small 3->16 relu LN 16->16 MLP (encoder preprocessing), one thread per node
static __device__ __forceinline__ void mlp16(float in0, float in1, float in2,
    const float* __restrict__ W1, const float* __restrict__ b1,
    const float* __restrict__ g, const float* __restrict__ be,
    const float* __restrict__ W2, const float* __restrict__ b2,
    float* __restrict__ out) {
  float h[16];
  float s1 = 0.f, s2 = 0.f;
#pragma unroll
  for (int j = 0; j < 16; ++j) {
    float v = b1[j] + W1[j*3+0]*in0 + W1[j*3+1]*in1 + W1[j*3+2]*in2;
    v = fmaxf(v, 0.f);
    h[j] = v; s1 += v; s2 += v*v;
  }
  float mu = s1 * (1.f/16.f);
  float var = fmaxf(s2 * (1.f/16.f) - mu*mu, 0.f);
  float rs = rsqrtf(var + LN_EPSF);
  float z[16];
#pragma unroll
  for (int j = 0; j < 16; ++j) z[j] = (h[j]-mu)*rs*g[j] + be[j];
#pragma unroll
  for (int j = 0; j < 16; ++j) {
    float v = b2[j];
#pragma unroll
    for (int k = 0; k < 16; ++k) v += W2[j*16+k]*z[k];
    out[j] = v;
  }
}

// ---------- CSR build ----------
__global__ __launch_bounds__(256) void hist_kernel(const int* __restrict__ ei, int* __restrict__ deg) {
  int e = blockIdx.x * 256 + threadIdx.x;
  if (e < N_EDGESC) atomicAdd(&deg[ei[N_EDGESC + e]], 1);
}

__global__ __launch_bounds__(1024) void scan_kernel(const int* __restrict__ deg,
                                                    int* __restrict__ rowptr,
                                                    int* __restrict__ cursor) {
  __shared__ int ps[1024];
  const int t = threadIdx.x;
  const int CH = 49;  // ceil(50000/1024)
  int start = t * CH;
  int end = start + CH; if (end > N_NODESC) end = N_NODESC;
  int s = 0;
  for (int i = start; i < end; ++i) s += deg[i];
  ps[t] = s;
  __syncthreads();
  for (int off = 1; off < 1024; off <<= 1) {
    int v = (t >= off) ? ps[t - off] : 0;
    __syncthreads();
    ps[t] += v;
    __syncthreads();
  }
  int run = ps[t] - s;  // exclusive prefix
  for (int i = start; i < end; ++i) {
    rowptr[i] = run; cursor[i] = run;
    run += deg[i];
  }
  if (t == 1023) rowptr[N_NODESC] = run;
}

__global__ __launch_bounds__(256) void scatter_kernel(const int* __restrict__ ei,
                                                      int* __restrict__ cursor,
                                                      int* __restrict__ esrc) {
  int e = blockIdx.x * 256 + threadIdx.x;
  if (e < N_EDGESC) {
    int d = ei[N_EDGESC + e];
    int slot = atomicAdd(&cursor[d], 1);
    esrc[slot] = ei[e];
  }
}

// ---------- graph boundary detection (batch is sorted) ----------
__global__ __launch_bounds__(256) void gbound_kernel(const int* __restrict__ batch,
                                                     int* __restrict__ gstart) {
  int i = blockIdx.x * 256 + threadIdx.x;
  if (i >= N_NODESC) return;
  int b = batch[i];
  int prev = (i == 0) ? -1 : batch[i-1];
  for (int g = prev + 1; g <= b; ++g) gstart[g] = i;
  if (i == N_NODESC - 1) {
    for (int g = b + 1; g <= N_GRAPHSC; ++g) gstart[g] = N_NODESC;
  }
}

// ---------- encoder: small MLPs + 45->128 projection ----------
__global__ __launch_bounds__(128) void enc_kernel(
    const float* __restrict__ x,
    const float* __restrict__ aW1, const float* __restrict__ ab1,
    const float* __restrict__ ag,  const float* __restrict__ abe,
    const float* __restrict__ aW2, const float* __restrict__ ab2,
    const float* __restrict__ oW1, const float* __restrict__ ob1,
    const float* __restrict__ og,  const float* __restrict__ obe,
    const float* __restrict__ oW2, const float* __restrict__ ob2,
    const float* __restrict__ ninW, const float* __restrict__ ninb,
    float* __restrict__ H) {
  __shared__ float sa[48*68];   // [k][n], n<64 pad 68
  __shared__ float sw[48*132];  // [k][f], f<128 pad 132
  const int t = threadIdx.x;
  const int lane = t & 63, w = t >> 6;
  const int nb = blockIdx.x * 64;

  if (t < 64) {
    float in45[45];
    const int gn = nb + t;
    if (gn < N_NODESC) {
      const float* xr = x + gn * 19;
#pragma unroll
      for (int k = 0; k < 9; ++k) in45[k] = xr[k];
#pragma unroll
      for (int k = 0; k < 4; ++k) in45[9+k] = xr[15+k];
      mlp16(xr[9], xr[10], xr[11], aW1, ab1, ag, abe, aW2, ab2, &in45[13]);
      mlp16(xr[12], xr[13], xr[14], oW1, ob1, og, obe, oW2, ob2, &in45[29]);
    } else {
#pragma unroll
      for (int k = 0; k < 45; ++k) in45[k] = 0.f;
    }
#pragma unroll
    for (int k = 0; k < 45; ++k) sa[k*68 + t] = in45[k];
#pragma unroll
    for (int k = 45; k < 48; ++k) sa[k*68 + t] = 0.f;
  }
  for (int idx = t; idx < 48*128; idx += 128) {
    int k = idx >> 7, f = idx & 127;
    sw[k*132 + f] = (k < 45) ? ninW[f*45 + k] : 0.f;
  }
  __syncthreads();

  const int n0 = (lane & 7) * 8;
  const int f0 = ((lane >> 3) << 3) + w * 64;
  float acc[8][8];
#pragma unroll
  for (int i = 0; i < 8; ++i)
#pragma unroll
    for (int j = 0; j < 8; ++j) acc[i][j] = 0.f;

#pragma unroll 4
  for (int k = 0; k < 48; ++k) {
    float av[8], wv[8];
    float4 a0 = *(const float4*)&sa[k*68 + n0];
    float4 a1 = *(const float4*)&sa[k*68 + n0 + 4];
    float4 w0 = *(const float4*)&sw[k*132 + f0];
    float4 w1 = *(const float4*)&sw[k*132 + f0 + 4];
    av[0]=a0.x; av[1]=a0.y; av[2]=a0.z; av[3]=a0.w;
    av[4]=a1.x; av[5]=a1.y; av[6]=a1.z; av[7]=a1.w;
    wv[0]=w0.x; wv[1]=w0.y; wv[2]=w0.z; wv[3]=w0.w;
    wv[4]=w1.x; wv[5]=w1.y; wv[6]=w1.z; wv[7]=w1.w;
#pragma unroll
    for (int i = 0; i < 8; ++i)
#pragma unroll
      for (int j = 0; j < 8; ++j) acc[i][j] += av[i]*wv[j];
  }
  float bb[8];
#pragma unroll
  for (int j = 0; j < 8; ++j) bb[j] = ninb[f0+j];
#pragma unroll
  for (int i = 0; i < 8; ++i) {
    int gn = nb + n0 + i;
    if (gn < N_NODESC) {
      float o[8];
#pragma unroll
      for (int j = 0; j < 8; ++j) o[j] = acc[i][j] + bb[j];
      *(float4*)&H[gn*HIDC + f0]     = make_float4(o[0],o[1],o[2],o[3]);
      *(float4*)&H[gn*HIDC + f0 + 4] = make_float4(o[4],o[5],o[6],o[7]);
    }
  }
}

// ---------- aggregation: M = (1+eps)*H + sum_{src in bucket(dst)} H[src] ----------
__global__ __launch_bounds__(128) void agg_kernel(const float* __restrict__ H,
    const int* __restrict__ rowptr, const int* __restrict__ esrc,
    const float* __restrict__ epsp, float* __restrict__ M) {
  const int t = threadIdx.x;
  const int c = t & 31;    // float4 column (128 floats = 32 float4)
  const int v = t >> 5;    // node sub-index 0..3
  const int node = blockIdx.x * 4 + v;
  if (node >= N_NODESC) return;
  const float4* H4 = (const float4*)H;
  float4 h = H4[node*32 + c];
  const float e1 = 1.0f + epsp[0];
  float4 a0 = make_float4(0,0,0,0), a1 = a0, a2 = a0, a3 = a0;
  int s = rowptr[node];
  const int e = rowptr[node+1];
  for (; s + 4 <= e; s += 4) {
    int i0 = esrc[s], i1 = esrc[s+1], i2 = esrc[s+2], i3 = esrc[s+3];
    float4 x0 = H4[i0*32+c], x1 = H4[i1*32+c], x2 = H4[i2*32+c], x3 = H4[i3*32+c];
    f4add(a0,x0); f4add(a1,x1); f4add(a2,x2); f4add(a3,x3);
  }
  for (; s < e; ++s) f4add(a0, H4[esrc[s]*32+c]);
  float4 m;
  m.x = e1*h.x + a0.x+a1.x+a2.x+a3.x;
  m.y = e1*h.y + a0.y+a1.y+a2.y+a3.y;
  m.z = e1*h.z + a0.z+a1.z+a2.z+a3.z;
  m.w = e1*h.w + a0.w+a1.w+a2.w+a3.w;
  ((float4*)M)[node*32 + c] = m;
}

// ---------- MFMA GEMM: OUT[64 x 128] tile = IN @ W^T, + bias + relu + LN (+resid) ----------
// A operand split into hi+lo bf16 for near-fp32 activation precision; W plain bf16.
// LDS rows padded to 136 ushorts so fragment ds_read_b128 is 2-way (free).
__global__ __launch_bounds__(256, 2) void gemm_mfma_kernel(
    const float* __restrict__ IN, const float* __restrict__ W,
    const float* __restrict__ bias, const float* __restrict__ lng,
    const float* __restrict__ lnb, const float* __restrict__ resid,
    float* __restrict__ OUT) {
  __shared__ unsigned short Ah[64*136];
  __shared__ unsigned short Al[64*136];
  __shared__ unsigned short Wl[128*136];
  const int t = threadIdx.x;
  const int nb = blockIdx.x * 64;
  // stage W (128x128 fp32 -> bf16)
#pragma unroll
  for (int i = 0; i < 16; ++i) {
    int q = t + i*256;
    int f = q >> 5, c4 = q & 31;
    float4 v = *(const float4*)&W[f*HIDC + c4*4];
    ushort4 h;
    h.x = f2bf(v.x); h.y = f2bf(v.y); h.z = f2bf(v.z); h.w = f2bf(v.w);
    *(ushort4*)&Wl[f*136 + c4*4] = h;
  }
  // stage A (64x128 fp32 -> bf16 hi + lo)
#pragma unroll
  for (int i = 0; i < 8; ++i) {
    int q = t + i*256;
    int n = q >> 5, c4 = q & 31;
    int gn = nb + n;
    float4 v = make_float4(0,0,0,0);
    if (gn < N_NODESC) v = *(const float4*)&IN[gn*HIDC + c4*4];
    ushort4 hi, lo;
    hi.x = f2bf(v.x); lo.x = f2bf(v.x - bf2f(hi.x));
    hi.y = f2bf(v.y); lo.y = f2bf(v.y - bf2f(hi.y));
    hi.z = f2bf(v.z); lo.z = f2bf(v.z - bf2f(hi.z));
    hi.w = f2bf(v.w); lo.w = f2bf(v.w - bf2f(hi.w));
    *(ushort4*)&Ah[n*136 + c4*4] = hi;
    *(ushort4*)&Al[n*136 + c4*4] = lo;
  }
  __syncthreads();

  const int lane = t & 63, wv = t >> 6;
  const int quad = lane >> 4, l16 = lane & 15;
  f32x4 acc[8];
#pragma unroll
  for (int ft = 0; ft < 8; ++ft) acc[ft] = (f32x4){0.f,0.f,0.f,0.f};

  const int arow = (wv*16 + l16)*136 + quad*8;
#pragma unroll
  for (int ks = 0; ks < 4; ++ks) {
    bf16x8 a_h = *(const bf16x8*)(const void*)&Ah[arow + ks*32];
    bf16x8 a_l = *(const bf16x8*)(const void*)&Al[arow + ks*32];
#pragma unroll
    for (int ft = 0; ft < 8; ++ft) {
      bf16x8 b = *(const bf16x8*)(const void*)&Wl[(ft*16 + l16)*136 + quad*8 + ks*32];
      acc[ft] = __builtin_amdgcn_mfma_f32_16x16x32_bf16(a_h, b, acc[ft], 0, 0, 0);
      acc[ft] = __builtin_amdgcn_mfma_f32_16x16x32_bf16(a_l, b, acc[ft], 0, 0, 0);
    }
  }

  // epilogue: bias + relu + LN(128) + optional residual.
  // C/D layout: feature f = ft*16 + l16 (col), node = nb + wv*16 + quad*4 + reg (row).
  float bb[8], gg[8], bee[8];
#pragma unroll
  for (int ft = 0; ft < 8; ++ft) {
    int f = ft*16 + l16;
    bb[ft] = bias[f]; gg[ft] = lng[f]; bee[ft] = lnb[f];
  }
  float s1[4] = {0,0,0,0}, s2[4] = {0,0,0,0};
#pragma unroll
  for (int ft = 0; ft < 8; ++ft)
#pragma unroll
    for (int r = 0; r < 4; ++r) {
      float v = fmaxf(acc[ft][r] + bb[ft], 0.f);
      acc[ft][r] = v; s1[r] += v; s2[r] += v*v;
    }
#pragma unroll
  for (int m = 1; m < 16; m <<= 1)
#pragma unroll
    for (int r = 0; r < 4; ++r) {
      s1[r] += __shfl_xor(s1[r], m);
      s2[r] += __shfl_xor(s2[r], m);
    }
  float mu[4], rs[4];
#pragma unroll
  for (int r = 0; r < 4; ++r) {
    mu[r] = s1[r] * (1.f/128.f);
    float var = fmaxf(s2[r] * (1.f/128.f) - mu[r]*mu[r], 0.f);
    rs[r] = rsqrtf(var + LN_EPSF);
  }
#pragma unroll
  for (int r = 0; r < 4; ++r) {
    int node = nb + wv*16 + quad*4 + r;
    if (node >= N_NODESC) continue;
    const int base = node*HIDC + l16;
#pragma unroll
    for (int ft = 0; ft < 8; ++ft) {
      float o = (acc[ft][r] - mu[r])*rs[r]*gg[ft] + bee[ft];
      if (resid) o += resid[base + ft*16];
      OUT[base + ft*16] = o;
    }
  }
}

// ---------- MFMA gate: per node z = LN(relu(H@W1^T+b1)); gate = z.W2 + b2 ----------
__global__ __launch_bounds__(256, 2) void gate_mfma_kernel(
    const float* __restrict__ H, const float* __restrict__ W1,
    const float* __restrict__ b1, const float* __restrict__ lng,
    const float* __restrict__ lnb, const float* __restrict__ W2,
    const float* __restrict__ b2, const int* __restrict__ batch,
    float* __restrict__ gateb, unsigned* __restrict__ gmaxu) {
  __shared__ unsigned short Ah[64*136];
  __shared__ unsigned short Al[64*136];
  __shared__ unsigned short Wl[64*136];
  const int t = threadIdx.x;
  const int nb = blockIdx.x * 64;
#pragma unroll
  for (int i = 0; i < 8; ++i) {
    int q = t + i*256;
    int f = q >> 5, c4 = q & 31;
    float4 v = *(const float4*)&W1[f*HIDC + c4*4];
    ushort4 h;
    h.x = f2bf(v.x); h.y = f2bf(v.y); h.z = f2bf(v.z); h.w = f2bf(v.w);
    *(ushort4*)&Wl[f*136 + c4*4] = h;
  }
#pragma unroll
  for (int i = 0; i < 8; ++i) {
    int q = t + i*256;
    int n = q >> 5, c4 = q & 31;
    int gn = nb + n;
    float4 v = make_float4(0,0,0,0);
    if (gn < N_NODESC) v = *(const float4*)&H[gn*HIDC + c4*4];
    ushort4 hi, lo;
    hi.x = f2bf(v.x); lo.x = f2bf(v.x - bf2f(hi.x));
    hi.y = f2bf(v.y); lo.y = f2bf(v.y - bf2f(hi.y));
    hi.z = f2bf(v.z); lo.z = f2bf(v.z - bf2f(hi.z));
    hi.w = f2bf(v.w); lo.w = f2bf(v.w - bf2f(hi.w));
    *(ushort4*)&Ah[n*136 + c4*4] = hi;
    *(ushort4*)&Al[n*136 + c4*4] = lo;
  }
  __syncthreads();

  const int lane = t & 63, wv = t >> 6;
  const int quad = lane >> 4, l16 = lane & 15;
  f32x4 acc[4];
#pragma unroll
  for (int ft = 0; ft < 4; ++ft) acc[ft] = (f32x4){0.f,0.f,0.f,0.f};

  const int arow = (wv*16 + l16)*136 + quad*8;
#pragma unroll
  for (int ks = 0; ks < 4; ++ks) {
    bf16x8 a_h = *(const bf16x8*)(const void*)&Ah[arow + ks*32];
    bf16x8 a_l = *(const bf16x8*)(const void*)&Al[arow + ks*32];
#pragma unroll
    for (int ft = 0; ft < 4; ++ft) {
      bf16x8 b = *(const bf16x8*)(const void*)&Wl[(ft*16 + l16)*136 + quad*8 + ks*32];
      acc[ft] = __builtin_amdgcn_mfma_f32_16x16x32_bf16(a_h, b, acc[ft], 0, 0, 0);
      acc[ft] = __builtin_amdgcn_mfma_f32_16x16x32_bf16(a_l, b, acc[ft], 0, 0, 0);
    }
  }

  float bb[4], gg[4], bee[4], w2v[4];
#pragma unroll
  for (int ft = 0; ft < 4; ++ft) {
    int f = ft*16 + l16;
    bb[ft] = b1[f]; gg[ft] = lng[f]; bee[ft] = lnb[f]; w2v[ft] = W2[f];
  }
  float s1[4] = {0,0,0,0}, s2[4] = {0,0,0,0};
#pragma unroll
  for (int ft = 0; ft < 4; ++ft)
#pragma unroll
    for (int r = 0; r < 4; ++r) {
      float v = fmaxf(acc[ft][r] + bb[ft], 0.f);
      acc[ft][r] = v; s1[r] += v; s2[r] += v*v;
    }
#pragma unroll
  for (int m = 1; m < 16; m <<= 1)
#pragma unroll
    for (int r = 0; r < 4; ++r) {
      s1[r] += __shfl_xor(s1[r], m);
      s2[r] += __shfl_xor(s2[r], m);
    }
  float pd[4];
#pragma unroll
  for (int r = 0; r < 4; ++r) {
    float mu = s1[r] * (1.f/64.f);
    float var = fmaxf(s2[r] * (1.f/64.f) - mu*mu, 0.f);
    float rs = rsqrtf(var + LN_EPSF);
    float p = 0.f;
#pragma unroll
    for (int ft = 0; ft < 4; ++ft)
      p += ((acc[ft][r] - mu)*rs*gg[ft] + bee[ft]) * w2v[ft];
    pd[r] = p;
  }
#pragma unroll
  for (int m = 1; m < 16; m <<= 1)
#pragma unroll
    for (int r = 0; r < 4; ++r) pd[r] += __shfl_xor(pd[r], m);
  if (l16 == 0) {
    float b2v = b2[0];
#pragma unroll
    for (int r = 0; r < 4; ++r) {
      int node = nb + wv*16 + quad*4 + r;
      if (node < N_NODESC) {
        float gv = pd[r] + b2v;
        gateb[node] = gv;
        atomicMax(&gmaxu[batch[node]], ord_enc(gv));
      }
    }
  }
}

// ---------- segmented softmax-weighted pooling ----------
__global__ __launch_bounds__(256) void pool_kernel(const float* __restrict__ H,
    const float* __restrict__ gateb, const int* __restrict__ gstart,
    const unsigned* __restrict__ gmaxu, float* __restrict__ S,
    float* __restrict__ denom) {
  const int g    = blockIdx.x / POOL_SPLIT;
  const int part = blockIdx.x % POOL_SPLIT;
  const int s0 = gstart[g], s1 = gstart[g+1];
  const int cnt = s1 - s0;
  const int chunk = (cnt + POOL_SPLIT - 1) / POOL_SPLIT;
  int lo = s0 + part * chunk;
  int hi = lo + chunk; if (hi > s1) hi = s1;
  const int t = threadIdx.x;
  const int j = t & 127;   // feature
  const int v = t >> 7;    // node subgroup 0..1
  const float gm = ord_dec(gmaxu[g]);
  float acc = 0.f, de = 0.f;
  for (int n = lo + v; n < hi; n += 2) {
    float e = expf(gateb[n] - gm);
    acc += e * H[n*HIDC + j];
    if (j == 0) de += e;
  }
  __shared__ float sacc[256];
  __shared__ float sden[2];
  sacc[t] = acc;
  if (j == 0) sden[v] = de;
  __syncthreads();
  if (t < 128) {
    float s = sacc[t] + sacc[t+128];
    atomicAdd(&S[g*HIDC + t], s);
  }
  if (t == 0) atomicAdd(&denom[g], sden[0] + sden[1]);
}

// ---------- head MLP per graph ----------
__global__ __launch_bounds__(64) void head_kernel(const float* __restrict__ S,
    const float* __restrict__ denom, const float* __restrict__ W1,
    const float* __restrict__ b1, const float* __restrict__ g,
    const float* __restrict__ be, const float* __restrict__ W2,
    const float* __restrict__ b2, float* __restrict__ out) {
  const int gr = blockIdx.x;
  const int j = threadIdx.x;
  const float inv = 1.0f / denom[gr];
  float v = b1[j];
  for (int k = 0; k < HIDC; ++k) v += (S[gr*HIDC + k] * inv) * W1[j*HIDC + k];
  v = fmaxf(v, 0.f);
  float s1 = v, s2 = v*v;
  for (int off = 32; off; off >>= 1) { s1 += __shfl_xor(s1, off); s2 += __shfl_xor(s2, off); }
  float mu = s1 * (1.f/64.f);
  float var = fmaxf(s2 * (1.f/64.f) - mu*mu, 0.f);
  float rs = rsqrtf(var + LN_EPSF);
  float z = (v-mu)*rs*g[j] + be[j];
  float p = z * W2[j];
  for (int off = 32; off; off >>= 1) p += __shfl_xor(p, off);
  if (j == 0) out[gr] = p + b2[0];
}

// ---------- launch ----------
extern "C" void kernel_launch(void* const* d_in, const int* in_sizes, int n_in,
                              void* d_out, int out_size, void* d_ws, size_t ws_size,
                              hipStream_t stream) {
  (void)in_sizes; (void)n_in; (void)out_size; (void)ws_size;
  const float* x     = (const float*)d_in[0];
  const int*   ei    = (const int*)d_in[1];
  const int*   batch = (const int*)d_in[2];
  const float* aW1 = (const float*)d_in[3];
  const float* ab1 = (const float*)d_in[4];
  const float* ag  = (const float*)d_in[5];
  const float* abe = (const float*)d_in[6];
  const float* aW2 = (const float*)d_in[7];
  const float* ab2 = (const float*)d_in[8];
  const float* oW1 = (const float*)d_in[9];
  const float* ob1 = (const float*)d_in[10];
  const float* og  = (const float*)d_in[11];
  const float* obe = (const float*)d_in[12];
  const float* oW2 = (const float*)d_in[13];
  const float* ob2 = (const float*)d_in[14];
  const float* ninW = (const float*)d_in[15];
  const float* ninb = (const float*)d_in[16];
  const float* cW1 = (const float*)d_in[17];
  const float* cb1 = (const float*)d_in[18];
  const float* cg  = (const float*)d_in[19];
  const float* cbe = (const float*)d_in[20];
  const float* cW2 = (const float*)d_in[21];
  const float* cb2 = (const float*)d_in[22];
  const float* eps = (const float*)d_in[23];
  const float* lng = (const float*)d_in[24];
  const float* lnb = (const float*)d_in[25];
  const float* gW1 = (const float*)d_in[26];
  const float* gb1 = (const float*)d_in[27];
  const float* gg  = (const float*)d_in[28];
  const float* gbe = (const float*)d_in[29];
  const float* gW2 = (const float*)d_in[30];
  const float* gb2 = (const float*)d_in[31];
  const float* hW1 = (const float*)d_in[32];
  const float* hb1 = (const float*)d_in[33];
  const float* hg  = (const float*)d_in[34];
  const float* hbe = (const float*)d_in[35];
  const float* hW2 = (const float*)d_in[36];
  const float* hb2 = (const float*)d_in[37];

  char* ws = (char*)d_ws;
  float* H     = (float*)(ws + 0);            // 25,600,000 B
  float* T     = (float*)(ws + 25600000);     // 25,600,000 B
  float* M     = (float*)(ws + 51200000);     // 25,600,000 B
  float* gateb = (float*)(ws + 76800000);     // 200,000 B
  float* S     = (float*)(ws + 77000000);     // 32,768 B
  float* denom = (float*)(ws + 77032768);     // 256 B
  unsigned* gmaxu = (unsigned*)(ws + 77033024); // 256 B
  int* deg     = (int*)(ws + 77033280);       // 200,000 B
  int* rowptr  = (int*)(ws + 77233280);       // 200,004 B
  int* cursor  = (int*)(ws + 77433284);       // 200,000 B
  int* esrc    = (int*)(ws + 77633284);       // 2,560,000 B
  int* gstart  = cursor;  // alias: cursor is dead after scatter_kernel

  hipMemsetAsync(deg, 0, 200000, stream);
  hipMemsetAsync(S, 0, 33280, stream);  // S + denom + gmaxu contiguous

  const int egrid = (N_EDGESC + 255) / 256;
  hist_kernel<<<egrid, 256, 0, stream>>>(ei, deg);
  scan_kernel<<<1, 1024, 0, stream>>>(deg, rowptr, cursor);
  scatter_kernel<<<egrid, 256, 0, stream>>>(ei, cursor, esrc);
  gbound_kernel<<<(N_NODESC + 255) / 256, 256, 0, stream>>>(batch, gstart);

  const int ngrid64 = (N_NODESC + 63) / 64;
  enc_kernel<<<ngrid64, 128, 0, stream>>>(x, aW1, ab1, ag, abe, aW2, ab2,
                                          oW1, ob1, og, obe, oW2, ob2,
                                          ninW, ninb, H);
  for (int l = 0; l < 3; ++l) {
    agg_kernel<<<(N_NODESC + 3) / 4, 128, 0, stream>>>(H, rowptr, esrc, eps + l, M);
    gemm_mfma_kernel<<<ngrid64, 256, 0, stream>>>(M, cW1 + l*HIDC*HIDC, cb1 + l*HIDC,
                                                  cg + l*HIDC, cbe + l*HIDC, nullptr, T);
    gemm_mfma_kernel<<<ngrid64, 256, 0, stream>>>(T, cW2 + l*HIDC*HIDC, cb2 + l*HIDC,
                                                  lng + l*HIDC, lnb + l*HIDC, H, H);
  }
  gate_mfma_kernel<<<ngrid64, 256, 0, stream>>>(H, gW1, gb1, gg, gbe, gW2, gb2,
                                                batch, gateb, gmaxu);
  pool_kernel<<<N_GRAPHSC * POOL_SPLIT, 256, 0, stream>>>(H, gateb, gstart, gmaxu, S, denom);
  head_kernel<<<N_GRAPHSC, 64, 0, stream>>>(S, denom, hW1, hb1, hg, hbe, hW2, hb2,
                                            (float*)d_out);
}

// Round 4
// 664.698 us; speedup vs baseline: 1.9352x; 1.2793x over previous
//
#include <hip/hip_runtime.h>

#define N_NODESC 50000
#define N_EDGESC 640000
#define N_GRAPHSC 64
#define HIDC 128
#define LN_EPSF 1e-5f
#define POOL_SPLIT 16

typedef short bf16x8 __attribute__((ext_vector_type(8)));
typedef float f32x4 __attribute__((ext_vector_type(4)));

// ---------- helpers ----------
static __device__ __forceinline__ unsigned ord_enc(float f) {
  unsigned u = __float_as_uint(f);
  return (u & 0x80000000u) ? ~u : (u | 0x80000000u);
}
static __device__ __forceinline__ float ord_dec(unsigned u) {
  return __uint_as_float((u & 0x80000000u) ? (u ^ 0x80000000u) : ~u);
}
static __device__ __forceinline__ void f4add(float4& a, const float4 b) {
  a.x += b.x; a.y += b.y; a.z += b.z; a.w += b.w;
}
// fp32 -> bf16 bits, round-to-nearest-even
static __device__ __forceinline__ unsigned short f2bf(float x) {
  unsigned u = __float_as_uint(x);
  u += 0x7fffu + ((u >> 16) & 1u);
  return (unsigned short)(u >> 16);
}
static __device__ __forceinline__ float bf2f(unsigned short b) {
  return __uint_as_float(((unsigned)b) << 16);
}

// small 3->16 relu LN 16->16 MLP (encoder preprocessing), one thread per node
static __device__ __forceinline__ void mlp16(float in0, float in1, float in2,
    const float* __restrict__ W1, const float* __restrict__ b1,
    const float* __restrict__ g, const float* __restrict__ be,
    const float* __restrict__ W2, const float* __restrict__ b2,
    float* __restrict__ out) {
  float h[16];
  float s1 = 0.f, s2 = 0.f;
#pragma unroll
  for (int j = 0; j < 16; ++j) {
    float v = b1[j] + W1[j*3+0]*in0 + W1[j*3+1]*in1 + W1[j*3+2]*in2;
    v = fmaxf(v, 0.f);
    h[j] = v; s1 += v; s2 += v*v;
  }
  float mu = s1 * (1.f/16.f);
  float var = fmaxf(s2 * (1.f/16.f) - mu*mu, 0.f);
  float rs = rsqrtf(var + LN_EPSF);
  float z[16];
#pragma unroll
  for (int j = 0; j < 16; ++j) z[j] = (h[j]-mu)*rs*g[j] + be[j];
#pragma unroll
  for (int j = 0; j < 16; ++j) {
    float v = b2[j];
#pragma unroll
    for (int k = 0; k < 16; ++k) v += W2[j*16+k]*z[k];
    out[j] = v;
  }
}

// ---------- CSR build ----------
__global__ __launch_bounds__(256) void hist_kernel(const int* __restrict__ ei, int* __restrict__ deg) {
  int e = blockIdx.x * 256 + threadIdx.x;
  if (e < N_EDGESC) atomicAdd(&deg[ei[N_EDGESC + e]], 1);
}

__global__ __launch_bounds__(1024) void scan_kernel(const int* __restrict__ deg,
                                                    int* __restrict__ rowptr,
                                                    int* __restrict__ cursor) {
  __shared__ int ps[1024];
  const int t = threadIdx.x;
  const int CH = 49;  // ceil(50000/1024)
  int start = t * CH;
  int end = start + CH; if (end > N_NODESC) end = N_NODESC;
  int s = 0;
  for (int i = start; i < end; ++i) s += deg[i];
  ps[t] = s;
  __syncthreads();
  for (int off = 1; off < 1024; off <<= 1) {
    int v = (t >= off) ? ps[t - off] : 0;
    __syncthreads();
    ps[t] += v;
    __syncthreads();
  }
  int run = ps[t] - s;  // exclusive prefix
  for (int i = start; i < end; ++i) {
    rowptr[i] = run; cursor[i] = run;
    run += deg[i];
  }
  if (t == 1023) rowptr[N_NODESC] = run;
}

__global__ __launch_bounds__(256) void scatter_kernel(const int* __restrict__ ei,
                                                      int* __restrict__ cursor,
                                                      int* __restrict__ esrc) {
  int e = blockIdx.x * 256 + threadIdx.x;
  if (e < N_EDGESC) {
    int d = ei[N_EDGESC + e];
    int slot = atomicAdd(&cursor[d], 1);
    esrc[slot] = ei[e];
  }
}

// ---------- graph boundary detection (batch is sorted) ----------
__global__ __launch_bounds__(256) void gbound_kernel(const int* __restrict__ batch,
                                                     int* __restrict__ gstart) {
  int i = blockIdx.x * 256 + threadIdx.x;
  if (i >= N_NODESC) return;
  int b = batch[i];
  int prev = (i == 0) ? -1 : batch[i-1];
  for (int g = prev + 1; g <= b; ++g) gstart[g] = i;
  if (i == N_NODESC - 1) {
    for (int g = b + 1; g <= N_GRAPHSC; ++g) gstart[g] = N_NODESC;
  }
}

// ---------- encoder: small MLPs + 45->128 projection ----------
__global__ __launch_bounds__(128) void enc_kernel(
    const float* __restrict__ x,
    const float* __restrict__ aW1, const float* __restrict__ ab1,
    const float* __restrict__ ag,  const float* __restrict__ abe,
    const float* __restrict__ aW2, const float* __restrict__ ab2,
    const float* __restrict__ oW1, const float* __restrict__ ob1,
    const float* __restrict__ og,  const float* __restrict__ obe,
    const float* __restrict__ oW2, const float* __restrict__ ob2,
    const float* __restrict__ ninW, const float* __restrict__ ninb,
    float* __restrict__ H) {
  __shared__ float sa[48*68];   // [k][n], n<64 pad 68
  __shared__ float sw[48*132];  // [k][f], f<128 pad 132
  const int t = threadIdx.x;
  const int lane = t & 63, w = t >> 6;
  const int nb = blockIdx.x * 64;

  if (t < 64) {
    float in45[45];
    const int gn = nb + t;
    if (gn < N_NODESC) {
      const float* xr = x + gn * 19;
#pragma unroll
      for (int k = 0; k < 9; ++k) in45[k] = xr[k];
#pragma unroll
      for (int k = 0; k < 4; ++k) in45[9+k] = xr[15+k];
      mlp16(xr[9], xr[10], xr[11], aW1, ab1, ag, abe, aW2, ab2, &in45[13]);
      mlp16(xr[12], xr[13], xr[14], oW1, ob1, og, obe, oW2, ob2, &in45[29]);
    } else {
#pragma unroll
      for (int k = 0; k < 45; ++k) in45[k] = 0.f;
    }
#pragma unroll
    for (int k = 0; k < 45; ++k) sa[k*68 + t] = in45[k];
#pragma unroll
    for (int k = 45; k < 48; ++k) sa[k*68 + t] = 0.f;
  }
  for (int idx = t; idx < 48*128; idx += 128) {
    int k = idx >> 7, f = idx & 127;
    sw[k*132 + f] = (k < 45) ? ninW[f*45 + k] : 0.f;
  }
  __syncthreads();

  const int n0 = (lane & 7) * 8;
  const int f0 = ((lane >> 3) << 3) + w * 64;
  float acc[8][8];
#pragma unroll
  for (int i = 0; i < 8; ++i)
#pragma unroll
    for (int j = 0; j < 8; ++j) acc[i][j] = 0.f;

#pragma unroll 4
  for (int k = 0; k < 48; ++k) {
    float av[8], wv[8];
    float4 a0 = *(const float4*)&sa[k*68 + n0];
    float4 a1 = *(const float4*)&sa[k*68 + n0 + 4];
    float4 w0 = *(const float4*)&sw[k*132 + f0];
    float4 w1 = *(const float4*)&sw[k*132 + f0 + 4];
    av[0]=a0.x; av[1]=a0.y; av[2]=a0.z; av[3]=a0.w;
    av[4]=a1.x; av[5]=a1.y; av[6]=a1.z; av[7]=a1.w;
    wv[0]=w0.x; wv[1]=w0.y; wv[2]=w0.z; wv[3]=w0.w;
    wv[4]=w1.x; wv[5]=w1.y; wv[6]=w1.z; wv[7]=w1.w;
#pragma unroll
    for (int i = 0; i < 8; ++i)
#pragma unroll
      for (int j = 0; j < 8; ++j) acc[i][j] += av[i]*wv[j];
  }
  float bb[8];
#pragma unroll
  for (int j = 0; j < 8; ++j) bb[j] = ninb[f0+j];
#pragma unroll
  for (int i = 0; i < 8; ++i) {
    int gn = nb + n0 + i;
    if (gn < N_NODESC) {
      float o[8];
#pragma unroll
      for (int j = 0; j < 8; ++j) o[j] = acc[i][j] + bb[j];
      *(float4*)&H[gn*HIDC + f0]     = make_float4(o[0],o[1],o[2],o[3]);
      *(float4*)&H[gn*HIDC + f0 + 4] = make_float4(o[4],o[5],o[6],o[7]);
    }
  }
}

// ---------- aggregation: M = (1+eps)*H + sum_{src in bucket(dst)} H[src] ----------
__global__ __launch_bounds__(128) void agg_kernel(const float* __restrict__ H,
    const int* __restrict__ rowptr, const int* __restrict__ esrc,
    const float* __restrict__ epsp, float* __restrict__ M) {
  const int t = threadIdx.x;
  const int c = t & 31;    // float4 column (128 floats = 32 float4)
  const int v = t >> 5;    // node sub-index 0..3
  const int node = blockIdx.x * 4 + v;
  if (node >= N_NODESC) return;
  const float4* H4 = (const float4*)H;
  float4 h = H4[node*32 + c];
  const float e1 = 1.0f + epsp[0];
  float4 a0 = make_float4(0,0,0,0), a1 = a0, a2 = a0, a3 = a0;
  int s = rowptr[node];
  const int e = rowptr[node+1];
  for (; s + 4 <= e; s += 4) {
    int i0 = esrc[s], i1 = esrc[s+1], i2 = esrc[s+2], i3 = esrc[s+3];
    float4 x0 = H4[i0*32+c], x1 = H4[i1*32+c], x2 = H4[i2*32+c], x3 = H4[i3*32+c];
    f4add(a0,x0); f4add(a1,x1); f4add(a2,x2); f4add(a3,x3);
  }
  for (; s < e; ++s) f4add(a0, H4[esrc[s]*32+c]);
  float4 m;
  m.x = e1*h.x + a0.x+a1.x+a2.x+a3.x;
  m.y = e1*h.y + a0.y+a1.y+a2.y+a3.y;
  m.z = e1*h.z + a0.z+a1.z+a2.z+a3.z;
  m.w = e1*h.w + a0.w+a1.w+a2.w+a3.w;
  ((float4*)M)[node*32 + c] = m;
}

// ---------- MFMA GEMM: OUT[64 x 128] tile = IN @ W^T, + bias + relu + LN (+resid) ----------
__global__ __launch_bounds__(256, 2) void gemm_mfma_kernel(
    const float* __restrict__ IN, const float* __restrict__ W,
    const float* __restrict__ bias, const float* __restrict__ lng,
    const float* __restrict__ lnb, const float* __restrict__ resid,
    float* __restrict__ OUT) {
  __shared__ unsigned short Ah[64*136];
  __shared__ unsigned short Al[64*136];
  __shared__ unsigned short Wl[128*136];
  const int t = threadIdx.x;
  const int nb = blockIdx.x * 64;
  // stage W (128x128 fp32 -> bf16)
#pragma unroll
  for (int i = 0; i < 16; ++i) {
    int q = t + i*256;
    int f = q >> 5, c4 = q & 31;
    float4 v = *(const float4*)&W[f*HIDC + c4*4];
    ushort4 h;
    h.x = f2bf(v.x); h.y = f2bf(v.y); h.z = f2bf(v.z); h.w = f2bf(v.w);
    *(ushort4*)&Wl[f*136 + c4*4] = h;
  }
  // stage A (64x128 fp32 -> bf16 hi + lo)
#pragma unroll
  for (int i = 0; i < 8; ++i) {
    int q = t + i*256;
    int n = q >> 5, c4 = q & 31;
    int gn = nb + n;
    float4 v = make_float4(0,0,0,0);
    if (gn < N_NODESC) v = *(const float4*)&IN[gn*HIDC + c4*4];
    ushort4 hi, lo;
    hi.x = f2bf(v.x); lo.x = f2bf(v.x - bf2f(hi.x));
    hi.y = f2bf(v.y); lo.y = f2bf(v.y - bf2f(hi.y));
    hi.z = f2bf(v.z); lo.z = f2bf(v.z - bf2f(hi.z));
    hi.w = f2bf(v.w); lo.w = f2bf(v.w - bf2f(hi.w));
    *(ushort4*)&Ah[n*136 + c4*4] = hi;
    *(ushort4*)&Al[n*136 + c4*4] = lo;
  }
  __syncthreads();

  const int lane = t & 63, wv = t >> 6;
  const int quad = lane >> 4, l16 = lane & 15;
  f32x4 acc[8];
#pragma unroll
  for (int ft = 0; ft < 8; ++ft) acc[ft] = (f32x4){0.f,0.f,0.f,0.f};

  const int arow = (wv*16 + l16)*136 + quad*8;
#pragma unroll
  for (int ks = 0; ks < 4; ++ks) {
    bf16x8 a_h = *(const bf16x8*)(const void*)&Ah[arow + ks*32];
    bf16x8 a_l = *(const bf16x8*)(const void*)&Al[arow + ks*32];
#pragma unroll
    for (int ft = 0; ft < 8; ++ft) {
      bf16x8 b = *(const bf16x8*)(const void*)&Wl[(ft*16 + l16)*136 + quad*8 + ks*32];
      acc[ft] = __builtin_amdgcn_mfma_f32_16x16x32_bf16(a_h, b, acc[ft], 0, 0, 0);
      acc[ft] = __builtin_amdgcn_mfma_f32_16x16x32_bf16(a_l, b, acc[ft], 0, 0, 0);
    }
  }

  // epilogue: bias + relu + LN(128) + optional residual.
  float bb[8], gg[8], bee[8];
#pragma unroll
  for (int ft = 0; ft < 8; ++ft) {
    int f = ft*16 + l16;
    bb[ft] = bias[f]; gg[ft] = lng[f]; bee[ft] = lnb[f];
  }
  float s1[4] = {0,0,0,0}, s2[4] = {0,0,0,0};
#pragma unroll
  for (int ft = 0; ft < 8; ++ft)
#pragma unroll
    for (int r = 0; r < 4; ++r) {
      float v = fmaxf(acc[ft][r] + bb[ft], 0.f);
      acc[ft][r] = v; s1[r] += v; s2[r] += v*v;
    }
#pragma unroll
  for (int m = 1; m < 16; m <<= 1)
#pragma unroll
    for (int r = 0; r < 4; ++r) {
      s1[r] += __shfl_xor(s1[r], m);
      s2[r] += __shfl_xor(s2[r], m);
    }
  float mu[4], rs[4];
#pragma unroll
  for (int r = 0; r < 4; ++r) {
    mu[r] = s1[r] * (1.f/128.f);
    float var = fmaxf(s2[r] * (1.f/128.f) - mu[r]*mu[r], 0.f);
    rs[r] = rsqrtf(var + LN_EPSF);
  }
#pragma unroll
  for (int r = 0; r < 4; ++r) {
    int node = nb + wv*16 + quad*4 + r;
    if (node >= N_NODESC) continue;
    const int base = node*HIDC + l16;
#pragma unroll
    for (int ft = 0; ft < 8; ++ft) {
      float o = (acc[ft][r] - mu[r])*rs[r]*gg[ft] + bee[ft];
      if (resid) o += resid[base + ft*16];
      OUT[base + ft*16] = o;
    }
  }
}

// ---------- MFMA gate: per node z = LN(relu(H@W1^T+b1)); gate = z.W2 + b2 ----------
// NO atomics here: per-node atomicMax onto 64 graph slots serializes ~780 deep
// (measured ~200us). gmax is computed by a segmented kernel afterwards.
__global__ __launch_bounds__(256, 2) void gate_mfma_kernel(
    const float* __restrict__ H, const float* __restrict__ W1,
    const float* __restrict__ b1, const float* __restrict__ lng,
    const float* __restrict__ lnb, const float* __restrict__ W2,
    const float* __restrict__ b2,
    float* __restrict__ gateb) {
  __shared__ unsigned short Ah[64*136];
  __shared__ unsigned short Al[64*136];
  __shared__ unsigned short Wl[64*136];
  const int t = threadIdx.x;
  const int nb = blockIdx.x * 64;
#pragma unroll
  for (int i = 0; i < 8; ++i) {
    int q = t + i*256;
    int f = q >> 5, c4 = q & 31;
    float4 v = *(const float4*)&W1[f*HIDC + c4*4];
    ushort4 h;
    h.x = f2bf(v.x); h.y = f2bf(v.y); h.z = f2bf(v.z); h.w = f2bf(v.w);
    *(ushort4*)&Wl[f*136 + c4*4] = h;
  }
#pragma unroll
  for (int i = 0; i < 8; ++i) {
    int q = t + i*256;
    int n = q >> 5, c4 = q & 31;
    int gn = nb + n;
    float4 v = make_float4(0,0,0,0);
    if (gn < N_NODESC) v = *(const float4*)&H[gn*HIDC + c4*4];
    ushort4 hi, lo;
    hi.x = f2bf(v.x); lo.x = f2bf(v.x - bf2f(hi.x));
    hi.y = f2bf(v.y); lo.y = f2bf(v.y - bf2f(hi.y));
    hi.z = f2bf(v.z); lo.z = f2bf(v.z - bf2f(hi.z));
    hi.w = f2bf(v.w); lo.w = f2bf(v.w - bf2f(hi.w));
    *(ushort4*)&Ah[n*136 + c4*4] = hi;
    *(ushort4*)&Al[n*136 + c4*4] = lo;
  }
  __syncthreads();

  const int lane = t & 63, wv = t >> 6;
  const int quad = lane >> 4, l16 = lane & 15;
  f32x4 acc[4];
#pragma unroll
  for (int ft = 0; ft < 4; ++ft) acc[ft] = (f32x4){0.f,0.f,0.f,0.f};

  const int arow = (wv*16 + l16)*136 + quad*8;
#pragma unroll
  for (int ks = 0; ks < 4; ++ks) {
    bf16x8 a_h = *(const bf16x8*)(const void*)&Ah[arow + ks*32];
    bf16x8 a_l = *(const bf16x8*)(const void*)&Al[arow + ks*32];
#pragma unroll
    for (int ft = 0; ft < 4; ++ft) {
      bf16x8 b = *(const bf16x8*)(const void*)&Wl[(ft*16 + l16)*136 + quad*8 + ks*32];
      acc[ft] = __builtin_amdgcn_mfma_f32_16x16x32_bf16(a_h, b, acc[ft], 0, 0, 0);
      acc[ft] = __builtin_amdgcn_mfma_f32_16x16x32_bf16(a_l, b, acc[ft], 0, 0, 0);
    }
  }

  float bb[4], gg[4], bee[4], w2v[4];
#pragma unroll
  for (int ft = 0; ft < 4; ++ft) {
    int f = ft*16 + l16;
    bb[ft] = b1[f]; gg[ft] = lng[f]; bee[ft] = lnb[f]; w2v[ft] = W2[f];
  }
  float s1[4] = {0,0,0,0}, s2[4] = {0,0,0,0};
#pragma unroll
  for (int ft = 0; ft < 4; ++ft)
#pragma unroll
    for (int r = 0; r < 4; ++r) {
      float v = fmaxf(acc[ft][r] + bb[ft], 0.f);
      acc[ft][r] = v; s1[r] += v; s2[r] += v*v;
    }
#pragma unroll
  for (int m = 1; m < 16; m <<= 1)
#pragma unroll
    for (int r = 0; r < 4; ++r) {
      s1[r] += __shfl_xor(s1[r], m);
      s2[r] += __shfl_xor(s2[r], m);
    }
  float pd[4];
#pragma unroll
  for (int r = 0; r < 4; ++r) {
    float mu = s1[r] * (1.f/64.f);
    float var = fmaxf(s2[r] * (1.f/64.f) - mu*mu, 0.f);
    float rs = rsqrtf(var + LN_EPSF);
    float p = 0.f;
#pragma unroll
    for (int ft = 0; ft < 4; ++ft)
      p += ((acc[ft][r] - mu)*rs*gg[ft] + bee[ft]) * w2v[ft];
    pd[r] = p;
  }
#pragma unroll
  for (int m = 1; m < 16; m <<= 1)
#pragma unroll
    for (int r = 0; r < 4; ++r) pd[r] += __shfl_xor(pd[r], m);
  if (l16 == 0) {
    float b2v = b2[0];
#pragma unroll
    for (int r = 0; r < 4; ++r) {
      int node = nb + wv*16 + quad*4 + r;
      if (node < N_NODESC) gateb[node] = pd[r] + b2v;
    }
  }
}

// ---------- segmented per-graph max of gateb (16 blocks/graph, 1 atomic each) ----------
__global__ __launch_bounds__(256) void gmax_kernel(const float* __restrict__ gateb,
    const int* __restrict__ gstart, unsigned* __restrict__ gmaxu) {
  const int g    = blockIdx.x / POOL_SPLIT;
  const int part = blockIdx.x % POOL_SPLIT;
  const int s0 = gstart[g], s1 = gstart[g+1];
  const int cnt = s1 - s0;
  const int chunk = (cnt + POOL_SPLIT - 1) / POOL_SPLIT;
  int lo = s0 + part * chunk;
  int hi = lo + chunk; if (hi > s1) hi = s1;
  const int t = threadIdx.x;
  float m = -3.4e38f;
  for (int n = lo + t; n < hi; n += 256) m = fmaxf(m, gateb[n]);
  __shared__ float sm[256];
  sm[t] = m;
  __syncthreads();
#pragma unroll
  for (int off = 128; off >= 1; off >>= 1) {
    if (t < off) sm[t] = fmaxf(sm[t], sm[t + off]);
    __syncthreads();
  }
  if (t == 0 && sm[0] > -3.4e38f) atomicMax(&gmaxu[g], ord_enc(sm[0]));
}

// ---------- segmented softmax-weighted pooling ----------
__global__ __launch_bounds__(256) void pool_kernel(const float* __restrict__ H,
    const float* __restrict__ gateb, const int* __restrict__ gstart,
    const unsigned* __restrict__ gmaxu, float* __restrict__ S,
    float* __restrict__ denom) {
  const int g    = blockIdx.x / POOL_SPLIT;
  const int part = blockIdx.x % POOL_SPLIT;
  const int s0 = gstart[g], s1 = gstart[g+1];
  const int cnt = s1 - s0;
  const int chunk = (cnt + POOL_SPLIT - 1) / POOL_SPLIT;
  int lo = s0 + part * chunk;
  int hi = lo + chunk; if (hi > s1) hi = s1;
  const int t = threadIdx.x;
  const int j = t & 127;   // feature
  const int v = t >> 7;    // node subgroup 0..1
  const float gm = ord_dec(gmaxu[g]);
  float acc = 0.f, de = 0.f;
  for (int n = lo + v; n < hi; n += 2) {
    float e = expf(gateb[n] - gm);
    acc += e * H[n*HIDC + j];
    if (j == 0) de += e;
  }
  __shared__ float sacc[256];
  __shared__ float sden[2];
  sacc[t] = acc;
  if (j == 0) sden[v] = de;
  __syncthreads();
  if (t < 128) {
    float s = sacc[t] + sacc[t+128];
    atomicAdd(&S[g*HIDC + t], s);
  }
  if (t == 0) atomicAdd(&denom[g], sden[0] + sden[1]);
}

// ---------- head MLP per graph ----------
__global__ __launch_bounds__(64) void head_kernel(const float* __restrict__ S,
    const float* __restrict__ denom, const float* __restrict__ W1,
    const float* __restrict__ b1, const float* __restrict__ g,
    const float* __restrict__ be, const float* __restrict__ W2,
    const float* __restrict__ b2, float* __restrict__ out) {
  const int gr = blockIdx.x;
  const int j = threadIdx.x;
  const float inv = 1.0f / denom[gr];
  float v = b1[j];
  for (int k = 0; k < HIDC; ++k) v += (S[gr*HIDC + k] * inv) * W1[j*HIDC + k];
  v = fmaxf(v, 0.f);
  float s1 = v, s2 = v*v;
  for (int off = 32; off; off >>= 1) { s1 += __shfl_xor(s1, off); s2 += __shfl_xor(s2, off); }
  float mu = s1 * (1.f/64.f);
  float var = fmaxf(s2 * (1.f/64.f) - mu*mu, 0.f);
  float rs = rsqrtf(var + LN_EPSF);
  float z = (v-mu)*rs*g[j] + be[j];
  float p = z * W2[j];
  for (int off = 32; off; off >>= 1) p += __shfl_xor(p, off);
  if (j == 0) out[gr] = p + b2[0];
}

// ---------- launch ----------
extern "C" void kernel_launch(void* const* d_in, const int* in_sizes, int n_in,
                              void* d_out, int out_size, void* d_ws, size_t ws_size,
                              hipStream_t stream) {
  (void)in_sizes; (void)n_in; (void)out_size; (void)ws_size;
  const float* x     = (const float*)d_in[0];
  const int*   ei    = (const int*)d_in[1];
  const int*   batch = (const int*)d_in[2];
  const float* aW1 = (const float*)d_in[3];
  const float* ab1 = (const float*)d_in[4];
  const float* ag  = (const float*)d_in[5];
  const float* abe = (const float*)d_in[6];
  const float* aW2 = (const float*)d_in[7];
  const float* ab2 = (const float*)d_in[8];
  const float* oW1 = (const float*)d_in[9];
  const float* ob1 = (const float*)d_in[10];
  const float* og  = (const float*)d_in[11];
  const float* obe = (const float*)d_in[12];
  const float* oW2 = (const float*)d_in[13];
  const float* ob2 = (const float*)d_in[14];
  const float* ninW = (const float*)d_in[15];
  const float* ninb = (const float*)d_in[16];
  const float* cW1 = (const float*)d_in[17];
  const float* cb1 = (const float*)d_in[18];
  const float* cg  = (const float*)d_in[19];
  const float* cbe = (const float*)d_in[20];
  const float* cW2 = (const float*)d_in[21];
  const float* cb2 = (const float*)d_in[22];
  const float* eps = (const float*)d_in[23];
  const float* lng = (const float*)d_in[24];
  const float* lnb = (const float*)d_in[25];
  const float* gW1 = (const float*)d_in[26];
  const float* gb1 = (const float*)d_in[27];
  const float* gg  = (const float*)d_in[28];
  const float* gbe = (const float*)d_in[29];
  const float* gW2 = (const float*)d_in[30];
  const float* gb2 = (const float*)d_in[31];
  const float* hW1 = (const float*)d_in[32];
  const float* hb1 = (const float*)d_in[33];
  const float* hg  = (const float*)d_in[34];
  const float* hbe = (const float*)d_in[35];
  const float* hW2 = (const float*)d_in[36];
  const float* hb2 = (const float*)d_in[37];

  char* ws = (char*)d_ws;
  float* H     = (float*)(ws + 0);            // 25,600,000 B
  float* T     = (float*)(ws + 25600000);     // 25,600,000 B
  float* M     = (float*)(ws + 51200000);     // 25,600,000 B
  float* gateb = (float*)(ws + 76800000);     // 200,000 B
  float* S     = (float*)(ws + 77000000);     // 32,768 B
  float* denom = (float*)(ws + 77032768);     // 256 B
  unsigned* gmaxu = (unsigned*)(ws + 77033024); // 256 B
  int* deg     = (int*)(ws + 77033280);       // 200,000 B
  int* rowptr  = (int*)(ws + 77233280);       // 200,004 B
  int* cursor  = (int*)(ws + 77433284);       // 200,000 B
  int* esrc    = (int*)(ws + 77633284);       // 2,560,000 B
  int* gstart  = cursor;  // alias: cursor is dead after scatter_kernel

  hipMemsetAsync(deg, 0, 200000, stream);
  hipMemsetAsync(S, 0, 33280, stream);  // S + denom + gmaxu contiguous

  const int egrid = (N_EDGESC + 255) / 256;
  hist_kernel<<<egrid, 256, 0, stream>>>(ei, deg);
  scan_kernel<<<1, 1024, 0, stream>>>(deg, rowptr, cursor);
  scatter_kernel<<<egrid, 256, 0, stream>>>(ei, cursor, esrc);
  gbound_kernel<<<(N_NODESC + 255) / 256, 256, 0, stream>>>(batch, gstart);

  const int ngrid64 = (N_NODESC + 63) / 64;
  enc_kernel<<<ngrid64, 128, 0, stream>>>(x, aW1, ab1, ag, abe, aW2, ab2,
                                          oW1, ob1, og, obe, oW2, ob2,
                                          ninW, ninb, H);
  for (int l = 0; l < 3; ++l) {
    agg_kernel<<<(N_NODESC + 3) / 4, 128, 0, stream>>>(H, rowptr, esrc, eps + l, M);
    gemm_mfma_kernel<<<ngrid64, 256, 0, stream>>>(M, cW1 + l*HIDC*HIDC, cb1 + l*HIDC,
                                                  cg + l*HIDC, cbe + l*HIDC, nullptr, T);
    gemm_mfma_kernel<<<ngrid64, 256, 0, stream>>>(T, cW2 + l*HIDC*HIDC, cb2 + l*HIDC,
                                                  lng + l*HIDC, lnb + l*HIDC, H, H);
  }
  gate_mfma_kernel<<<ngrid64, 256, 0, stream>>>(H, gW1, gb1, gg, gbe, gW2, gb2, gateb);
  gmax_kernel<<<N_GRAPHSC * POOL_SPLIT, 256, 0, stream>>>(gateb, gstart, gmaxu);
  pool_kernel<<<N_GRAPHSC * POOL_SPLIT, 256, 0, stream>>>(H, gateb, gstart, gmaxu, S, denom);
  head_kernel<<<N_GRAPHSC, 64, 0, stream>>>(S, denom, hW1, hb1, hg, hbe, hW2, hb2,
                                            (float*)d_out);
}

// Round 5
// 564.401 us; speedup vs baseline: 2.2792x; 1.1777x over previous
//
#include <hip/hip_runtime.h>

#define N_NODESC 50000
#define N_EDGESC 640000
#define N_GRAPHSC 64
#define HIDC 128
#define LN_EPSF 1e-5f
#define POOL_SPLIT 16
#define SCAN_NB 49  // 49*1024 = 50176 >= 50000

typedef short bf16x8 __attribute__((ext_vector_type(8)));
typedef float f32x4 __attribute__((ext_vector_type(4)));

// ---------- helpers ----------
static __device__ __forceinline__ unsigned ord_enc(float f) {
  unsigned u = __float_as_uint(f);
  return (u & 0x80000000u) ? ~u : (u | 0x80000000u);
}
static __device__ __forceinline__ float ord_dec(unsigned u) {
  return __uint_as_float((u & 0x80000000u) ? (u ^ 0x80000000u) : ~u);
}
static __device__ __forceinline__ void f4add(float4& a, const float4 b) {
  a.x += b.x; a.y += b.y; a.z += b.z; a.w += b.w;
}
// fp32 -> bf16 bits, round-to-nearest-even
static __device__ __forceinline__ unsigned short f2bf(float x) {
  unsigned u = __float_as_uint(x);
  u += 0x7fffu + ((u >> 16) & 1u);
  return (unsigned short)(u >> 16);
}
static __device__ __forceinline__ float bf2f(unsigned short b) {
  return __uint_as_float(((unsigned)b) << 16);
}

// small 3->16 relu LN 16->16 MLP (encoder preprocessing), one thread per node
static __device__ __forceinline__ void mlp16(float in0, float in1, float in2,
    const float* __restrict__ W1, const float* __restrict__ b1,
    const float* __restrict__ g, const float* __restrict__ be,
    const float* __restrict__ W2, const float* __restrict__ b2,
    float* __restrict__ out) {
  float h[16];
  float s1 = 0.f, s2 = 0.f;
#pragma unroll
  for (int j = 0; j < 16; ++j) {
    float v = b1[j] + W1[j*3+0]*in0 + W1[j*3+1]*in1 + W1[j*3+2]*in2;
    v = fmaxf(v, 0.f);
    h[j] = v; s1 += v; s2 += v*v;
  }
  float mu = s1 * (1.f/16.f);
  float var = fmaxf(s2 * (1.f/16.f) - mu*mu, 0.f);
  float rs = rsqrtf(var + LN_EPSF);
  float z[16];
#pragma unroll
  for (int j = 0; j < 16; ++j) z[j] = (h[j]-mu)*rs*g[j] + be[j];
#pragma unroll
  for (int j = 0; j < 16; ++j) {
    float v = b2[j];
#pragma unroll
    for (int k = 0; k < 16; ++k) v += W2[j*16+k]*z[k];
    out[j] = v;
  }
}

// ---------- CSR build ----------
__global__ __launch_bounds__(256) void hist_kernel(const int* __restrict__ ei, int* __restrict__ deg) {
  int e = blockIdx.x * 256 + threadIdx.x;
  if (e < N_EDGESC) atomicAdd(&deg[ei[N_EDGESC + e]], 1);
}

// phase 1: per-block inclusive scan (coalesced), block sums out
__global__ __launch_bounds__(1024) void scan1_kernel(const int* __restrict__ deg,
                                                     int* __restrict__ incl,
                                                     int* __restrict__ bsum) {
  const int b = blockIdx.x, t = threadIdx.x;
  const int i = b * 1024 + t;
  const int lane = t & 63, w = t >> 6;
  int v = (i < N_NODESC) ? deg[i] : 0;
  // wave inclusive scan
#pragma unroll
  for (int off = 1; off < 64; off <<= 1) {
    int n = __shfl_up(v, off);
    if (lane >= off) v += n;
  }
  __shared__ int wsum[16];
  if (lane == 63) wsum[w] = v;
  __syncthreads();
  if (t == 0) {
    int run = 0;
#pragma unroll
    for (int k = 0; k < 16; ++k) { int x = wsum[k]; wsum[k] = run; run += x; }
  }
  __syncthreads();
  v += wsum[w];
  if (i < N_NODESC) incl[i] = v;
  if (t == 1023) bsum[b] = v;
}

// phase 2: exclusive scan of the 49 block sums (single wave)
__global__ __launch_bounds__(64) void scan2_kernel(int* __restrict__ bsum,
                                                   int* __restrict__ rowptr) {
  const int t = threadIdx.x;
  int v = (t < SCAN_NB) ? bsum[t] : 0;
  const int orig = v;
#pragma unroll
  for (int off = 1; off < 64; off <<= 1) {
    int n = __shfl_up(v, off);
    if (t >= off) v += n;
  }
  if (t < SCAN_NB) bsum[t] = v - orig;            // exclusive
  if (t == SCAN_NB - 1) rowptr[N_NODESC] = v;     // grand total
}

// phase 3: inclusive -> exclusive + block offset; fill rowptr & cursor
__global__ __launch_bounds__(1024) void scan3_kernel(const int* __restrict__ deg,
                                                     const int* __restrict__ bsum,
                                                     int* __restrict__ rowptr,
                                                     int* __restrict__ cursor) {
  const int b = blockIdx.x, t = threadIdx.x;
  const int i = b * 1024 + t;
  if (i >= N_NODESC) return;
  int excl = rowptr[i] - deg[i] + bsum[b];
  rowptr[i] = excl;
  cursor[i] = excl;
}

__global__ __launch_bounds__(256) void scatter_kernel(const int* __restrict__ ei,
                                                      int* __restrict__ cursor,
                                                      int* __restrict__ esrc) {
  int e = blockIdx.x * 256 + threadIdx.x;
  if (e < N_EDGESC) {
    int d = ei[N_EDGESC + e];
    int slot = atomicAdd(&cursor[d], 1);
    esrc[slot] = ei[e];
  }
}

// ---------- graph boundary detection (batch is sorted) ----------
__global__ __launch_bounds__(256) void gbound_kernel(const int* __restrict__ batch,
                                                     int* __restrict__ gstart) {
  int i = blockIdx.x * 256 + threadIdx.x;
  if (i >= N_NODESC) return;
  int b = batch[i];
  int prev = (i == 0) ? -1 : batch[i-1];
  for (int g = prev + 1; g <= b; ++g) gstart[g] = i;
  if (i == N_NODESC - 1) {
    for (int g = b + 1; g <= N_GRAPHSC; ++g) gstart[g] = N_NODESC;
  }
}

// ---------- encoder: small MLPs + 45->128 projection ----------
__global__ __launch_bounds__(128) void enc_kernel(
    const float* __restrict__ x,
    const float* __restrict__ aW1, const float* __restrict__ ab1,
    const float* __restrict__ ag,  const float* __restrict__ abe,
    const float* __restrict__ aW2, const float* __restrict__ ab2,
    const float* __restrict__ oW1, const float* __restrict__ ob1,
    const float* __restrict__ og,  const float* __restrict__ obe,
    const float* __restrict__ oW2, const float* __restrict__ ob2,
    const float* __restrict__ ninW, const float* __restrict__ ninb,
    float* __restrict__ H) {
  __shared__ float sa[48*68];   // [k][n], n<64 pad 68
  __shared__ float sw[48*132];  // [k][f], f<128 pad 132
  const int t = threadIdx.x;
  const int lane = t & 63, w = t >> 6;
  const int nb = blockIdx.x * 64;

  if (t < 64) {
    float in45[45];
    const int gn = nb + t;
    if (gn < N_NODESC) {
      const float* xr = x + gn * 19;
#pragma unroll
      for (int k = 0; k < 9; ++k) in45[k] = xr[k];
#pragma unroll
      for (int k = 0; k < 4; ++k) in45[9+k] = xr[15+k];
      mlp16(xr[9], xr[10], xr[11], aW1, ab1, ag, abe, aW2, ab2, &in45[13]);
      mlp16(xr[12], xr[13], xr[14], oW1, ob1, og, obe, oW2, ob2, &in45[29]);
    } else {
#pragma unroll
      for (int k = 0; k < 45; ++k) in45[k] = 0.f;
    }
#pragma unroll
    for (int k = 0; k < 45; ++k) sa[k*68 + t] = in45[k];
#pragma unroll
    for (int k = 45; k < 48; ++k) sa[k*68 + t] = 0.f;
  }
  for (int idx = t; idx < 48*128; idx += 128) {
    int k = idx >> 7, f = idx & 127;
    sw[k*132 + f] = (k < 45) ? ninW[f*45 + k] : 0.f;
  }
  __syncthreads();

  const int n0 = (lane & 7) * 8;
  const int f0 = ((lane >> 3) << 3) + w * 64;
  float acc[8][8];
#pragma unroll
  for (int i = 0; i < 8; ++i)
#pragma unroll
    for (int j = 0; j < 8; ++j) acc[i][j] = 0.f;

#pragma unroll 4
  for (int k = 0; k < 48; ++k) {
    float av[8], wv[8];
    float4 a0 = *(const float4*)&sa[k*68 + n0];
    float4 a1 = *(const float4*)&sa[k*68 + n0 + 4];
    float4 w0 = *(const float4*)&sw[k*132 + f0];
    float4 w1 = *(const float4*)&sw[k*132 + f0 + 4];
    av[0]=a0.x; av[1]=a0.y; av[2]=a0.z; av[3]=a0.w;
    av[4]=a1.x; av[5]=a1.y; av[6]=a1.z; av[7]=a1.w;
    wv[0]=w0.x; wv[1]=w0.y; wv[2]=w0.z; wv[3]=w0.w;
    wv[4]=w1.x; wv[5]=w1.y; wv[6]=w1.z; wv[7]=w1.w;
#pragma unroll
    for (int i = 0; i < 8; ++i)
#pragma unroll
      for (int j = 0; j < 8; ++j) acc[i][j] += av[i]*wv[j];
  }
  float bb[8];
#pragma unroll
  for (int j = 0; j < 8; ++j) bb[j] = ninb[f0+j];
#pragma unroll
  for (int i = 0; i < 8; ++i) {
    int gn = nb + n0 + i;
    if (gn < N_NODESC) {
      float o[8];
#pragma unroll
      for (int j = 0; j < 8; ++j) o[j] = acc[i][j] + bb[j];
      *(float4*)&H[gn*HIDC + f0]     = make_float4(o[0],o[1],o[2],o[3]);
      *(float4*)&H[gn*HIDC + f0 + 4] = make_float4(o[4],o[5],o[6],o[7]);
    }
  }
}

// ---------- aggregation: M = (1+eps)*H + sum_{src in bucket(dst)} H[src] ----------
__global__ __launch_bounds__(128) void agg_kernel(const float* __restrict__ H,
    const int* __restrict__ rowptr, const int* __restrict__ esrc,
    const float* __restrict__ epsp, float* __restrict__ M) {
  const int t = threadIdx.x;
  const int c = t & 31;    // float4 column (128 floats = 32 float4)
  const int v = t >> 5;    // node sub-index 0..3
  const int node = blockIdx.x * 4 + v;
  if (node >= N_NODESC) return;
  const float4* H4 = (const float4*)H;
  float4 h = H4[node*32 + c];
  const float e1 = 1.0f + epsp[0];
  float4 a0 = make_float4(0,0,0,0), a1 = a0, a2 = a0, a3 = a0;
  int s = rowptr[node];
  const int e = rowptr[node+1];
  for (; s + 4 <= e; s += 4) {
    int i0 = esrc[s], i1 = esrc[s+1], i2 = esrc[s+2], i3 = esrc[s+3];
    float4 x0 = H4[i0*32+c], x1 = H4[i1*32+c], x2 = H4[i2*32+c], x3 = H4[i3*32+c];
    f4add(a0,x0); f4add(a1,x1); f4add(a2,x2); f4add(a3,x3);
  }
  for (; s < e; ++s) f4add(a0, H4[esrc[s]*32+c]);
  float4 m;
  m.x = e1*h.x + a0.x+a1.x+a2.x+a3.x;
  m.y = e1*h.y + a0.y+a1.y+a2.y+a3.y;
  m.z = e1*h.z + a0.z+a1.z+a2.z+a3.z;
  m.w = e1*h.w + a0.w+a1.w+a2.w+a3.w;
  ((float4*)M)[node*32 + c] = m;
}

// ---------- MFMA GEMM: OUT[64 x 128] tile = IN @ W^T, + bias + relu + LN (+resid) ----------
__global__ __launch_bounds__(256, 2) void gemm_mfma_kernel(
    const float* __restrict__ IN, const float* __restrict__ W,
    const float* __restrict__ bias, const float* __restrict__ lng,
    const float* __restrict__ lnb, const float* __restrict__ resid,
    float* __restrict__ OUT) {
  __shared__ unsigned short Ah[64*136];
  __shared__ unsigned short Al[64*136];
  __shared__ unsigned short Wl[128*136];
  const int t = threadIdx.x;
  const int nb = blockIdx.x * 64;
  // stage W (128x128 fp32 -> bf16)
#pragma unroll
  for (int i = 0; i < 16; ++i) {
    int q = t + i*256;
    int f = q >> 5, c4 = q & 31;
    float4 v = *(const float4*)&W[f*HIDC + c4*4];
    ushort4 h;
    h.x = f2bf(v.x); h.y = f2bf(v.y); h.z = f2bf(v.z); h.w = f2bf(v.w);
    *(ushort4*)&Wl[f*136 + c4*4] = h;
  }
  // stage A (64x128 fp32 -> bf16 hi + lo)
#pragma unroll
  for (int i = 0; i < 8; ++i) {
    int q = t + i*256;
    int n = q >> 5, c4 = q & 31;
    int gn = nb + n;
    float4 v = make_float4(0,0,0,0);
    if (gn < N_NODESC) v = *(const float4*)&IN[gn*HIDC + c4*4];
    ushort4 hi, lo;
    hi.x = f2bf(v.x); lo.x = f2bf(v.x - bf2f(hi.x));
    hi.y = f2bf(v.y); lo.y = f2bf(v.y - bf2f(hi.y));
    hi.z = f2bf(v.z); lo.z = f2bf(v.z - bf2f(hi.z));
    hi.w = f2bf(v.w); lo.w = f2bf(v.w - bf2f(hi.w));
    *(ushort4*)&Ah[n*136 + c4*4] = hi;
    *(ushort4*)&Al[n*136 + c4*4] = lo;
  }
  __syncthreads();

  const int lane = t & 63, wv = t >> 6;
  const int quad = lane >> 4, l16 = lane & 15;
  f32x4 acc[8];
#pragma unroll
  for (int ft = 0; ft < 8; ++ft) acc[ft] = (f32x4){0.f,0.f,0.f,0.f};

  const int arow = (wv*16 + l16)*136 + quad*8;
#pragma unroll
  for (int ks = 0; ks < 4; ++ks) {
    bf16x8 a_h = *(const bf16x8*)(const void*)&Ah[arow + ks*32];
    bf16x8 a_l = *(const bf16x8*)(const void*)&Al[arow + ks*32];
#pragma unroll
    for (int ft = 0; ft < 8; ++ft) {
      bf16x8 b = *(const bf16x8*)(const void*)&Wl[(ft*16 + l16)*136 + quad*8 + ks*32];
      acc[ft] = __builtin_amdgcn_mfma_f32_16x16x32_bf16(a_h, b, acc[ft], 0, 0, 0);
      acc[ft] = __builtin_amdgcn_mfma_f32_16x16x32_bf16(a_l, b, acc[ft], 0, 0, 0);
    }
  }

  // epilogue: bias + relu + LN(128) + optional residual.
  float bb[8], gg[8], bee[8];
#pragma unroll
  for (int ft = 0; ft < 8; ++ft) {
    int f = ft*16 + l16;
    bb[ft] = bias[f]; gg[ft] = lng[f]; bee[ft] = lnb[f];
  }
  float s1[4] = {0,0,0,0}, s2[4] = {0,0,0,0};
#pragma unroll
  for (int ft = 0; ft < 8; ++ft)
#pragma unroll
    for (int r = 0; r < 4; ++r) {
      float v = fmaxf(acc[ft][r] + bb[ft], 0.f);
      acc[ft][r] = v; s1[r] += v; s2[r] += v*v;
    }
#pragma unroll
  for (int m = 1; m < 16; m <<= 1)
#pragma unroll
    for (int r = 0; r < 4; ++r) {
      s1[r] += __shfl_xor(s1[r], m);
      s2[r] += __shfl_xor(s2[r], m);
    }
  float mu[4], rs[4];
#pragma unroll
  for (int r = 0; r < 4; ++r) {
    mu[r] = s1[r] * (1.f/128.f);
    float var = fmaxf(s2[r] * (1.f/128.f) - mu[r]*mu[r], 0.f);
    rs[r] = rsqrtf(var + LN_EPSF);
  }
#pragma unroll
  for (int r = 0; r < 4; ++r) {
    int node = nb + wv*16 + quad*4 + r;
    if (node >= N_NODESC) continue;
    const int base = node*HIDC + l16;
#pragma unroll
    for (int ft = 0; ft < 8; ++ft) {
      float o = (acc[ft][r] - mu[r])*rs[r]*gg[ft] + bee[ft];
      if (resid) o += resid[base + ft*16];
      OUT[base + ft*16] = o;
    }
  }
}

// ---------- MFMA gate: per node z = LN(relu(H@W1^T+b1)); gate = z.W2 + b2 ----------
__global__ __launch_bounds__(256, 2) void gate_mfma_kernel(
    const float* __restrict__ H, const float* __restrict__ W1,
    const float* __restrict__ b1, const float* __restrict__ lng,
    const float* __restrict__ lnb, const float* __restrict__ W2,
    const float* __restrict__ b2,
    float* __restrict__ gateb) {
  __shared__ unsigned short Ah[64*136];
  __shared__ unsigned short Al[64*136];
  __shared__ unsigned short Wl[64*136];
  const int t = threadIdx.x;
  const int nb = blockIdx.x * 64;
#pragma unroll
  for (int i = 0; i < 8; ++i) {
    int q = t + i*256;
    int f = q >> 5, c4 = q & 31;
    float4 v = *(const float4*)&W1[f*HIDC + c4*4];
    ushort4 h;
    h.x = f2bf(v.x); h.y = f2bf(v.y); h.z = f2bf(v.z); h.w = f2bf(v.w);
    *(ushort4*)&Wl[f*136 + c4*4] = h;
  }
#pragma unroll
  for (int i = 0; i < 8; ++i) {
    int q = t + i*256;
    int n = q >> 5, c4 = q & 31;
    int gn = nb + n;
    float4 v = make_float4(0,0,0,0);
    if (gn < N_NODESC) v = *(const float4*)&H[gn*HIDC + c4*4];
    ushort4 hi, lo;
    hi.x = f2bf(v.x); lo.x = f2bf(v.x - bf2f(hi.x));
    hi.y = f2bf(v.y); lo.y = f2bf(v.y - bf2f(hi.y));
    hi.z = f2bf(v.z); lo.z = f2bf(v.z - bf2f(hi.z));
    hi.w = f2bf(v.w); lo.w = f2bf(v.w - bf2f(hi.w));
    *(ushort4*)&Ah[n*136 + c4*4] = hi;
    *(ushort4*)&Al[n*136 + c4*4] = lo;
  }
  __syncthreads();

  const int lane = t & 63, wv = t >> 6;
  const int quad = lane >> 4, l16 = lane & 15;
  f32x4 acc[4];
#pragma unroll
  for (int ft = 0; ft < 4; ++ft) acc[ft] = (f32x4){0.f,0.f,0.f,0.f};

  const int arow = (wv*16 + l16)*136 + quad*8;
#pragma unroll
  for (int ks = 0; ks < 4; ++ks) {
    bf16x8 a_h = *(const bf16x8*)(const void*)&Ah[arow + ks*32];
    bf16x8 a_l = *(const bf16x8*)(const void*)&Al[arow + ks*32];
#pragma unroll
    for (int ft = 0; ft < 4; ++ft) {
      bf16x8 b = *(const bf16x8*)(const void*)&Wl[(ft*16 + l16)*136 + quad*8 + ks*32];
      acc[ft] = __builtin_amdgcn_mfma_f32_16x16x32_bf16(a_h, b, acc[ft], 0, 0, 0);
      acc[ft] = __builtin_amdgcn_mfma_f32_16x16x32_bf16(a_l, b, acc[ft], 0, 0, 0);
    }
  }

  float bb[4], gg[4], bee[4], w2v[4];
#pragma unroll
  for (int ft = 0; ft < 4; ++ft) {
    int f = ft*16 + l16;
    bb[ft] = b1[f]; gg[ft] = lng[f]; bee[ft] = lnb[f]; w2v[ft] = W2[f];
  }
  float s1[4] = {0,0,0,0}, s2[4] = {0,0,0,0};
#pragma unroll
  for (int ft = 0; ft < 4; ++ft)
#pragma unroll
    for (int r = 0; r < 4; ++r) {
      float v = fmaxf(acc[ft][r] + bb[ft], 0.f);
      acc[ft][r] = v; s1[r] += v; s2[r] += v*v;
    }
#pragma unroll
  for (int m = 1; m < 16; m <<= 1)
#pragma unroll
    for (int r = 0; r < 4; ++r) {
      s1[r] += __shfl_xor(s1[r], m);
      s2[r] += __shfl_xor(s2[r], m);
    }
  float pd[4];
#pragma unroll
  for (int r = 0; r < 4; ++r) {
    float mu = s1[r] * (1.f/64.f);
    float var = fmaxf(s2[r] * (1.f/64.f) - mu*mu, 0.f);
    float rs = rsqrtf(var + LN_EPSF);
    float p = 0.f;
#pragma unroll
    for (int ft = 0; ft < 4; ++ft)
      p += ((acc[ft][r] - mu)*rs*gg[ft] + bee[ft]) * w2v[ft];
    pd[r] = p;
  }
#pragma unroll
  for (int m = 1; m < 16; m <<= 1)
#pragma unroll
    for (int r = 0; r < 4; ++r) pd[r] += __shfl_xor(pd[r], m);
  if (l16 == 0) {
    float b2v = b2[0];
#pragma unroll
    for (int r = 0; r < 4; ++r) {
      int node = nb + wv*16 + quad*4 + r;
      if (node < N_NODESC) gateb[node] = pd[r] + b2v;
    }
  }
}

// ---------- segmented per-graph max of gateb (16 blocks/graph, 1 atomic each) ----------
__global__ __launch_bounds__(256) void gmax_kernel(const float* __restrict__ gateb,
    const int* __restrict__ gstart, unsigned* __restrict__ gmaxu) {
  const int g    = blockIdx.x / POOL_SPLIT;
  const int part = blockIdx.x % POOL_SPLIT;
  const int s0 = gstart[g], s1 = gstart[g+1];
  const int cnt = s1 - s0;
  const int chunk = (cnt + POOL_SPLIT - 1) / POOL_SPLIT;
  int lo = s0 + part * chunk;
  int hi = lo + chunk; if (hi > s1) hi = s1;
  const int t = threadIdx.x;
  float m = -3.4e38f;
  for (int n = lo + t; n < hi; n += 256) m = fmaxf(m, gateb[n]);
  __shared__ float sm[256];
  sm[t] = m;
  __syncthreads();
#pragma unroll
  for (int off = 128; off >= 1; off >>= 1) {
    if (t < off) sm[t] = fmaxf(sm[t], sm[t + off]);
    __syncthreads();
  }
  if (t == 0 && sm[0] > -3.4e38f) atomicMax(&gmaxu[g], ord_enc(sm[0]));
}

// ---------- segmented softmax-weighted pooling ----------
__global__ __launch_bounds__(256) void pool_kernel(const float* __restrict__ H,
    const float* __restrict__ gateb, const int* __restrict__ gstart,
    const unsigned* __restrict__ gmaxu, float* __restrict__ S,
    float* __restrict__ denom) {
  const int g    = blockIdx.x / POOL_SPLIT;
  const int part = blockIdx.x % POOL_SPLIT;
  const int s0 = gstart[g], s1 = gstart[g+1];
  const int cnt = s1 - s0;
  const int chunk = (cnt + POOL_SPLIT - 1) / POOL_SPLIT;
  int lo = s0 + part * chunk;
  int hi = lo + chunk; if (hi > s1) hi = s1;
  const int t = threadIdx.x;
  const int j = t & 127;   // feature
  const int v = t >> 7;    // node subgroup 0..1
  const float gm = ord_dec(gmaxu[g]);
  float acc = 0.f, de = 0.f;
  for (int n = lo + v; n < hi; n += 2) {
    float e = expf(gateb[n] - gm);
    acc += e * H[n*HIDC + j];
    if (j == 0) de += e;
  }
  __shared__ float sacc[256];
  __shared__ float sden[2];
  sacc[t] = acc;
  if (j == 0) sden[v] = de;
  __syncthreads();
  if (t < 128) {
    float s = sacc[t] + sacc[t+128];
    atomicAdd(&S[g*HIDC + t], s);
  }
  if (t == 0) atomicAdd(&denom[g], sden[0] + sden[1]);
}

// ---------- head MLP per graph ----------
__global__ __launch_bounds__(64) void head_kernel(const float* __restrict__ S,
    const float* __restrict__ denom, const float* __restrict__ W1,
    const float* __restrict__ b1, const float* __restrict__ g,
    const float* __restrict__ be, const float* __restrict__ W2,
    const float* __restrict__ b2, float* __restrict__ out) {
  const int gr = blockIdx.x;
  const int j = threadIdx.x;
  const float inv = 1.0f / denom[gr];
  float v = b1[j];
  for (int k = 0; k < HIDC; ++k) v += (S[gr*HIDC + k] * inv) * W1[j*HIDC + k];
  v = fmaxf(v, 0.f);
  float s1 = v, s2 = v*v;
  for (int off = 32; off; off >>= 1) { s1 += __shfl_xor(s1, off); s2 += __shfl_xor(s2, off); }
  float mu = s1 * (1.f/64.f);
  float var = fmaxf(s2 * (1.f/64.f) - mu*mu, 0.f);
  float rs = rsqrtf(var + LN_EPSF);
  float z = (v-mu)*rs*g[j] + be[j];
  float p = z * W2[j];
  for (int off = 32; off; off >>= 1) p += __shfl_xor(p, off);
  if (j == 0) out[gr] = p + b2[0];
}

// ---------- launch ----------
extern "C" void kernel_launch(void* const* d_in, const int* in_sizes, int n_in,
                              void* d_out, int out_size, void* d_ws, size_t ws_size,
                              hipStream_t stream) {
  (void)in_sizes; (void)n_in; (void)out_size; (void)ws_size;
  const float* x     = (const float*)d_in[0];
  const int*   ei    = (const int*)d_in[1];
  const int*   batch = (const int*)d_in[2];
  const float* aW1 = (const float*)d_in[3];
  const float* ab1 = (const float*)d_in[4];
  const float* ag  = (const float*)d_in[5];
  const float* abe = (const float*)d_in[6];
  const float* aW2 = (const float*)d_in[7];
  const float* ab2 = (const float*)d_in[8];
  const float* oW1 = (const float*)d_in[9];
  const float* ob1 = (const float*)d_in[10];
  const float* og  = (const float*)d_in[11];
  const float* obe = (const float*)d_in[12];
  const float* oW2 = (const float*)d_in[13];
  const float* ob2 = (const float*)d_in[14];
  const float* ninW = (const float*)d_in[15];
  const float* ninb = (const float*)d_in[16];
  const float* cW1 = (const float*)d_in[17];
  const float* cb1 = (const float*)d_in[18];
  const float* cg  = (const float*)d_in[19];
  const float* cbe = (const float*)d_in[20];
  const float* cW2 = (const float*)d_in[21];
  const float* cb2 = (const float*)d_in[22];
  const float* eps = (const float*)d_in[23];
  const float* lng = (const float*)d_in[24];
  const float* lnb = (const float*)d_in[25];
  const float* gW1 = (const float*)d_in[26];
  const float* gb1 = (const float*)d_in[27];
  const float* gg  = (const float*)d_in[28];
  const float* gbe = (const float*)d_in[29];
  const float* gW2 = (const float*)d_in[30];
  const float* gb2 = (const float*)d_in[31];
  const float* hW1 = (const float*)d_in[32];
  const float* hb1 = (const float*)d_in[33];
  const float* hg  = (const float*)d_in[34];
  const float* hbe = (const float*)d_in[35];
  const float* hW2 = (const float*)d_in[36];
  const float* hb2 = (const float*)d_in[37];

  char* ws = (char*)d_ws;
  float* H     = (float*)(ws + 0);            // 25,600,000 B
  float* T     = (float*)(ws + 25600000);     // 25,600,000 B
  float* M     = (float*)(ws + 51200000);     // 25,600,000 B
  float* gateb = (float*)(ws + 76800000);     // 200,000 B
  float* S     = (float*)(ws + 77000000);     // 32,768 B
  float* denom = (float*)(ws + 77032768);     // 256 B
  unsigned* gmaxu = (unsigned*)(ws + 77033024); // 256 B
  int* deg     = (int*)(ws + 77033280);       // 200,000 B
  int* rowptr  = (int*)(ws + 77233280);       // 200,004 B
  int* cursor  = (int*)(ws + 77433284);       // 200,000 B
  int* esrc    = (int*)(ws + 77633284);       // 2,560,000 B
  int* bsum    = (int*)(ws + 80193284);       // 256 B
  int* gstart  = cursor;  // alias: cursor is dead after scatter_kernel

  hipMemsetAsync(deg, 0, 200000, stream);
  hipMemsetAsync(S, 0, 33280, stream);  // S + denom + gmaxu contiguous

  const int egrid = (N_EDGESC + 255) / 256;
  hist_kernel<<<egrid, 256, 0, stream>>>(ei, deg);
  scan1_kernel<<<SCAN_NB, 1024, 0, stream>>>(deg, rowptr, bsum);
  scan2_kernel<<<1, 64, 0, stream>>>(bsum, rowptr);
  scan3_kernel<<<SCAN_NB, 1024, 0, stream>>>(deg, bsum, rowptr, cursor);
  scatter_kernel<<<egrid, 256, 0, stream>>>(ei, cursor, esrc);
  gbound_kernel<<<(N_NODESC + 255) / 256, 256, 0, stream>>>(batch, gstart);

  const int ngrid64 = (N_NODESC + 63) / 64;
  enc_kernel<<<ngrid64, 128, 0, stream>>>(x, aW1, ab1, ag, abe, aW2, ab2,
                                          oW1, ob1, og, obe, oW2, ob2,
                                          ninW, ninb, H);
  for (int l = 0; l < 3; ++l) {
    agg_kernel<<<(N_NODESC + 3) / 4, 128, 0, stream>>>(H, rowptr, esrc, eps + l, M);
    gemm_mfma_kernel<<<ngrid64, 256, 0, stream>>>(M, cW1 + l*HIDC*HIDC, cb1 + l*HIDC,
                                                  cg + l*HIDC, cbe + l*HIDC, nullptr, T);
    gemm_mfma_kernel<<<ngrid64, 256, 0, stream>>>(T, cW2 + l*HIDC*HIDC, cb2 + l*HIDC,
                                                  lng + l*HIDC, lnb + l*HIDC, H, H);
  }
  gate_mfma_kernel<<<ngrid64, 256, 0, stream>>>(H, gW1, gb1, gg, gbe, gW2, gb2, gateb);
  gmax_kernel<<<N_GRAPHSC * POOL_SPLIT, 256, 0, stream>>>(gateb, gstart, gmaxu);
  pool_kernel<<<N_GRAPHSC * POOL_SPLIT, 256, 0, stream>>>(H, gateb, gstart, gmaxu, S, denom);
  head_kernel<<<N_GRAPHSC, 64, 0, stream>>>(S, denom, hW1, hb1, hg, hbe, hW2, hb2,
                                            (float*)d_out);
}

// Round 6
// 420.124 us; speedup vs baseline: 3.0619x; 1.3434x over previous
//
#include <hip/hip_runtime.h>

#define N_NODESC 50000
#define N_EDGESC 640000
#define N_GRAPHSC 64
#define HIDC 128
#define LN_EPSF 1e-5f
#define POOL_SPLIT 16
#define SCAN_NB 49  // 49*1024 = 50176 >= 50000

typedef short bf16x8 __attribute__((ext_vector_type(8)));
typedef float f32x4 __attribute__((ext_vector_type(4)));

// ---------- helpers ----------
static __device__ __forceinline__ unsigned ord_enc(float f) {
  unsigned u = __float_as_uint(f);
  return (u & 0x80000000u) ? ~u : (u | 0x80000000u);
}
static __device__ __forceinline__ float ord_dec(unsigned u) {
  return __uint_as_float((u & 0x80000000u) ? (u ^ 0x80000000u) : ~u);
}
// fp32 -> bf16 bits, round-to-nearest-even
static __device__ __forceinline__ unsigned short f2bf(float x) {
  unsigned u = __float_as_uint(x);
  u += 0x7fffu + ((u >> 16) & 1u);
  return (unsigned short)(u >> 16);
}
static __device__ __forceinline__ float bf2f(unsigned short b) {
  return __uint_as_float(((unsigned)b) << 16);
}

// small 3->16 relu LN 16->16 MLP (encoder preprocessing), one thread per node
static __device__ __forceinline__ void mlp16(float in0, float in1, float in2,
    const float* __restrict__ W1, const float* __restrict__ b1,
    const float* __restrict__ g, const float* __restrict__ be,
    const float* __restrict__ W2, const float* __restrict__ b2,
    float* __restrict__ out) {
  float h[16];
  float s1 = 0.f, s2 = 0.f;
#pragma unroll
  for (int j = 0; j < 16; ++j) {
    float v = b1[j] + W1[j*3+0]*in0 + W1[j*3+1]*in1 + W1[j*3+2]*in2;
    v = fmaxf(v, 0.f);
    h[j] = v; s1 += v; s2 += v*v;
  }
  float mu = s1 * (1.f/16.f);
  float var = fmaxf(s2 * (1.f/16.f) - mu*mu, 0.f);
  float rs = rsqrtf(var + LN_EPSF);
  float z[16];
#pragma unroll
  for (int j = 0; j < 16; ++j) z[j] = (h[j]-mu)*rs*g[j] + be[j];
#pragma unroll
  for (int j = 0; j < 16; ++j) {
    float v = b2[j];
#pragma unroll
    for (int k = 0; k < 16; ++k) v += W2[j*16+k]*z[k];
    out[j] = v;
  }
}

// ---------- CSR build ----------
__global__ __launch_bounds__(256) void hist_kernel(const int* __restrict__ ei, int* __restrict__ deg) {
  int e = blockIdx.x * 256 + threadIdx.x;
  if (e < N_EDGESC) atomicAdd(&deg[ei[N_EDGESC + e]], 1);
}

__global__ __launch_bounds__(1024) void scan1_kernel(const int* __restrict__ deg,
                                                     int* __restrict__ incl,
                                                     int* __restrict__ bsum) {
  const int b = blockIdx.x, t = threadIdx.x;
  const int i = b * 1024 + t;
  const int lane = t & 63, w = t >> 6;
  int v = (i < N_NODESC) ? deg[i] : 0;
#pragma unroll
  for (int off = 1; off < 64; off <<= 1) {
    int n = __shfl_up(v, off);
    if (lane >= off) v += n;
  }
  __shared__ int wsum[16];
  if (lane == 63) wsum[w] = v;
  __syncthreads();
  if (t == 0) {
    int run = 0;
#pragma unroll
    for (int k = 0; k < 16; ++k) { int x = wsum[k]; wsum[k] = run; run += x; }
  }
  __syncthreads();
  v += wsum[w];
  if (i < N_NODESC) incl[i] = v;
  if (t == 1023) bsum[b] = v;
}

__global__ __launch_bounds__(64) void scan2_kernel(int* __restrict__ bsum,
                                                   int* __restrict__ rowptr) {
  const int t = threadIdx.x;
  int v = (t < SCAN_NB) ? bsum[t] : 0;
  const int orig = v;
#pragma unroll
  for (int off = 1; off < 64; off <<= 1) {
    int n = __shfl_up(v, off);
    if (t >= off) v += n;
  }
  if (t < SCAN_NB) bsum[t] = v - orig;
  if (t == SCAN_NB - 1) rowptr[N_NODESC] = v;
}

__global__ __launch_bounds__(1024) void scan3_kernel(const int* __restrict__ deg,
                                                     const int* __restrict__ bsum,
                                                     int* __restrict__ rowptr,
                                                     int* __restrict__ cursor) {
  const int b = blockIdx.x, t = threadIdx.x;
  const int i = b * 1024 + t;
  if (i >= N_NODESC) return;
  int excl = rowptr[i] - deg[i] + bsum[b];
  rowptr[i] = excl;
  cursor[i] = excl;
}

__global__ __launch_bounds__(256) void scatter_kernel(const int* __restrict__ ei,
                                                      int* __restrict__ cursor,
                                                      int* __restrict__ esrc) {
  int e = blockIdx.x * 256 + threadIdx.x;
  if (e < N_EDGESC) {
    int d = ei[N_EDGESC + e];
    int slot = atomicAdd(&cursor[d], 1);
    esrc[slot] = ei[e];
  }
}

// ---------- graph boundary detection (batch is sorted) ----------
__global__ __launch_bounds__(256) void gbound_kernel(const int* __restrict__ batch,
                                                     int* __restrict__ gstart) {
  int i = blockIdx.x * 256 + threadIdx.x;
  if (i >= N_NODESC) return;
  int b = batch[i];
  int prev = (i == 0) ? -1 : batch[i-1];
  for (int g = prev + 1; g <= b; ++g) gstart[g] = i;
  if (i == N_NODESC - 1) {
    for (int g = b + 1; g <= N_GRAPHSC; ++g) gstart[g] = N_NODESC;
  }
}

// ---------- encoder: small MLPs + 45->128 projection; output bf16 ----------
__global__ __launch_bounds__(128) void enc_kernel(
    const float* __restrict__ x,
    const float* __restrict__ aW1, const float* __restrict__ ab1,
    const float* __restrict__ ag,  const float* __restrict__ abe,
    const float* __restrict__ aW2, const float* __restrict__ ab2,
    const float* __restrict__ oW1, const float* __restrict__ ob1,
    const float* __restrict__ og,  const float* __restrict__ obe,
    const float* __restrict__ oW2, const float* __restrict__ ob2,
    const float* __restrict__ ninW, const float* __restrict__ ninb,
    unsigned short* __restrict__ Hb) {
  __shared__ float sa[48*68];
  __shared__ float sw[48*132];
  const int t = threadIdx.x;
  const int lane = t & 63, w = t >> 6;
  const int nb = blockIdx.x * 64;

  if (t < 64) {
    float in45[45];
    const int gn = nb + t;
    if (gn < N_NODESC) {
      const float* xr = x + gn * 19;
#pragma unroll
      for (int k = 0; k < 9; ++k) in45[k] = xr[k];
#pragma unroll
      for (int k = 0; k < 4; ++k) in45[9+k] = xr[15+k];
      mlp16(xr[9], xr[10], xr[11], aW1, ab1, ag, abe, aW2, ab2, &in45[13]);
      mlp16(xr[12], xr[13], xr[14], oW1, ob1, og, obe, oW2, ob2, &in45[29]);
    } else {
#pragma unroll
      for (int k = 0; k < 45; ++k) in45[k] = 0.f;
    }
#pragma unroll
    for (int k = 0; k < 45; ++k) sa[k*68 + t] = in45[k];
#pragma unroll
    for (int k = 45; k < 48; ++k) sa[k*68 + t] = 0.f;
  }
  for (int idx = t; idx < 48*128; idx += 128) {
    int k = idx >> 7, f = idx & 127;
    sw[k*132 + f] = (k < 45) ? ninW[f*45 + k] : 0.f;
  }
  __syncthreads();

  const int n0 = (lane & 7) * 8;
  const int f0 = ((lane >> 3) << 3) + w * 64;
  float acc[8][8];
#pragma unroll
  for (int i = 0; i < 8; ++i)
#pragma unroll
    for (int j = 0; j < 8; ++j) acc[i][j] = 0.f;

#pragma unroll 4
  for (int k = 0; k < 48; ++k) {
    float av[8], wv[8];
    float4 a0 = *(const float4*)&sa[k*68 + n0];
    float4 a1 = *(const float4*)&sa[k*68 + n0 + 4];
    float4 w0 = *(const float4*)&sw[k*132 + f0];
    float4 w1 = *(const float4*)&sw[k*132 + f0 + 4];
    av[0]=a0.x; av[1]=a0.y; av[2]=a0.z; av[3]=a0.w;
    av[4]=a1.x; av[5]=a1.y; av[6]=a1.z; av[7]=a1.w;
    wv[0]=w0.x; wv[1]=w0.y; wv[2]=w0.z; wv[3]=w0.w;
    wv[4]=w1.x; wv[5]=w1.y; wv[6]=w1.z; wv[7]=w1.w;
#pragma unroll
    for (int i = 0; i < 8; ++i)
#pragma unroll
      for (int j = 0; j < 8; ++j) acc[i][j] += av[i]*wv[j];
  }
  float bb[8];
#pragma unroll
  for (int j = 0; j < 8; ++j) bb[j] = ninb[f0+j];
#pragma unroll
  for (int i = 0; i < 8; ++i) {
    int gn = nb + n0 + i;
    if (gn < N_NODESC) {
      bf16x8 o8;
#pragma unroll
      for (int j = 0; j < 8; ++j) o8[j] = (short)f2bf(acc[i][j] + bb[j]);
      *(bf16x8*)&Hb[gn*HIDC + f0] = o8;
    }
  }
}

// ---------- aggregation (bf16): Mb = bf16( (1+eps)*Hb + sum Hb[src] ) ----------
// 8 nodes/block, 16 lanes/node, 16B per lane.
__global__ __launch_bounds__(128) void agg_kernel(const unsigned short* __restrict__ Hb,
    const int* __restrict__ rowptr, const int* __restrict__ esrc,
    const float* __restrict__ epsp, unsigned short* __restrict__ Mb) {
  const int t = threadIdx.x;
  const int c8 = t & 15;   // 16B chunk within 256B row
  const int v  = t >> 4;   // node sub-index 0..7
  const int node = blockIdx.x * 8 + v;
  if (node >= N_NODESC) return;
  const float e1 = 1.0f + epsp[0];
  bf16x8 h = *(const bf16x8*)&Hb[node*HIDC + c8*8];
  float acc[8];
#pragma unroll
  for (int k = 0; k < 8; ++k) acc[k] = 0.f;
  int s = rowptr[node];
  const int e = rowptr[node+1];
  for (; s + 4 <= e; s += 4) {
    int i0 = esrc[s], i1 = esrc[s+1], i2 = esrc[s+2], i3 = esrc[s+3];
    bf16x8 x0 = *(const bf16x8*)&Hb[i0*HIDC + c8*8];
    bf16x8 x1 = *(const bf16x8*)&Hb[i1*HIDC + c8*8];
    bf16x8 x2 = *(const bf16x8*)&Hb[i2*HIDC + c8*8];
    bf16x8 x3 = *(const bf16x8*)&Hb[i3*HIDC + c8*8];
#pragma unroll
    for (int k = 0; k < 8; ++k)
      acc[k] += (bf2f((unsigned short)x0[k]) + bf2f((unsigned short)x1[k]))
              + (bf2f((unsigned short)x2[k]) + bf2f((unsigned short)x3[k]));
  }
  for (; s < e; ++s) {
    bf16x8 x0 = *(const bf16x8*)&Hb[esrc[s]*HIDC + c8*8];
#pragma unroll
    for (int k = 0; k < 8; ++k) acc[k] += bf2f((unsigned short)x0[k]);
  }
  bf16x8 m8;
#pragma unroll
  for (int k = 0; k < 8; ++k)
    m8[k] = (short)f2bf(e1*bf2f((unsigned short)h[k]) + acc[k]);
  *(bf16x8*)&Mb[node*HIDC + c8*8] = m8;
}

// ---------- MFMA GEMM (bf16 in/out): OUT[64x128] = IN @ W^T + bias, relu, LN, (+resid) ----------
__global__ __launch_bounds__(256, 2) void gemm_mfma_kernel(
    const unsigned short* __restrict__ INb, const float* __restrict__ W,
    const float* __restrict__ bias, const float* __restrict__ lng,
    const float* __restrict__ lnb, const unsigned short* __restrict__ residb,
    unsigned short* __restrict__ OUTb) {
  __shared__ unsigned short Ab[64*136];
  __shared__ unsigned short Wl[128*136];
  const int t = threadIdx.x;
  const int nb = blockIdx.x * 64;
  // stage A (bf16 straight copy, 16B chunks)
#pragma unroll
  for (int i = 0; i < 4; ++i) {
    int chunk = t + i*256;
    int n = chunk >> 4, c8 = chunk & 15;
    int gn = nb + n;
    bf16x8 v = {0,0,0,0,0,0,0,0};
    if (gn < N_NODESC) v = *(const bf16x8*)&INb[gn*HIDC + c8*8];
    *(bf16x8*)&Ab[n*136 + c8*8] = v;
  }
  // stage W (fp32 -> bf16)
#pragma unroll
  for (int i = 0; i < 16; ++i) {
    int q = t + i*256;
    int f = q >> 5, c4 = q & 31;
    float4 v = *(const float4*)&W[f*HIDC + c4*4];
    ushort4 h;
    h.x = f2bf(v.x); h.y = f2bf(v.y); h.z = f2bf(v.z); h.w = f2bf(v.w);
    *(ushort4*)&Wl[f*136 + c4*4] = h;
  }
  __syncthreads();

  const int lane = t & 63, wv = t >> 6;
  const int quad = lane >> 4, l16 = lane & 15;
  f32x4 acc[8];
#pragma unroll
  for (int ft = 0; ft < 8; ++ft) acc[ft] = (f32x4){0.f,0.f,0.f,0.f};

  const int arow = (wv*16 + l16)*136 + quad*8;
#pragma unroll
  for (int ks = 0; ks < 4; ++ks) {
    bf16x8 a = *(const bf16x8*)(const void*)&Ab[arow + ks*32];
#pragma unroll
    for (int ft = 0; ft < 8; ++ft) {
      bf16x8 b = *(const bf16x8*)(const void*)&Wl[(ft*16 + l16)*136 + quad*8 + ks*32];
      acc[ft] = __builtin_amdgcn_mfma_f32_16x16x32_bf16(a, b, acc[ft], 0, 0, 0);
    }
  }

  // epilogue: bias + relu + LN in registers (C/D: col=l16-based feature, row=quad*4+reg)
  float bb[8], gg[8], bee[8];
#pragma unroll
  for (int ft = 0; ft < 8; ++ft) {
    int f = ft*16 + l16;
    bb[ft] = bias[f]; gg[ft] = lng[f]; bee[ft] = lnb[f];
  }
  float s1[4] = {0,0,0,0}, s2[4] = {0,0,0,0};
#pragma unroll
  for (int ft = 0; ft < 8; ++ft)
#pragma unroll
    for (int r = 0; r < 4; ++r) {
      float v = fmaxf(acc[ft][r] + bb[ft], 0.f);
      acc[ft][r] = v; s1[r] += v; s2[r] += v*v;
    }
#pragma unroll
  for (int m = 1; m < 16; m <<= 1)
#pragma unroll
    for (int r = 0; r < 4; ++r) {
      s1[r] += __shfl_xor(s1[r], m);
      s2[r] += __shfl_xor(s2[r], m);
    }
  float mu[4], rs[4];
#pragma unroll
  for (int r = 0; r < 4; ++r) {
    mu[r] = s1[r] * (1.f/128.f);
    float var = fmaxf(s2[r] * (1.f/128.f) - mu[r]*mu[r], 0.f);
    rs[r] = rsqrtf(var + LN_EPSF);
  }
  // round-trip C through LDS (reuse Ab) for coalesced bf16 stores
  __syncthreads();
#pragma unroll
  for (int r = 0; r < 4; ++r) {
    int nloc = wv*16 + quad*4 + r;
#pragma unroll
    for (int ft = 0; ft < 8; ++ft) {
      float o = (acc[ft][r] - mu[r])*rs[r]*gg[ft] + bee[ft];
      Ab[nloc*136 + ft*16 + l16] = f2bf(o);
    }
  }
  __syncthreads();
#pragma unroll
  for (int i = 0; i < 4; ++i) {
    int chunk = t + i*256;
    int n = chunk >> 4, c8 = chunk & 15;
    int gn = nb + n;
    if (gn >= N_NODESC) continue;
    bf16x8 v = *(const bf16x8*)&Ab[n*136 + c8*8];
    bf16x8 o8;
    if (residb) {
      bf16x8 rch = *(const bf16x8*)&residb[gn*HIDC + c8*8];
#pragma unroll
      for (int k = 0; k < 8; ++k)
        o8[k] = (short)f2bf(bf2f((unsigned short)v[k]) + bf2f((unsigned short)rch[k]));
    } else {
      o8 = v;
    }
    *(bf16x8*)&OUTb[gn*HIDC + c8*8] = o8;
  }
}

// ---------- MFMA gate (bf16 in): gate = LN(relu(H@W1^T+b1)).W2 + b2 ----------
__global__ __launch_bounds__(256, 2) void gate_mfma_kernel(
    const unsigned short* __restrict__ Hb, const float* __restrict__ W1,
    const float* __restrict__ b1, const float* __restrict__ lng,
    const float* __restrict__ lnb, const float* __restrict__ W2,
    const float* __restrict__ b2,
    float* __restrict__ gateb) {
  __shared__ unsigned short Ab[64*136];
  __shared__ unsigned short Wl[64*136];
  const int t = threadIdx.x;
  const int nb = blockIdx.x * 64;
#pragma unroll
  for (int i = 0; i < 4; ++i) {
    int chunk = t + i*256;
    int n = chunk >> 4, c8 = chunk & 15;
    int gn = nb + n;
    bf16x8 v = {0,0,0,0,0,0,0,0};
    if (gn < N_NODESC) v = *(const bf16x8*)&Hb[gn*HIDC + c8*8];
    *(bf16x8*)&Ab[n*136 + c8*8] = v;
  }
#pragma unroll
  for (int i = 0; i < 8; ++i) {
    int q = t + i*256;
    int f = q >> 5, c4 = q & 31;
    float4 v = *(const float4*)&W1[f*HIDC + c4*4];
    ushort4 h;
    h.x = f2bf(v.x); h.y = f2bf(v.y); h.z = f2bf(v.z); h.w = f2bf(v.w);
    *(ushort4*)&Wl[f*136 + c4*4] = h;
  }
  __syncthreads();

  const int lane = t & 63, wv = t >> 6;
  const int quad = lane >> 4, l16 = lane & 15;
  f32x4 acc[4];
#pragma unroll
  for (int ft = 0; ft < 4; ++ft) acc[ft] = (f32x4){0.f,0.f,0.f,0.f};

  const int arow = (wv*16 + l16)*136 + quad*8;
#pragma unroll
  for (int ks = 0; ks < 4; ++ks) {
    bf16x8 a = *(const bf16x8*)(const void*)&Ab[arow + ks*32];
#pragma unroll
    for (int ft = 0; ft < 4; ++ft) {
      bf16x8 b = *(const bf16x8*)(const void*)&Wl[(ft*16 + l16)*136 + quad*8 + ks*32];
      acc[ft] = __builtin_amdgcn_mfma_f32_16x16x32_bf16(a, b, acc[ft], 0, 0, 0);
    }
  }

  float bb[4], gg[4], bee[4], w2v[4];
#pragma unroll
  for (int ft = 0; ft < 4; ++ft) {
    int f = ft*16 + l16;
    bb[ft] = b1[f]; gg[ft] = lng[f]; bee[ft] = lnb[f]; w2v[ft] = W2[f];
  }
  float s1[4] = {0,0,0,0}, s2[4] = {0,0,0,0};
#pragma unroll
  for (int ft = 0; ft < 4; ++ft)
#pragma unroll
    for (int r = 0; r < 4; ++r) {
      float v = fmaxf(acc[ft][r] + bb[ft], 0.f);
      acc[ft][r] = v; s1[r] += v; s2[r] += v*v;
    }
#pragma unroll
  for (int m = 1; m < 16; m <<= 1)
#pragma unroll
    for (int r = 0; r < 4; ++r) {
      s1[r] += __shfl_xor(s1[r], m);
      s2[r] += __shfl_xor(s2[r], m);
    }
  float pd[4];
#pragma unroll
  for (int r = 0; r < 4; ++r) {
    float mu = s1[r] * (1.f/64.f);
    float var = fmaxf(s2[r] * (1.f/64.f) - mu*mu, 0.f);
    float rs = rsqrtf(var + LN_EPSF);
    float p = 0.f;
#pragma unroll
    for (int ft = 0; ft < 4; ++ft)
      p += ((acc[ft][r] - mu)*rs*gg[ft] + bee[ft]) * w2v[ft];
    pd[r] = p;
  }
#pragma unroll
  for (int m = 1; m < 16; m <<= 1)
#pragma unroll
    for (int r = 0; r < 4; ++r) pd[r] += __shfl_xor(pd[r], m);
  if (l16 == 0) {
    float b2v = b2[0];
#pragma unroll
    for (int r = 0; r < 4; ++r) {
      int node = nb + wv*16 + quad*4 + r;
      if (node < N_NODESC) gateb[node] = pd[r] + b2v;
    }
  }
}

// ---------- segmented per-graph max of gateb ----------
__global__ __launch_bounds__(256) void gmax_kernel(const float* __restrict__ gateb,
    const int* __restrict__ gstart, unsigned* __restrict__ gmaxu) {
  const int g    = blockIdx.x / POOL_SPLIT;
  const int part = blockIdx.x % POOL_SPLIT;
  const int s0 = gstart[g], s1 = gstart[g+1];
  const int cnt = s1 - s0;
  const int chunk = (cnt + POOL_SPLIT - 1) / POOL_SPLIT;
  int lo = s0 + part * chunk;
  int hi = lo + chunk; if (hi > s1) hi = s1;
  const int t = threadIdx.x;
  float m = -3.4e38f;
  for (int n = lo + t; n < hi; n += 256) m = fmaxf(m, gateb[n]);
  __shared__ float sm[256];
  sm[t] = m;
  __syncthreads();
#pragma unroll
  for (int off = 128; off >= 1; off >>= 1) {
    if (t < off) sm[t] = fmaxf(sm[t], sm[t + off]);
    __syncthreads();
  }
  if (t == 0 && sm[0] > -3.4e38f) atomicMax(&gmaxu[g], ord_enc(sm[0]));
}

// ---------- segmented softmax-weighted pooling (bf16 H) ----------
// 16 lanes per node (16B each), 16 nodes in flight per block.
__global__ __launch_bounds__(256) void pool_kernel(const unsigned short* __restrict__ Hb,
    const float* __restrict__ gateb, const int* __restrict__ gstart,
    const unsigned* __restrict__ gmaxu, float* __restrict__ S,
    float* __restrict__ denom) {
  const int g    = blockIdx.x / POOL_SPLIT;
  const int part = blockIdx.x % POOL_SPLIT;
  const int s0 = gstart[g], s1 = gstart[g+1];
  const int cnt = s1 - s0;
  const int chunk = (cnt + POOL_SPLIT - 1) / POOL_SPLIT;
  int lo = s0 + part * chunk;
  int hi = lo + chunk; if (hi > s1) hi = s1;
  const int t = threadIdx.x;
  const int c8 = t & 15;   // 16B chunk (features c8*8 .. +7)
  const int v  = t >> 4;   // node subgroup 0..15
  const float gm = ord_dec(gmaxu[g]);
  float acc[8];
#pragma unroll
  for (int k = 0; k < 8; ++k) acc[k] = 0.f;
  float de = 0.f;
  for (int n = lo + v; n < hi; n += 16) {
    float e = expf(gateb[n] - gm);
    bf16x8 hv = *(const bf16x8*)&Hb[n*HIDC + c8*8];
#pragma unroll
    for (int k = 0; k < 8; ++k) acc[k] += e * bf2f((unsigned short)hv[k]);
    if (c8 == 0) de += e;
  }
  __shared__ float sacc[16*128];
  __shared__ float sden[16];
#pragma unroll
  for (int k = 0; k < 8; ++k) sacc[v*128 + c8*8 + k] = acc[k];
  if (c8 == 0) sden[v] = de;
  __syncthreads();
  if (t < 128) {
    float s = 0.f;
#pragma unroll
    for (int vv = 0; vv < 16; ++vv) s += sacc[vv*128 + t];
    atomicAdd(&S[g*HIDC + t], s);
  }
  if (t == 0) {
    float d = 0.f;
#pragma unroll
    for (int vv = 0; vv < 16; ++vv) d += sden[vv];
    atomicAdd(&denom[g], d);
  }
}

// ---------- head MLP per graph ----------
__global__ __launch_bounds__(64) void head_kernel(const float* __restrict__ S,
    const float* __restrict__ denom, const float* __restrict__ W1,
    const float* __restrict__ b1, const float* __restrict__ g,
    const float* __restrict__ be, const float* __restrict__ W2,
    const float* __restrict__ b2, float* __restrict__ out) {
  const int gr = blockIdx.x;
  const int j = threadIdx.x;
  const float inv = 1.0f / denom[gr];
  float v = b1[j];
  for (int k = 0; k < HIDC; ++k) v += (S[gr*HIDC + k] * inv) * W1[j*HIDC + k];
  v = fmaxf(v, 0.f);
  float s1 = v, s2 = v*v;
  for (int off = 32; off; off >>= 1) { s1 += __shfl_xor(s1, off); s2 += __shfl_xor(s2, off); }
  float mu = s1 * (1.f/64.f);
  float var = fmaxf(s2 * (1.f/64.f) - mu*mu, 0.f);
  float rs = rsqrtf(var + LN_EPSF);
  float z = (v-mu)*rs*g[j] + be[j];
  float p = z * W2[j];
  for (int off = 32; off; off >>= 1) p += __shfl_xor(p, off);
  if (j == 0) out[gr] = p + b2[0];
}

// ---------- launch ----------
extern "C" void kernel_launch(void* const* d_in, const int* in_sizes, int n_in,
                              void* d_out, int out_size, void* d_ws, size_t ws_size,
                              hipStream_t stream) {
  (void)in_sizes; (void)n_in; (void)out_size; (void)ws_size;
  const float* x     = (const float*)d_in[0];
  const int*   ei    = (const int*)d_in[1];
  const int*   batch = (const int*)d_in[2];
  const float* aW1 = (const float*)d_in[3];
  const float* ab1 = (const float*)d_in[4];
  const float* ag  = (const float*)d_in[5];
  const float* abe = (const float*)d_in[6];
  const float* aW2 = (const float*)d_in[7];
  const float* ab2 = (const float*)d_in[8];
  const float* oW1 = (const float*)d_in[9];
  const float* ob1 = (const float*)d_in[10];
  const float* og  = (const float*)d_in[11];
  const float* obe = (const float*)d_in[12];
  const float* oW2 = (const float*)d_in[13];
  const float* ob2 = (const float*)d_in[14];
  const float* ninW = (const float*)d_in[15];
  const float* ninb = (const float*)d_in[16];
  const float* cW1 = (const float*)d_in[17];
  const float* cb1 = (const float*)d_in[18];
  const float* cg  = (const float*)d_in[19];
  const float* cbe = (const float*)d_in[20];
  const float* cW2 = (const float*)d_in[21];
  const float* cb2 = (const float*)d_in[22];
  const float* eps = (const float*)d_in[23];
  const float* lng = (const float*)d_in[24];
  const float* lnb = (const float*)d_in[25];
  const float* gW1 = (const float*)d_in[26];
  const float* gb1 = (const float*)d_in[27];
  const float* gg  = (const float*)d_in[28];
  const float* gbe = (const float*)d_in[29];
  const float* gW2 = (const float*)d_in[30];
  const float* gb2 = (const float*)d_in[31];
  const float* hW1 = (const float*)d_in[32];
  const float* hb1 = (const float*)d_in[33];
  const float* hg  = (const float*)d_in[34];
  const float* hbe = (const float*)d_in[35];
  const float* hW2 = (const float*)d_in[36];
  const float* hb2 = (const float*)d_in[37];

  char* ws = (char*)d_ws;
  unsigned short* Hb = (unsigned short*)(ws + 0);          // 12,800,000 B
  unsigned short* Tb = (unsigned short*)(ws + 12800000);   // 12,800,000 B
  unsigned short* Mb = (unsigned short*)(ws + 25600000);   // 12,800,000 B
  float* gateb = (float*)(ws + 38400000);                  // 200,000 B
  float* S     = (float*)(ws + 38600000);                  // 32,768 B
  float* denom = (float*)(ws + 38632768);                  // 256 B
  unsigned* gmaxu = (unsigned*)(ws + 38633024);            // 256 B
  int* deg     = (int*)(ws + 38633280);                    // 200,000 B
  int* rowptr  = (int*)(ws + 38833280);                    // 200,004 B
  int* cursor  = (int*)(ws + 39033284);                    // 200,000 B
  int* esrc    = (int*)(ws + 39233284);                    // 2,560,000 B
  int* bsum    = (int*)(ws + 41793284);                    // 256 B
  int* gstart  = cursor;  // alias: cursor dead after scatter_kernel

  hipMemsetAsync(deg, 0, 200000, stream);
  hipMemsetAsync(S, 0, 33280, stream);  // S + denom + gmaxu contiguous

  const int egrid = (N_EDGESC + 255) / 256;
  hist_kernel<<<egrid, 256, 0, stream>>>(ei, deg);
  scan1_kernel<<<SCAN_NB, 1024, 0, stream>>>(deg, rowptr, bsum);
  scan2_kernel<<<1, 64, 0, stream>>>(bsum, rowptr);
  scan3_kernel<<<SCAN_NB, 1024, 0, stream>>>(deg, bsum, rowptr, cursor);
  scatter_kernel<<<egrid, 256, 0, stream>>>(ei, cursor, esrc);
  gbound_kernel<<<(N_NODESC + 255) / 256, 256, 0, stream>>>(batch, gstart);

  const int ngrid64 = (N_NODESC + 63) / 64;
  enc_kernel<<<ngrid64, 128, 0, stream>>>(x, aW1, ab1, ag, abe, aW2, ab2,
                                          oW1, ob1, og, obe, oW2, ob2,
                                          ninW, ninb, Hb);
  for (int l = 0; l < 3; ++l) {
    agg_kernel<<<(N_NODESC + 7) / 8, 128, 0, stream>>>(Hb, rowptr, esrc, eps + l, Mb);
    gemm_mfma_kernel<<<ngrid64, 256, 0, stream>>>(Mb, cW1 + l*HIDC*HIDC, cb1 + l*HIDC,
                                                  cg + l*HIDC, cbe + l*HIDC, nullptr, Tb);
    gemm_mfma_kernel<<<ngrid64, 256, 0, stream>>>(Tb, cW2 + l*HIDC*HIDC, cb2 + l*HIDC,
                                                  lng + l*HIDC, lnb + l*HIDC, Hb, Hb);
  }
  gate_mfma_kernel<<<ngrid64, 256, 0, stream>>>(Hb, gW1, gb1, gg, gbe, gW2, gb2, gateb);
  gmax_kernel<<<N_GRAPHSC * POOL_SPLIT, 256, 0, stream>>>(gateb, gstart, gmaxu);
  pool_kernel<<<N_GRAPHSC * POOL_SPLIT, 256, 0, stream>>>(Hb, gateb, gstart, gmaxu, S, denom);
  head_kernel<<<N_GRAPHSC, 64, 0, stream>>>(S, denom, hW1, hb1, hg, hbe, hW2, hb2,
                                            (float*)d_out);
}

// Round 7
// 419.788 us; speedup vs baseline: 3.0643x; 1.0008x over previous
//
#include <hip/hip_runtime.h>

#define N_NODESC 50000
#define N_EDGESC 640000
#define N_GRAPHSC 64
#define HIDC 128
#define LN_EPSF 1e-5f
#define POOL_SPLIT 16
#define SCAN_NB 49   // 49*1024 = 50176 >= 50000
#define EGRID ((N_EDGESC + 255) / 256)
#define NGRID_GB ((N_NODESC + 255) / 256)

typedef short bf16x8 __attribute__((ext_vector_type(8)));
typedef float f32x4 __attribute__((ext_vector_type(4)));

// ---------- helpers ----------
static __device__ __forceinline__ unsigned ord_enc(float f) {
  unsigned u = __float_as_uint(f);
  return (u & 0x80000000u) ? ~u : (u | 0x80000000u);
}
static __device__ __forceinline__ float ord_dec(unsigned u) {
  return __uint_as_float((u & 0x80000000u) ? (u ^ 0x80000000u) : ~u);
}
static __device__ __forceinline__ unsigned short f2bf(float x) {
  unsigned u = __float_as_uint(x);
  u += 0x7fffu + ((u >> 16) & 1u);
  return (unsigned short)(u >> 16);
}
static __device__ __forceinline__ float bf2f(unsigned short b) {
  return __uint_as_float(((unsigned)b) << 16);
}

static __device__ __forceinline__ void mlp16(float in0, float in1, float in2,
    const float* __restrict__ W1, const float* __restrict__ b1,
    const float* __restrict__ g, const float* __restrict__ be,
    const float* __restrict__ W2, const float* __restrict__ b2,
    float* __restrict__ out) {
  float h[16];
  float s1 = 0.f, s2 = 0.f;
#pragma unroll
  for (int j = 0; j < 16; ++j) {
    float v = b1[j] + W1[j*3+0]*in0 + W1[j*3+1]*in1 + W1[j*3+2]*in2;
    v = fmaxf(v, 0.f);
    h[j] = v; s1 += v; s2 += v*v;
  }
  float mu = s1 * (1.f/16.f);
  float var = fmaxf(s2 * (1.f/16.f) - mu*mu, 0.f);
  float rs = rsqrtf(var + LN_EPSF);
  float z[16];
#pragma unroll
  for (int j = 0; j < 16; ++j) z[j] = (h[j]-mu)*rs*g[j] + be[j];
#pragma unroll
  for (int j = 0; j < 16; ++j) {
    float v = b2[j];
#pragma unroll
    for (int k = 0; k < 16; ++k) v += W2[j*16+k]*z[k];
    out[j] = v;
  }
}

// ---------- hist (edges) + gbound (nodes) in one dispatch ----------
__global__ __launch_bounds__(256) void hist_gbound_kernel(const int* __restrict__ ei,
    int* __restrict__ deg, const int* __restrict__ batch, int* __restrict__ gstart) {
  const int b = blockIdx.x;
  if (b < EGRID) {
    int e = b * 256 + threadIdx.x;
    if (e < N_EDGESC) atomicAdd(&deg[ei[N_EDGESC + e]], 1);
  } else {
    int i = (b - EGRID) * 256 + threadIdx.x;
    if (i >= N_NODESC) return;
    int bb = batch[i];
    int prev = (i == 0) ? -1 : batch[i-1];
    for (int g = prev + 1; g <= bb; ++g) gstart[g] = i;
    if (i == N_NODESC - 1) {
      for (int g = bb + 1; g <= N_GRAPHSC; ++g) gstart[g] = N_NODESC;
    }
  }
}

// ---------- scan phase 1: per-block inclusive scan + block sums ----------
__global__ __launch_bounds__(1024) void scan1_kernel(const int* __restrict__ deg,
                                                     int* __restrict__ incl,
                                                     int* __restrict__ bsum) {
  const int b = blockIdx.x, t = threadIdx.x;
  const int i = b * 1024 + t;
  const int lane = t & 63, w = t >> 6;
  int v = (i < N_NODESC) ? deg[i] : 0;
#pragma unroll
  for (int off = 1; off < 64; off <<= 1) {
    int n = __shfl_up(v, off);
    if (lane >= off) v += n;
  }
  __shared__ int wsum[16];
  if (lane == 63) wsum[w] = v;
  __syncthreads();
  if (t == 0) {
    int run = 0;
#pragma unroll
    for (int k = 0; k < 16; ++k) { int x = wsum[k]; wsum[k] = run; run += x; }
  }
  __syncthreads();
  v += wsum[w];
  if (i < N_NODESC) incl[i] = v;
  if (t == 1023) bsum[b] = v;
}

// ---------- scan phases 2+3 fused: each block re-scans the 49 block sums ----------
__global__ __launch_bounds__(1024) void scan23_kernel(const int* __restrict__ deg,
                                                      const int* __restrict__ bsum,
                                                      int* __restrict__ rowptr,
                                                      int* __restrict__ cursor) {
  __shared__ int ex[SCAN_NB + 1];
  const int b = blockIdx.x, t = threadIdx.x;
  if (t < 64) {
    int v = (t < SCAN_NB) ? bsum[t] : 0;
    const int orig = v;
#pragma unroll
    for (int off = 1; off < 64; off <<= 1) {
      int n = __shfl_up(v, off);
      if (t >= off) v += n;
    }
    if (t < SCAN_NB) ex[t] = v - orig;
    if (t == SCAN_NB - 1) ex[SCAN_NB] = v;   // grand total
  }
  __syncthreads();
  const int i = b * 1024 + t;
  if (i < N_NODESC) {
    int excl = rowptr[i] - deg[i] + ex[b];
    rowptr[i] = excl;
    cursor[i] = excl;
  }
  if (b == 0 && t == 0) rowptr[N_NODESC] = ex[SCAN_NB];
}

__global__ __launch_bounds__(256) void scatter_kernel(const int* __restrict__ ei,
                                                      int* __restrict__ cursor,
                                                      int* __restrict__ esrc) {
  int e = blockIdx.x * 256 + threadIdx.x;
  if (e < N_EDGESC) {
    int d = ei[N_EDGESC + e];
    int slot = atomicAdd(&cursor[d], 1);
    esrc[slot] = ei[e];
  }
}

// ---------- encoder: small MLPs + 45->128 projection; output bf16 ----------
__global__ __launch_bounds__(128) void enc_kernel(
    const float* __restrict__ x,
    const float* __restrict__ aW1, const float* __restrict__ ab1,
    const float* __restrict__ ag,  const float* __restrict__ abe,
    const float* __restrict__ aW2, const float* __restrict__ ab2,
    const float* __restrict__ oW1, const float* __restrict__ ob1,
    const float* __restrict__ og,  const float* __restrict__ obe,
    const float* __restrict__ oW2, const float* __restrict__ ob2,
    const float* __restrict__ ninW, const float* __restrict__ ninb,
    unsigned short* __restrict__ Hb) {
  __shared__ float sa[48*68];
  __shared__ float sw[48*132];
  const int t = threadIdx.x;
  const int lane = t & 63, w = t >> 6;
  const int nb = blockIdx.x * 64;

  if (t < 64) {
    float in45[45];
    const int gn = nb + t;
    if (gn < N_NODESC) {
      const float* xr = x + gn * 19;
#pragma unroll
      for (int k = 0; k < 9; ++k) in45[k] = xr[k];
#pragma unroll
      for (int k = 0; k < 4; ++k) in45[9+k] = xr[15+k];
      mlp16(xr[9], xr[10], xr[11], aW1, ab1, ag, abe, aW2, ab2, &in45[13]);
      mlp16(xr[12], xr[13], xr[14], oW1, ob1, og, obe, oW2, ob2, &in45[29]);
    } else {
#pragma unroll
      for (int k = 0; k < 45; ++k) in45[k] = 0.f;
    }
#pragma unroll
    for (int k = 0; k < 45; ++k) sa[k*68 + t] = in45[k];
#pragma unroll
    for (int k = 45; k < 48; ++k) sa[k*68 + t] = 0.f;
  }
  for (int idx = t; idx < 48*128; idx += 128) {
    int k = idx >> 7, f = idx & 127;
    sw[k*132 + f] = (k < 45) ? ninW[f*45 + k] : 0.f;
  }
  __syncthreads();

  const int n0 = (lane & 7) * 8;
  const int f0 = ((lane >> 3) << 3) + w * 64;
  float acc[8][8];
#pragma unroll
  for (int i = 0; i < 8; ++i)
#pragma unroll
    for (int j = 0; j < 8; ++j) acc[i][j] = 0.f;

#pragma unroll 4
  for (int k = 0; k < 48; ++k) {
    float av[8], wv[8];
    float4 a0 = *(const float4*)&sa[k*68 + n0];
    float4 a1 = *(const float4*)&sa[k*68 + n0 + 4];
    float4 w0 = *(const float4*)&sw[k*132 + f0];
    float4 w1 = *(const float4*)&sw[k*132 + f0 + 4];
    av[0]=a0.x; av[1]=a0.y; av[2]=a0.z; av[3]=a0.w;
    av[4]=a1.x; av[5]=a1.y; av[6]=a1.z; av[7]=a1.w;
    wv[0]=w0.x; wv[1]=w0.y; wv[2]=w0.z; wv[3]=w0.w;
    wv[4]=w1.x; wv[5]=w1.y; wv[6]=w1.z; wv[7]=w1.w;
#pragma unroll
    for (int i = 0; i < 8; ++i)
#pragma unroll
      for (int j = 0; j < 8; ++j) acc[i][j] += av[i]*wv[j];
  }
  float bb[8];
#pragma unroll
  for (int j = 0; j < 8; ++j) bb[j] = ninb[f0+j];
#pragma unroll
  for (int i = 0; i < 8; ++i) {
    int gn = nb + n0 + i;
    if (gn < N_NODESC) {
      bf16x8 o8;
#pragma unroll
      for (int j = 0; j < 8; ++j) o8[j] = (short)f2bf(acc[i][j] + bb[j]);
      *(bf16x8*)&Hb[gn*HIDC + f0] = o8;
    }
  }
}

// ---------- fused conv layer: gather + GEMM1 + LN + GEMM2 + LN + resid ----------
// One block = 64 nodes. Hin is read-only (prev layer), Hout separate (ping-pong).
__global__ __launch_bounds__(256, 2) void conv_fused_kernel(
    const unsigned short* __restrict__ Hin,
    const int* __restrict__ rowptr, const int* __restrict__ esrc,
    const float* __restrict__ epsp,
    const float* __restrict__ W1, const float* __restrict__ b1,
    const float* __restrict__ g1, const float* __restrict__ be1,
    const float* __restrict__ W2, const float* __restrict__ b2,
    const float* __restrict__ lng, const float* __restrict__ lnb,
    unsigned short* __restrict__ Hout) {
  __shared__ unsigned short Ab[64*136];   // M tile, then T tile, then OUT tile
  __shared__ unsigned short Wl[128*136];  // W1 then W2
  const int t = threadIdx.x;
  const int nb = blockIdx.x * 64;

  // stage W1 (fp32 -> bf16)
#pragma unroll
  for (int i = 0; i < 16; ++i) {
    int q = t + i*256;
    int f = q >> 5, c4 = q & 31;
    float4 v = *(const float4*)&W1[f*HIDC + c4*4];
    ushort4 h;
    h.x = f2bf(v.x); h.y = f2bf(v.y); h.z = f2bf(v.z); h.w = f2bf(v.w);
    *(ushort4*)&Wl[f*136 + c4*4] = h;
  }

  // gather phase: M = (1+eps)*Hin[node] + sum Hin[src]; 16 lanes/node, 16 nodes/pass
  {
    const float e1 = 1.0f + epsp[0];
    const int c8 = t & 15, v16 = t >> 4;
#pragma unroll
    for (int grp = 0; grp < 4; ++grp) {
      const int nloc = grp*16 + v16;
      const int node = nb + nloc;
      bf16x8 m8 = {0,0,0,0,0,0,0,0};
      if (node < N_NODESC) {
        bf16x8 h = *(const bf16x8*)&Hin[node*HIDC + c8*8];
        float acc[8];
#pragma unroll
        for (int k = 0; k < 8; ++k) acc[k] = 0.f;
        int s = rowptr[node];
        const int e = rowptr[node+1];
        for (; s + 4 <= e; s += 4) {
          int i0 = esrc[s], i1 = esrc[s+1], i2 = esrc[s+2], i3 = esrc[s+3];
          bf16x8 x0 = *(const bf16x8*)&Hin[i0*HIDC + c8*8];
          bf16x8 x1 = *(const bf16x8*)&Hin[i1*HIDC + c8*8];
          bf16x8 x2 = *(const bf16x8*)&Hin[i2*HIDC + c8*8];
          bf16x8 x3 = *(const bf16x8*)&Hin[i3*HIDC + c8*8];
#pragma unroll
          for (int k = 0; k < 8; ++k)
            acc[k] += (bf2f((unsigned short)x0[k]) + bf2f((unsigned short)x1[k]))
                    + (bf2f((unsigned short)x2[k]) + bf2f((unsigned short)x3[k]));
        }
        for (; s < e; ++s) {
          bf16x8 x0 = *(const bf16x8*)&Hin[esrc[s]*HIDC + c8*8];
#pragma unroll
          for (int k = 0; k < 8; ++k) acc[k] += bf2f((unsigned short)x0[k]);
        }
#pragma unroll
        for (int k = 0; k < 8; ++k)
          m8[k] = (short)f2bf(e1*bf2f((unsigned short)h[k]) + acc[k]);
      }
      *(bf16x8*)&Ab[nloc*136 + c8*8] = m8;
    }
  }
  __syncthreads();

  const int lane = t & 63, wv = t >> 6;
  const int quad = lane >> 4, l16 = lane & 15;
  const int arow = (wv*16 + l16)*136 + quad*8;

  // MFMA loop 1: M @ W1^T
  f32x4 acc[8];
#pragma unroll
  for (int ft = 0; ft < 8; ++ft) acc[ft] = (f32x4){0.f,0.f,0.f,0.f};
#pragma unroll
  for (int ks = 0; ks < 4; ++ks) {
    bf16x8 a = *(const bf16x8*)(const void*)&Ab[arow + ks*32];
#pragma unroll
    for (int ft = 0; ft < 8; ++ft) {
      bf16x8 b = *(const bf16x8*)(const void*)&Wl[(ft*16 + l16)*136 + quad*8 + ks*32];
      acc[ft] = __builtin_amdgcn_mfma_f32_16x16x32_bf16(a, b, acc[ft], 0, 0, 0);
    }
  }

  // epilogue 1: bias1 + relu + LN(g1, be1) -> T (registers)
  {
    float bb[8], gg[8], bee[8];
#pragma unroll
    for (int ft = 0; ft < 8; ++ft) {
      int f = ft*16 + l16;
      bb[ft] = b1[f]; gg[ft] = g1[f]; bee[ft] = be1[f];
    }
    float s1[4] = {0,0,0,0}, s2[4] = {0,0,0,0};
#pragma unroll
    for (int ft = 0; ft < 8; ++ft)
#pragma unroll
      for (int r = 0; r < 4; ++r) {
        float v = fmaxf(acc[ft][r] + bb[ft], 0.f);
        acc[ft][r] = v; s1[r] += v; s2[r] += v*v;
      }
#pragma unroll
    for (int m = 1; m < 16; m <<= 1)
#pragma unroll
      for (int r = 0; r < 4; ++r) {
        s1[r] += __shfl_xor(s1[r], m);
        s2[r] += __shfl_xor(s2[r], m);
      }
    float mu[4], rs[4];
#pragma unroll
    for (int r = 0; r < 4; ++r) {
      mu[r] = s1[r] * (1.f/128.f);
      float var = fmaxf(s2[r] * (1.f/128.f) - mu[r]*mu[r], 0.f);
      rs[r] = rsqrtf(var + LN_EPSF);
    }
    __syncthreads();  // all loop-1 reads of Ab/Wl done
    // write T tile into Ab (bf16)
#pragma unroll
    for (int r = 0; r < 4; ++r) {
      int nloc = wv*16 + quad*4 + r;
#pragma unroll
      for (int ft = 0; ft < 8; ++ft) {
        float o = (acc[ft][r] - mu[r])*rs[r]*gg[ft] + bee[ft];
        Ab[nloc*136 + ft*16 + l16] = f2bf(o);
      }
    }
  }
  // restage Wl = W2
#pragma unroll
  for (int i = 0; i < 16; ++i) {
    int q = t + i*256;
    int f = q >> 5, c4 = q & 31;
    float4 v = *(const float4*)&W2[f*HIDC + c4*4];
    ushort4 h;
    h.x = f2bf(v.x); h.y = f2bf(v.y); h.z = f2bf(v.z); h.w = f2bf(v.w);
    *(ushort4*)&Wl[f*136 + c4*4] = h;
  }
  __syncthreads();

  // MFMA loop 2: T @ W2^T
#pragma unroll
  for (int ft = 0; ft < 8; ++ft) acc[ft] = (f32x4){0.f,0.f,0.f,0.f};
#pragma unroll
  for (int ks = 0; ks < 4; ++ks) {
    bf16x8 a = *(const bf16x8*)(const void*)&Ab[arow + ks*32];
#pragma unroll
    for (int ft = 0; ft < 8; ++ft) {
      bf16x8 b = *(const bf16x8*)(const void*)&Wl[(ft*16 + l16)*136 + quad*8 + ks*32];
      acc[ft] = __builtin_amdgcn_mfma_f32_16x16x32_bf16(a, b, acc[ft], 0, 0, 0);
    }
  }

  // epilogue 2: bias2 + relu + LN(lng, lnb) -> Ab, then +resid -> Hout
  {
    float bb[8], gg[8], bee[8];
#pragma unroll
    for (int ft = 0; ft < 8; ++ft) {
      int f = ft*16 + l16;
      bb[ft] = b2[f]; gg[ft] = lng[f]; bee[ft] = lnb[f];
    }
    float s1[4] = {0,0,0,0}, s2[4] = {0,0,0,0};
#pragma unroll
    for (int ft = 0; ft < 8; ++ft)
#pragma unroll
      for (int r = 0; r < 4; ++r) {
        float v = fmaxf(acc[ft][r] + bb[ft], 0.f);
        acc[ft][r] = v; s1[r] += v; s2[r] += v*v;
      }
#pragma unroll
    for (int m = 1; m < 16; m <<= 1)
#pragma unroll
      for (int r = 0; r < 4; ++r) {
        s1[r] += __shfl_xor(s1[r], m);
        s2[r] += __shfl_xor(s2[r], m);
      }
    float mu[4], rs[4];
#pragma unroll
    for (int r = 0; r < 4; ++r) {
      mu[r] = s1[r] * (1.f/128.f);
      float var = fmaxf(s2[r] * (1.f/128.f) - mu[r]*mu[r], 0.f);
      rs[r] = rsqrtf(var + LN_EPSF);
    }
    __syncthreads();  // all loop-2 reads of Ab done
#pragma unroll
    for (int r = 0; r < 4; ++r) {
      int nloc = wv*16 + quad*4 + r;
#pragma unroll
      for (int ft = 0; ft < 8; ++ft) {
        float o = (acc[ft][r] - mu[r])*rs[r]*gg[ft] + bee[ft];
        Ab[nloc*136 + ft*16 + l16] = f2bf(o);
      }
    }
  }
  __syncthreads();
  // final store: + residual (Hin row), coalesced 16B chunks
#pragma unroll
  for (int i = 0; i < 4; ++i) {
    int chunk = t + i*256;
    int n = chunk >> 4, cc = chunk & 15;
    int gn = nb + n;
    if (gn >= N_NODESC) continue;
    bf16x8 vv = *(const bf16x8*)&Ab[n*136 + cc*8];
    bf16x8 rr = *(const bf16x8*)&Hin[gn*HIDC + cc*8];
    bf16x8 o8;
#pragma unroll
    for (int k = 0; k < 8; ++k)
      o8[k] = (short)f2bf(bf2f((unsigned short)vv[k]) + bf2f((unsigned short)rr[k]));
    *(bf16x8*)&Hout[gn*HIDC + cc*8] = o8;
  }
}

// ---------- MFMA gate (bf16 in) + inline per-graph max ----------
__global__ __launch_bounds__(256, 2) void gate_mfma_kernel(
    const unsigned short* __restrict__ Hb, const float* __restrict__ W1,
    const float* __restrict__ b1, const float* __restrict__ lng,
    const float* __restrict__ lnb, const float* __restrict__ W2,
    const float* __restrict__ b2, const int* __restrict__ batch,
    float* __restrict__ gateb, unsigned* __restrict__ gmaxu) {
  __shared__ unsigned short Ab[64*136];
  __shared__ unsigned short Wl[64*136];
  __shared__ unsigned sgm[N_GRAPHSC];
  const int t = threadIdx.x;
  const int nb = blockIdx.x * 64;
  if (t < N_GRAPHSC) sgm[t] = 0u;
#pragma unroll
  for (int i = 0; i < 4; ++i) {
    int chunk = t + i*256;
    int n = chunk >> 4, c8 = chunk & 15;
    int gn = nb + n;
    bf16x8 v = {0,0,0,0,0,0,0,0};
    if (gn < N_NODESC) v = *(const bf16x8*)&Hb[gn*HIDC + c8*8];
    *(bf16x8*)&Ab[n*136 + c8*8] = v;
  }
#pragma unroll
  for (int i = 0; i < 8; ++i) {
    int q = t + i*256;
    int f = q >> 5, c4 = q & 31;
    float4 v = *(const float4*)&W1[f*HIDC + c4*4];
    ushort4 h;
    h.x = f2bf(v.x); h.y = f2bf(v.y); h.z = f2bf(v.z); h.w = f2bf(v.w);
    *(ushort4*)&Wl[f*136 + c4*4] = h;
  }
  __syncthreads();

  const int lane = t & 63, wv = t >> 6;
  const int quad = lane >> 4, l16 = lane & 15;
  f32x4 acc[4];
#pragma unroll
  for (int ft = 0; ft < 4; ++ft) acc[ft] = (f32x4){0.f,0.f,0.f,0.f};

  const int arow = (wv*16 + l16)*136 + quad*8;
#pragma unroll
  for (int ks = 0; ks < 4; ++ks) {
    bf16x8 a = *(const bf16x8*)(const void*)&Ab[arow + ks*32];
#pragma unroll
    for (int ft = 0; ft < 4; ++ft) {
      bf16x8 b = *(const bf16x8*)(const void*)&Wl[(ft*16 + l16)*136 + quad*8 + ks*32];
      acc[ft] = __builtin_amdgcn_mfma_f32_16x16x32_bf16(a, b, acc[ft], 0, 0, 0);
    }
  }

  float bb[4], gg[4], bee[4], w2v[4];
#pragma unroll
  for (int ft = 0; ft < 4; ++ft) {
    int f = ft*16 + l16;
    bb[ft] = b1[f]; gg[ft] = lng[f]; bee[ft] = lnb[f]; w2v[ft] = W2[f];
  }
  float s1[4] = {0,0,0,0}, s2[4] = {0,0,0,0};
#pragma unroll
  for (int ft = 0; ft < 4; ++ft)
#pragma unroll
    for (int r = 0; r < 4; ++r) {
      float v = fmaxf(acc[ft][r] + bb[ft], 0.f);
      acc[ft][r] = v; s1[r] += v; s2[r] += v*v;
    }
#pragma unroll
  for (int m = 1; m < 16; m <<= 1)
#pragma unroll
    for (int r = 0; r < 4; ++r) {
      s1[r] += __shfl_xor(s1[r], m);
      s2[r] += __shfl_xor(s2[r], m);
    }
  float pd[4];
#pragma unroll
  for (int r = 0; r < 4; ++r) {
    float mu = s1[r] * (1.f/64.f);
    float var = fmaxf(s2[r] * (1.f/64.f) - mu*mu, 0.f);
    float rs = rsqrtf(var + LN_EPSF);
    float p = 0.f;
#pragma unroll
    for (int ft = 0; ft < 4; ++ft)
      p += ((acc[ft][r] - mu)*rs*gg[ft] + bee[ft]) * w2v[ft];
    pd[r] = p;
  }
#pragma unroll
  for (int m = 1; m < 16; m <<= 1)
#pragma unroll
    for (int r = 0; r < 4; ++r) pd[r] += __shfl_xor(pd[r], m);
  if (l16 == 0) {
    float b2v = b2[0];
#pragma unroll
    for (int r = 0; r < 4; ++r) {
      int node = nb + wv*16 + quad*4 + r;
      if (node < N_NODESC) {
        float gv = pd[r] + b2v;
        gateb[node] = gv;
        atomicMax(&sgm[batch[node]], ord_enc(gv));
      }
    }
  }
  __syncthreads();
  if (t < N_GRAPHSC && sgm[t] != 0u) atomicMax(&gmaxu[t], sgm[t]);
}

// ---------- segmented softmax-weighted pooling (bf16 H) ----------
__global__ __launch_bounds__(256) void pool_kernel(const unsigned short* __restrict__ Hb,
    const float* __restrict__ gateb, const int* __restrict__ gstart,
    const unsigned* __restrict__ gmaxu, float* __restrict__ S,
    float* __restrict__ denom) {
  const int g    = blockIdx.x / POOL_SPLIT;
  const int part = blockIdx.x % POOL_SPLIT;
  const int s0 = gstart[g], s1 = gstart[g+1];
  const int cnt = s1 - s0;
  const int chunk = (cnt + POOL_SPLIT - 1) / POOL_SPLIT;
  int lo = s0 + part * chunk;
  int hi = lo + chunk; if (hi > s1) hi = s1;
  const int t = threadIdx.x;
  const int c8 = t & 15;
  const int v  = t >> 4;
  const float gm = ord_dec(gmaxu[g]);
  float acc[8];
#pragma unroll
  for (int k = 0; k < 8; ++k) acc[k] = 0.f;
  float de = 0.f;
  for (int n = lo + v; n < hi; n += 16) {
    float e = expf(gateb[n] - gm);
    bf16x8 hv = *(const bf16x8*)&Hb[n*HIDC + c8*8];
#pragma unroll
    for (int k = 0; k < 8; ++k) acc[k] += e * bf2f((unsigned short)hv[k]);
    if (c8 == 0) de += e;
  }
  __shared__ float sacc[16*128];
  __shared__ float sden[16];
#pragma unroll
  for (int k = 0; k < 8; ++k) sacc[v*128 + c8*8 + k] = acc[k];
  if (c8 == 0) sden[v] = de;
  __syncthreads();
  if (t < 128) {
    float s = 0.f;
#pragma unroll
    for (int vv = 0; vv < 16; ++vv) s += sacc[vv*128 + t];
    atomicAdd(&S[g*HIDC + t], s);
  }
  if (t == 0) {
    float d = 0.f;
#pragma unroll
    for (int vv = 0; vv < 16; ++vv) d += sden[vv];
    atomicAdd(&denom[g], d);
  }
}

// ---------- head MLP per graph ----------
__global__ __launch_bounds__(64) void head_kernel(const float* __restrict__ S,
    const float* __restrict__ denom, const float* __restrict__ W1,
    const float* __restrict__ b1, const float* __restrict__ g,
    const float* __restrict__ be, const float* __restrict__ W2,
    const float* __restrict__ b2, float* __restrict__ out) {
  const int gr = blockIdx.x;
  const int j = threadIdx.x;
  const float inv = 1.0f / denom[gr];
  float v = b1[j];
  for (int k = 0; k < HIDC; ++k) v += (S[gr*HIDC + k] * inv) * W1[j*HIDC + k];
  v = fmaxf(v, 0.f);
  float s1 = v, s2 = v*v;
  for (int off = 32; off; off >>= 1) { s1 += __shfl_xor(s1, off); s2 += __shfl_xor(s2, off); }
  float mu = s1 * (1.f/64.f);
  float var = fmaxf(s2 * (1.f/64.f) - mu*mu, 0.f);
  float rs = rsqrtf(var + LN_EPSF);
  float z = (v-mu)*rs*g[j] + be[j];
  float p = z * W2[j];
  for (int off = 32; off; off >>= 1) p += __shfl_xor(p, off);
  if (j == 0) out[gr] = p + b2[0];
}

// ---------- launch ----------
extern "C" void kernel_launch(void* const* d_in, const int* in_sizes, int n_in,
                              void* d_out, int out_size, void* d_ws, size_t ws_size,
                              hipStream_t stream) {
  (void)in_sizes; (void)n_in; (void)out_size; (void)ws_size;
  const float* x     = (const float*)d_in[0];
  const int*   ei    = (const int*)d_in[1];
  const int*   batch = (const int*)d_in[2];
  const float* aW1 = (const float*)d_in[3];
  const float* ab1 = (const float*)d_in[4];
  const float* ag  = (const float*)d_in[5];
  const float* abe = (const float*)d_in[6];
  const float* aW2 = (const float*)d_in[7];
  const float* ab2 = (const float*)d_in[8];
  const float* oW1 = (const float*)d_in[9];
  const float* ob1 = (const float*)d_in[10];
  const float* og  = (const float*)d_in[11];
  const float* obe = (const float*)d_in[12];
  const float* oW2 = (const float*)d_in[13];
  const float* ob2 = (const float*)d_in[14];
  const float* ninW = (const float*)d_in[15];
  const float* ninb = (const float*)d_in[16];
  const float* cW1 = (const float*)d_in[17];
  const float* cb1 = (const float*)d_in[18];
  const float* cg  = (const float*)d_in[19];
  const float* cbe = (const float*)d_in[20];
  const float* cW2 = (const float*)d_in[21];
  const float* cb2 = (const float*)d_in[22];
  const float* eps = (const float*)d_in[23];
  const float* lng = (const float*)d_in[24];
  const float* lnb = (const float*)d_in[25];
  const float* gW1 = (const float*)d_in[26];
  const float* gb1 = (const float*)d_in[27];
  const float* gg  = (const float*)d_in[28];
  const float* gbe = (const float*)d_in[29];
  const float* gW2 = (const float*)d_in[30];
  const float* gb2 = (const float*)d_in[31];
  const float* hW1 = (const float*)d_in[32];
  const float* hb1 = (const float*)d_in[33];
  const float* hg  = (const float*)d_in[34];
  const float* hbe = (const float*)d_in[35];
  const float* hW2 = (const float*)d_in[36];
  const float* hb2 = (const float*)d_in[37];

  char* ws = (char*)d_ws;
  unsigned short* Ha = (unsigned short*)(ws + 0);          // 12,800,000 B
  unsigned short* Hc = (unsigned short*)(ws + 12800000);   // 12,800,000 B
  float* gateb = (float*)(ws + 25600000);                  // 200,000 B
  // --- contiguous zero region: deg | S | denom | gmaxu ---
  int*   deg   = (int*)(ws + 25800000);                    // 200,000 B
  float* S     = (float*)(ws + 26000000);                  // 32,768 B
  float* denom = (float*)(ws + 26032768);                  // 256 B
  unsigned* gmaxu = (unsigned*)(ws + 26033024);            // 256 B
  // -------------------------------------------------------
  int* rowptr  = (int*)(ws + 26033280);                    // 200,004 B
  int* cursor  = (int*)(ws + 26233284);                    // 200,000 B
  int* esrc    = (int*)(ws + 26433284);                    // 2,560,000 B
  int* bsum    = (int*)(ws + 28993284);                    // 256 B
  int* gstart  = (int*)(ws + 28993540);                    // 260 B

  hipMemsetAsync(deg, 0, 233280, stream);  // deg + S + denom + gmaxu

  hist_gbound_kernel<<<EGRID + NGRID_GB, 256, 0, stream>>>(ei, deg, batch, gstart);
  scan1_kernel<<<SCAN_NB, 1024, 0, stream>>>(deg, rowptr, bsum);
  scan23_kernel<<<SCAN_NB, 1024, 0, stream>>>(deg, bsum, rowptr, cursor);
  scatter_kernel<<<EGRID, 256, 0, stream>>>(ei, cursor, esrc);

  const int ngrid64 = (N_NODESC + 63) / 64;
  enc_kernel<<<ngrid64, 128, 0, stream>>>(x, aW1, ab1, ag, abe, aW2, ab2,
                                          oW1, ob1, og, obe, oW2, ob2,
                                          ninW, ninb, Ha);
  unsigned short* cur = Ha;
  unsigned short* nxt = Hc;
  for (int l = 0; l < 3; ++l) {
    conv_fused_kernel<<<ngrid64, 256, 0, stream>>>(
        cur, rowptr, esrc, eps + l,
        cW1 + l*HIDC*HIDC, cb1 + l*HIDC, cg + l*HIDC, cbe + l*HIDC,
        cW2 + l*HIDC*HIDC, cb2 + l*HIDC, lng + l*HIDC, lnb + l*HIDC,
        nxt);
    unsigned short* tmp = cur; cur = nxt; nxt = tmp;
  }
  // after 3 layers, cur == Hc holds the final H
  gate_mfma_kernel<<<ngrid64, 256, 0, stream>>>(cur, gW1, gb1, gg, gbe, gW2, gb2,
                                                batch, gateb, gmaxu);
  pool_kernel<<<N_GRAPHSC * POOL_SPLIT, 256, 0, stream>>>(cur, gateb, gstart, gmaxu, S, denom);
  head_kernel<<<N_GRAPHSC, 64, 0, stream>>>(S, denom, hW1, hb1, hg, hbe, hW2, hb2,
                                            (float*)d_out);
}

// Round 8
// 396.784 us; speedup vs baseline: 3.2420x; 1.0580x over previous
//
#include <hip/hip_runtime.h>

#define N_NODESC 50000
#define N_EDGESC 640000
#define N_GRAPHSC 64
#define HIDC 128
#define LN_EPSF 1e-5f
#define POOL_SPLIT 16
#define SCAN_NB 49   // 49*1024 = 50176 >= 50000
#define EGRID ((N_EDGESC + 255) / 256)
#define NGRID_GB ((N_NODESC + 255) / 256)

typedef short bf16x8 __attribute__((ext_vector_type(8)));
typedef float f32x4 __attribute__((ext_vector_type(4)));

// ---------- helpers ----------
static __device__ __forceinline__ unsigned ord_enc(float f) {
  unsigned u = __float_as_uint(f);
  return (u & 0x80000000u) ? ~u : (u | 0x80000000u);
}
static __device__ __forceinline__ float ord_dec(unsigned u) {
  return __uint_as_float((u & 0x80000000u) ? (u ^ 0x80000000u) : ~u);
}
static __device__ __forceinline__ unsigned short f2bf(float x) {
  unsigned u = __float_as_uint(x);
  u += 0x7fffu + ((u >> 16) & 1u);
  return (unsigned short)(u >> 16);
}
static __device__ __forceinline__ float bf2f(unsigned short b) {
  return __uint_as_float(((unsigned)b) << 16);
}

static __device__ __forceinline__ void mlp16(float in0, float in1, float in2,
    const float* __restrict__ W1, const float* __restrict__ b1,
    const float* __restrict__ g, const float* __restrict__ be,
    const float* __restrict__ W2, const float* __restrict__ b2,
    float* __restrict__ out) {
  float h[16];
  float s1 = 0.f, s2 = 0.f;
#pragma unroll
  for (int j = 0; j < 16; ++j) {
    float v = b1[j] + W1[j*3+0]*in0 + W1[j*3+1]*in1 + W1[j*3+2]*in2;
    v = fmaxf(v, 0.f);
    h[j] = v; s1 += v; s2 += v*v;
  }
  float mu = s1 * (1.f/16.f);
  float var = fmaxf(s2 * (1.f/16.f) - mu*mu, 0.f);
  float rs = rsqrtf(var + LN_EPSF);
  float z[16];
#pragma unroll
  for (int j = 0; j < 16; ++j) z[j] = (h[j]-mu)*rs*g[j] + be[j];
#pragma unroll
  for (int j = 0; j < 16; ++j) {
    float v = b2[j];
#pragma unroll
    for (int k = 0; k < 16; ++k) v += W2[j*16+k]*z[k];
    out[j] = v;
  }
}

// ---------- hist (edges) + gbound (nodes) in one dispatch ----------
__global__ __launch_bounds__(256) void hist_gbound_kernel(const int* __restrict__ ei,
    int* __restrict__ deg, const int* __restrict__ batch, int* __restrict__ gstart) {
  const int b = blockIdx.x;
  if (b < EGRID) {
    int e = b * 256 + threadIdx.x;
    if (e < N_EDGESC) atomicAdd(&deg[ei[N_EDGESC + e]], 1);
  } else {
    int i = (b - EGRID) * 256 + threadIdx.x;
    if (i >= N_NODESC) return;
    int bb = batch[i];
    int prev = (i == 0) ? -1 : batch[i-1];
    for (int g = prev + 1; g <= bb; ++g) gstart[g] = i;
    if (i == N_NODESC - 1) {
      for (int g = bb + 1; g <= N_GRAPHSC; ++g) gstart[g] = N_NODESC;
    }
  }
}

// ---------- scan phase 1 ----------
__global__ __launch_bounds__(1024) void scan1_kernel(const int* __restrict__ deg,
                                                     int* __restrict__ incl,
                                                     int* __restrict__ bsum) {
  const int b = blockIdx.x, t = threadIdx.x;
  const int i = b * 1024 + t;
  const int lane = t & 63, w = t >> 6;
  int v = (i < N_NODESC) ? deg[i] : 0;
#pragma unroll
  for (int off = 1; off < 64; off <<= 1) {
    int n = __shfl_up(v, off);
    if (lane >= off) v += n;
  }
  __shared__ int wsum[16];
  if (lane == 63) wsum[w] = v;
  __syncthreads();
  if (t == 0) {
    int run = 0;
#pragma unroll
    for (int k = 0; k < 16; ++k) { int x = wsum[k]; wsum[k] = run; run += x; }
  }
  __syncthreads();
  v += wsum[w];
  if (i < N_NODESC) incl[i] = v;
  if (t == 1023) bsum[b] = v;
}

// ---------- scan phases 2+3 fused ----------
__global__ __launch_bounds__(1024) void scan23_kernel(const int* __restrict__ deg,
                                                      const int* __restrict__ bsum,
                                                      int* __restrict__ rowptr,
                                                      int* __restrict__ cursor) {
  __shared__ int ex[SCAN_NB + 1];
  const int b = blockIdx.x, t = threadIdx.x;
  if (t < 64) {
    int v = (t < SCAN_NB) ? bsum[t] : 0;
    const int orig = v;
#pragma unroll
    for (int off = 1; off < 64; off <<= 1) {
      int n = __shfl_up(v, off);
      if (t >= off) v += n;
    }
    if (t < SCAN_NB) ex[t] = v - orig;
    if (t == SCAN_NB - 1) ex[SCAN_NB] = v;
  }
  __syncthreads();
  const int i = b * 1024 + t;
  if (i < N_NODESC) {
    int excl = rowptr[i] - deg[i] + ex[b];
    rowptr[i] = excl;
    cursor[i] = excl;
  }
  if (b == 0 && t == 0) rowptr[N_NODESC] = ex[SCAN_NB];
}

__global__ __launch_bounds__(256) void scatter_kernel(const int* __restrict__ ei,
                                                      int* __restrict__ cursor,
                                                      int* __restrict__ esrc) {
  int e = blockIdx.x * 256 + threadIdx.x;
  if (e < N_EDGESC) {
    int d = ei[N_EDGESC + e];
    int slot = atomicAdd(&cursor[d], 1);
    esrc[slot] = ei[e];
  }
}

// ---------- encoder ----------
__global__ __launch_bounds__(128) void enc_kernel(
    const float* __restrict__ x,
    const float* __restrict__ aW1, const float* __restrict__ ab1,
    const float* __restrict__ ag,  const float* __restrict__ abe,
    const float* __restrict__ aW2, const float* __restrict__ ab2,
    const float* __restrict__ oW1, const float* __restrict__ ob1,
    const float* __restrict__ og,  const float* __restrict__ obe,
    const float* __restrict__ oW2, const float* __restrict__ ob2,
    const float* __restrict__ ninW, const float* __restrict__ ninb,
    unsigned short* __restrict__ Hb) {
  __shared__ float sa[48*68];
  __shared__ float sw[48*132];
  const int t = threadIdx.x;
  const int lane = t & 63, w = t >> 6;
  const int nb = blockIdx.x * 64;

  if (t < 64) {
    float in45[45];
    const int gn = nb + t;
    if (gn < N_NODESC) {
      const float* xr = x + gn * 19;
#pragma unroll
      for (int k = 0; k < 9; ++k) in45[k] = xr[k];
#pragma unroll
      for (int k = 0; k < 4; ++k) in45[9+k] = xr[15+k];
      mlp16(xr[9], xr[10], xr[11], aW1, ab1, ag, abe, aW2, ab2, &in45[13]);
      mlp16(xr[12], xr[13], xr[14], oW1, ob1, og, obe, oW2, ob2, &in45[29]);
    } else {
#pragma unroll
      for (int k = 0; k < 45; ++k) in45[k] = 0.f;
    }
#pragma unroll
    for (int k = 0; k < 45; ++k) sa[k*68 + t] = in45[k];
#pragma unroll
    for (int k = 45; k < 48; ++k) sa[k*68 + t] = 0.f;
  }
  for (int idx = t; idx < 48*128; idx += 128) {
    int k = idx >> 7, f = idx & 127;
    sw[k*132 + f] = (k < 45) ? ninW[f*45 + k] : 0.f;
  }
  __syncthreads();

  const int n0 = (lane & 7) * 8;
  const int f0 = ((lane >> 3) << 3) + w * 64;
  float acc[8][8];
#pragma unroll
  for (int i = 0; i < 8; ++i)
#pragma unroll
    for (int j = 0; j < 8; ++j) acc[i][j] = 0.f;

#pragma unroll 4
  for (int k = 0; k < 48; ++k) {
    float av[8], wv[8];
    float4 a0 = *(const float4*)&sa[k*68 + n0];
    float4 a1 = *(const float4*)&sa[k*68 + n0 + 4];
    float4 w0 = *(const float4*)&sw[k*132 + f0];
    float4 w1 = *(const float4*)&sw[k*132 + f0 + 4];
    av[0]=a0.x; av[1]=a0.y; av[2]=a0.z; av[3]=a0.w;
    av[4]=a1.x; av[5]=a1.y; av[6]=a1.z; av[7]=a1.w;
    wv[0]=w0.x; wv[1]=w0.y; wv[2]=w0.z; wv[3]=w0.w;
    wv[4]=w1.x; wv[5]=w1.y; wv[6]=w1.z; wv[7]=w1.w;
#pragma unroll
    for (int i = 0; i < 8; ++i)
#pragma unroll
      for (int j = 0; j < 8; ++j) acc[i][j] += av[i]*wv[j];
  }
  float bb[8];
#pragma unroll
  for (int j = 0; j < 8; ++j) bb[j] = ninb[f0+j];
#pragma unroll
  for (int i = 0; i < 8; ++i) {
    int gn = nb + n0 + i;
    if (gn < N_NODESC) {
      bf16x8 o8;
#pragma unroll
      for (int j = 0; j < 8; ++j) o8[j] = (short)f2bf(acc[i][j] + bb[j]);
      *(bf16x8*)&Hb[gn*HIDC + f0] = o8;
    }
  }
}

// ---------- fused conv layer: gather + GEMM1 + LN + GEMM2 + LN + resid ----------
// 3 blocks/CU; gather keeps all 64 nodes concurrent (4 lanes/node, 4x16B/edge).
__global__ __launch_bounds__(256, 3) void conv_fused_kernel(
    const unsigned short* __restrict__ Hin,
    const int* __restrict__ rowptr, const int* __restrict__ esrc,
    const float* __restrict__ epsp,
    const float* __restrict__ W1, const float* __restrict__ b1,
    const float* __restrict__ g1, const float* __restrict__ be1,
    const float* __restrict__ W2, const float* __restrict__ b2,
    const float* __restrict__ lng, const float* __restrict__ lnb,
    unsigned short* __restrict__ Hout) {
  __shared__ unsigned short Ab[64*136];   // M tile, then T tile, then OUT tile
  __shared__ unsigned short Wl[128*136];  // W1 then W2
  const int t = threadIdx.x;
  const int nb = blockIdx.x * 64;

  // stage W1 (fp32 -> bf16)
#pragma unroll
  for (int i = 0; i < 16; ++i) {
    int q = t + i*256;
    int f = q >> 5, c4 = q & 31;
    float4 v = *(const float4*)&W1[f*HIDC + c4*4];
    ushort4 h;
    h.x = f2bf(v.x); h.y = f2bf(v.y); h.z = f2bf(v.z); h.w = f2bf(v.w);
    *(ushort4*)&Wl[f*136 + c4*4] = h;
  }

  // gather: M = (1+eps)*Hin[node] + sum Hin[src]; 4 lanes/node, all 64 nodes live
  {
    const float e1 = 1.0f + epsp[0];
    const int v64 = t >> 2;         // node 0..63
    const int c   = t & 3;          // chunk group: chunks c*4 .. c*4+3
    const int node = nb + v64;
    if (node < N_NODESC) {
      const unsigned short* __restrict__ hrow = &Hin[node*HIDC + c*32];
      float acc[4][8];
#pragma unroll
      for (int j = 0; j < 4; ++j)
#pragma unroll
        for (int k = 0; k < 8; ++k) acc[j][k] = 0.f;
      int s = rowptr[node];
      const int e = rowptr[node+1];
      for (; s + 2 <= e; s += 2) {
        int i0 = esrc[s], i1 = esrc[s+1];
        const unsigned short* r0 = &Hin[i0*HIDC + c*32];
        const unsigned short* r1 = &Hin[i1*HIDC + c*32];
        bf16x8 x00 = *(const bf16x8*)&r0[0],  x01 = *(const bf16x8*)&r0[8];
        bf16x8 x02 = *(const bf16x8*)&r0[16], x03 = *(const bf16x8*)&r0[24];
        bf16x8 x10 = *(const bf16x8*)&r1[0],  x11 = *(const bf16x8*)&r1[8];
        bf16x8 x12 = *(const bf16x8*)&r1[16], x13 = *(const bf16x8*)&r1[24];
#pragma unroll
        for (int k = 0; k < 8; ++k) {
          acc[0][k] += bf2f((unsigned short)x00[k]) + bf2f((unsigned short)x10[k]);
          acc[1][k] += bf2f((unsigned short)x01[k]) + bf2f((unsigned short)x11[k]);
          acc[2][k] += bf2f((unsigned short)x02[k]) + bf2f((unsigned short)x12[k]);
          acc[3][k] += bf2f((unsigned short)x03[k]) + bf2f((unsigned short)x13[k]);
        }
      }
      if (s < e) {
        const unsigned short* r0 = &Hin[esrc[s]*HIDC + c*32];
        bf16x8 x00 = *(const bf16x8*)&r0[0],  x01 = *(const bf16x8*)&r0[8];
        bf16x8 x02 = *(const bf16x8*)&r0[16], x03 = *(const bf16x8*)&r0[24];
#pragma unroll
        for (int k = 0; k < 8; ++k) {
          acc[0][k] += bf2f((unsigned short)x00[k]);
          acc[1][k] += bf2f((unsigned short)x01[k]);
          acc[2][k] += bf2f((unsigned short)x02[k]);
          acc[3][k] += bf2f((unsigned short)x03[k]);
        }
      }
#pragma unroll
      for (int j = 0; j < 4; ++j) {
        bf16x8 h = *(const bf16x8*)&hrow[j*8];
        bf16x8 m8;
#pragma unroll
        for (int k = 0; k < 8; ++k)
          m8[k] = (short)f2bf(e1*bf2f((unsigned short)h[k]) + acc[j][k]);
        *(bf16x8*)&Ab[v64*136 + c*32 + j*8] = m8;
      }
    } else {
#pragma unroll
      for (int j = 0; j < 4; ++j)
        *(bf16x8*)&Ab[v64*136 + c*32 + j*8] = (bf16x8){0,0,0,0,0,0,0,0};
    }
  }
  __syncthreads();

  const int lane = t & 63, wv = t >> 6;
  const int quad = lane >> 4, l16 = lane & 15;
  const int arow = (wv*16 + l16)*136 + quad*8;

  // MFMA loop 1: M @ W1^T
  f32x4 acc[8];
#pragma unroll
  for (int ft = 0; ft < 8; ++ft) acc[ft] = (f32x4){0.f,0.f,0.f,0.f};
#pragma unroll
  for (int ks = 0; ks < 4; ++ks) {
    bf16x8 a = *(const bf16x8*)(const void*)&Ab[arow + ks*32];
#pragma unroll
    for (int ft = 0; ft < 8; ++ft) {
      bf16x8 b = *(const bf16x8*)(const void*)&Wl[(ft*16 + l16)*136 + quad*8 + ks*32];
      acc[ft] = __builtin_amdgcn_mfma_f32_16x16x32_bf16(a, b, acc[ft], 0, 0, 0);
    }
  }

  // epilogue 1: bias1 + relu + LN(g1, be1) -> T (into Ab)
  {
    float bb[8], gg[8], bee[8];
#pragma unroll
    for (int ft = 0; ft < 8; ++ft) {
      int f = ft*16 + l16;
      bb[ft] = b1[f]; gg[ft] = g1[f]; bee[ft] = be1[f];
    }
    float s1[4] = {0,0,0,0}, s2[4] = {0,0,0,0};
#pragma unroll
    for (int ft = 0; ft < 8; ++ft)
#pragma unroll
      for (int r = 0; r < 4; ++r) {
        float v = fmaxf(acc[ft][r] + bb[ft], 0.f);
        acc[ft][r] = v; s1[r] += v; s2[r] += v*v;
      }
#pragma unroll
    for (int m = 1; m < 16; m <<= 1)
#pragma unroll
      for (int r = 0; r < 4; ++r) {
        s1[r] += __shfl_xor(s1[r], m);
        s2[r] += __shfl_xor(s2[r], m);
      }
    float mu[4], rs[4];
#pragma unroll
    for (int r = 0; r < 4; ++r) {
      mu[r] = s1[r] * (1.f/128.f);
      float var = fmaxf(s2[r] * (1.f/128.f) - mu[r]*mu[r], 0.f);
      rs[r] = rsqrtf(var + LN_EPSF);
    }
    __syncthreads();
#pragma unroll
    for (int r = 0; r < 4; ++r) {
      int nloc = wv*16 + quad*4 + r;
#pragma unroll
      for (int ft = 0; ft < 8; ++ft) {
        float o = (acc[ft][r] - mu[r])*rs[r]*gg[ft] + bee[ft];
        Ab[nloc*136 + ft*16 + l16] = f2bf(o);
      }
    }
  }
  // restage Wl = W2
#pragma unroll
  for (int i = 0; i < 16; ++i) {
    int q = t + i*256;
    int f = q >> 5, c4 = q & 31;
    float4 v = *(const float4*)&W2[f*HIDC + c4*4];
    ushort4 h;
    h.x = f2bf(v.x); h.y = f2bf(v.y); h.z = f2bf(v.z); h.w = f2bf(v.w);
    *(ushort4*)&Wl[f*136 + c4*4] = h;
  }
  __syncthreads();

  // MFMA loop 2: T @ W2^T
#pragma unroll
  for (int ft = 0; ft < 8; ++ft) acc[ft] = (f32x4){0.f,0.f,0.f,0.f};
#pragma unroll
  for (int ks = 0; ks < 4; ++ks) {
    bf16x8 a = *(const bf16x8*)(const void*)&Ab[arow + ks*32];
#pragma unroll
    for (int ft = 0; ft < 8; ++ft) {
      bf16x8 b = *(const bf16x8*)(const void*)&Wl[(ft*16 + l16)*136 + quad*8 + ks*32];
      acc[ft] = __builtin_amdgcn_mfma_f32_16x16x32_bf16(a, b, acc[ft], 0, 0, 0);
    }
  }

  // epilogue 2: bias2 + relu + LN(lng, lnb) -> Ab
  {
    float bb[8], gg[8], bee[8];
#pragma unroll
    for (int ft = 0; ft < 8; ++ft) {
      int f = ft*16 + l16;
      bb[ft] = b2[f]; gg[ft] = lng[f]; bee[ft] = lnb[f];
    }
    float s1[4] = {0,0,0,0}, s2[4] = {0,0,0,0};
#pragma unroll
    for (int ft = 0; ft < 8; ++ft)
#pragma unroll
      for (int r = 0; r < 4; ++r) {
        float v = fmaxf(acc[ft][r] + bb[ft], 0.f);
        acc[ft][r] = v; s1[r] += v; s2[r] += v*v;
      }
#pragma unroll
    for (int m = 1; m < 16; m <<= 1)
#pragma unroll
      for (int r = 0; r < 4; ++r) {
        s1[r] += __shfl_xor(s1[r], m);
        s2[r] += __shfl_xor(s2[r], m);
      }
    float mu[4], rs[4];
#pragma unroll
    for (int r = 0; r < 4; ++r) {
      mu[r] = s1[r] * (1.f/128.f);
      float var = fmaxf(s2[r] * (1.f/128.f) - mu[r]*mu[r], 0.f);
      rs[r] = rsqrtf(var + LN_EPSF);
    }
    __syncthreads();
#pragma unroll
    for (int r = 0; r < 4; ++r) {
      int nloc = wv*16 + quad*4 + r;
#pragma unroll
      for (int ft = 0; ft < 8; ++ft) {
        float o = (acc[ft][r] - mu[r])*rs[r]*gg[ft] + bee[ft];
        Ab[nloc*136 + ft*16 + l16] = f2bf(o);
      }
    }
  }
  __syncthreads();
  // final store: + residual (Hin row), coalesced 16B chunks
#pragma unroll
  for (int i = 0; i < 4; ++i) {
    int chunk = t + i*256;
    int n = chunk >> 4, cc = chunk & 15;
    int gn = nb + n;
    if (gn >= N_NODESC) continue;
    bf16x8 vv = *(const bf16x8*)&Ab[n*136 + cc*8];
    bf16x8 rr = *(const bf16x8*)&Hin[gn*HIDC + cc*8];
    bf16x8 o8;
#pragma unroll
    for (int k = 0; k < 8; ++k)
      o8[k] = (short)f2bf(bf2f((unsigned short)vv[k]) + bf2f((unsigned short)rr[k]));
    *(bf16x8*)&Hout[gn*HIDC + cc*8] = o8;
  }
}

// ---------- MFMA gate (bf16 in) + inline per-graph max ----------
__global__ __launch_bounds__(256, 4) void gate_mfma_kernel(
    const unsigned short* __restrict__ Hb, const float* __restrict__ W1,
    const float* __restrict__ b1, const float* __restrict__ lng,
    const float* __restrict__ lnb, const float* __restrict__ W2,
    const float* __restrict__ b2, const int* __restrict__ batch,
    float* __restrict__ gateb, unsigned* __restrict__ gmaxu) {
  __shared__ unsigned short Ab[64*136];
  __shared__ unsigned short Wl[64*136];
  __shared__ unsigned sgm[N_GRAPHSC];
  const int t = threadIdx.x;
  const int nb = blockIdx.x * 64;
  if (t < N_GRAPHSC) sgm[t] = 0u;
#pragma unroll
  for (int i = 0; i < 4; ++i) {
    int chunk = t + i*256;
    int n = chunk >> 4, c8 = chunk & 15;
    int gn = nb + n;
    bf16x8 v = {0,0,0,0,0,0,0,0};
    if (gn < N_NODESC) v = *(const bf16x8*)&Hb[gn*HIDC + c8*8];
    *(bf16x8*)&Ab[n*136 + c8*8] = v;
  }
#pragma unroll
  for (int i = 0; i < 8; ++i) {
    int q = t + i*256;
    int f = q >> 5, c4 = q & 31;
    float4 v = *(const float4*)&W1[f*HIDC + c4*4];
    ushort4 h;
    h.x = f2bf(v.x); h.y = f2bf(v.y); h.z = f2bf(v.z); h.w = f2bf(v.w);
    *(ushort4*)&Wl[f*136 + c4*4] = h;
  }
  __syncthreads();

  const int lane = t & 63, wv = t >> 6;
  const int quad = lane >> 4, l16 = lane & 15;
  f32x4 acc[4];
#pragma unroll
  for (int ft = 0; ft < 4; ++ft) acc[ft] = (f32x4){0.f,0.f,0.f,0.f};

  const int arow = (wv*16 + l16)*136 + quad*8;
#pragma unroll
  for (int ks = 0; ks < 4; ++ks) {
    bf16x8 a = *(const bf16x8*)(const void*)&Ab[arow + ks*32];
#pragma unroll
    for (int ft = 0; ft < 4; ++ft) {
      bf16x8 b = *(const bf16x8*)(const void*)&Wl[(ft*16 + l16)*136 + quad*8 + ks*32];
      acc[ft] = __builtin_amdgcn_mfma_f32_16x16x32_bf16(a, b, acc[ft], 0, 0, 0);
    }
  }

  float bb[4], gg[4], bee[4], w2v[4];
#pragma unroll
  for (int ft = 0; ft < 4; ++ft) {
    int f = ft*16 + l16;
    bb[ft] = b1[f]; gg[ft] = lng[f]; bee[ft] = lnb[f]; w2v[ft] = W2[f];
  }
  float s1[4] = {0,0,0,0}, s2[4] = {0,0,0,0};
#pragma unroll
  for (int ft = 0; ft < 4; ++ft)
#pragma unroll
    for (int r = 0; r < 4; ++r) {
      float v = fmaxf(acc[ft][r] + bb[ft], 0.f);
      acc[ft][r] = v; s1[r] += v; s2[r] += v*v;
    }
#pragma unroll
  for (int m = 1; m < 16; m <<= 1)
#pragma unroll
    for (int r = 0; r < 4; ++r) {
      s1[r] += __shfl_xor(s1[r], m);
      s2[r] += __shfl_xor(s2[r], m);
    }
  float pd[4];
#pragma unroll
  for (int r = 0; r < 4; ++r) {
    float mu = s1[r] * (1.f/64.f);
    float var = fmaxf(s2[r] * (1.f/64.f) - mu*mu, 0.f);
    float rs = rsqrtf(var + LN_EPSF);
    float p = 0.f;
#pragma unroll
    for (int ft = 0; ft < 4; ++ft)
      p += ((acc[ft][r] - mu)*rs*gg[ft] + bee[ft]) * w2v[ft];
    pd[r] = p;
  }
#pragma unroll
  for (int m = 1; m < 16; m <<= 1)
#pragma unroll
    for (int r = 0; r < 4; ++r) pd[r] += __shfl_xor(pd[r], m);
  if (l16 == 0) {
    float b2v = b2[0];
#pragma unroll
    for (int r = 0; r < 4; ++r) {
      int node = nb + wv*16 + quad*4 + r;
      if (node < N_NODESC) {
        float gv = pd[r] + b2v;
        gateb[node] = gv;
        atomicMax(&sgm[batch[node]], ord_enc(gv));
      }
    }
  }
  __syncthreads();
  if (t < N_GRAPHSC && sgm[t] != 0u) atomicMax(&gmaxu[t], sgm[t]);
}

// ---------- segmented softmax-weighted pooling (bf16 H) ----------
__global__ __launch_bounds__(256) void pool_kernel(const unsigned short* __restrict__ Hb,
    const float* __restrict__ gateb, const int* __restrict__ gstart,
    const unsigned* __restrict__ gmaxu, float* __restrict__ S,
    float* __restrict__ denom) {
  const int g    = blockIdx.x / POOL_SPLIT;
  const int part = blockIdx.x % POOL_SPLIT;
  const int s0 = gstart[g], s1 = gstart[g+1];
  const int cnt = s1 - s0;
  const int chunk = (cnt + POOL_SPLIT - 1) / POOL_SPLIT;
  int lo = s0 + part * chunk;
  int hi = lo + chunk; if (hi > s1) hi = s1;
  const int t = threadIdx.x;
  const int c8 = t & 15;
  const int v  = t >> 4;
  const float gm = ord_dec(gmaxu[g]);
  float acc[8];
#pragma unroll
  for (int k = 0; k < 8; ++k) acc[k] = 0.f;
  float de = 0.f;
  for (int n = lo + v; n < hi; n += 16) {
    float e = expf(gateb[n] - gm);
    bf16x8 hv = *(const bf16x8*)&Hb[n*HIDC + c8*8];
#pragma unroll
    for (int k = 0; k < 8; ++k) acc[k] += e * bf2f((unsigned short)hv[k]);
    if (c8 == 0) de += e;
  }
  __shared__ float sacc[16*128];
  __shared__ float sden[16];
#pragma unroll
  for (int k = 0; k < 8; ++k) sacc[v*128 + c8*8 + k] = acc[k];
  if (c8 == 0) sden[v] = de;
  __syncthreads();
  if (t < 128) {
    float s = 0.f;
#pragma unroll
    for (int vv = 0; vv < 16; ++vv) s += sacc[vv*128 + t];
    atomicAdd(&S[g*HIDC + t], s);
  }
  if (t == 0) {
    float d = 0.f;
#pragma unroll
    for (int vv = 0; vv < 16; ++vv) d += sden[vv];
    atomicAdd(&denom[g], d);
  }
}

// ---------- head MLP per graph ----------
__global__ __launch_bounds__(64) void head_kernel(const float* __restrict__ S,
    const float* __restrict__ denom, const float* __restrict__ W1,
    const float* __restrict__ b1, const float* __restrict__ g,
    const float* __restrict__ be, const float* __restrict__ W2,
    const float* __restrict__ b2, float* __restrict__ out) {
  const int gr = blockIdx.x;
  const int j = threadIdx.x;
  const float inv = 1.0f / denom[gr];
  float v = b1[j];
  for (int k = 0; k < HIDC; ++k) v += (S[gr*HIDC + k] * inv) * W1[j*HIDC + k];
  v = fmaxf(v, 0.f);
  float s1 = v, s2 = v*v;
  for (int off = 32; off; off >>= 1) { s1 += __shfl_xor(s1, off); s2 += __shfl_xor(s2, off); }
  float mu = s1 * (1.f/64.f);
  float var = fmaxf(s2 * (1.f/64.f) - mu*mu, 0.f);
  float rs = rsqrtf(var + LN_EPSF);
  float z = (v-mu)*rs*g[j] + be[j];
  float p = z * W2[j];
  for (int off = 32; off; off >>= 1) p += __shfl_xor(p, off);
  if (j == 0) out[gr] = p + b2[0];
}

// ---------- launch ----------
extern "C" void kernel_launch(void* const* d_in, const int* in_sizes, int n_in,
                              void* d_out, int out_size, void* d_ws, size_t ws_size,
                              hipStream_t stream) {
  (void)in_sizes; (void)n_in; (void)out_size; (void)ws_size;
  const float* x     = (const float*)d_in[0];
  const int*   ei    = (const int*)d_in[1];
  const int*   batch = (const int*)d_in[2];
  const float* aW1 = (const float*)d_in[3];
  const float* ab1 = (const float*)d_in[4];
  const float* ag  = (const float*)d_in[5];
  const float* abe = (const float*)d_in[6];
  const float* aW2 = (const float*)d_in[7];
  const float* ab2 = (const float*)d_in[8];
  const float* oW1 = (const float*)d_in[9];
  const float* ob1 = (const float*)d_in[10];
  const float* og  = (const float*)d_in[11];
  const float* obe = (const float*)d_in[12];
  const float* oW2 = (const float*)d_in[13];
  const float* ob2 = (const float*)d_in[14];
  const float* ninW = (const float*)d_in[15];
  const float* ninb = (const float*)d_in[16];
  const float* cW1 = (const float*)d_in[17];
  const float* cb1 = (const float*)d_in[18];
  const float* cg  = (const float*)d_in[19];
  const float* cbe = (const float*)d_in[20];
  const float* cW2 = (const float*)d_in[21];
  const float* cb2 = (const float*)d_in[22];
  const float* eps = (const float*)d_in[23];
  const float* lng = (const float*)d_in[24];
  const float* lnb = (const float*)d_in[25];
  const float* gW1 = (const float*)d_in[26];
  const float* gb1 = (const float*)d_in[27];
  const float* gg  = (const float*)d_in[28];
  const float* gbe = (const float*)d_in[29];
  const float* gW2 = (const float*)d_in[30];
  const float* gb2 = (const float*)d_in[31];
  const float* hW1 = (const float*)d_in[32];
  const float* hb1 = (const float*)d_in[33];
  const float* hg  = (const float*)d_in[34];
  const float* hbe = (const float*)d_in[35];
  const float* hW2 = (const float*)d_in[36];
  const float* hb2 = (const float*)d_in[37];

  char* ws = (char*)d_ws;
  unsigned short* Ha = (unsigned short*)(ws + 0);          // 12,800,000 B
  unsigned short* Hc = (unsigned short*)(ws + 12800000);   // 12,800,000 B
  float* gateb = (float*)(ws + 25600000);                  // 200,000 B
  // --- contiguous zero region: deg | S | denom | gmaxu ---
  int*   deg   = (int*)(ws + 25800000);                    // 200,000 B
  float* S     = (float*)(ws + 26000000);                  // 32,768 B
  float* denom = (float*)(ws + 26032768);                  // 256 B
  unsigned* gmaxu = (unsigned*)(ws + 26033024);            // 256 B
  // -------------------------------------------------------
  int* rowptr  = (int*)(ws + 26033280);                    // 200,004 B
  int* cursor  = (int*)(ws + 26233284);                    // 200,000 B
  int* esrc    = (int*)(ws + 26433284);                    // 2,560,000 B
  int* bsum    = (int*)(ws + 28993284);                    // 256 B
  int* gstart  = (int*)(ws + 28993540);                    // 260 B

  hipMemsetAsync(deg, 0, 233280, stream);  // deg + S + denom + gmaxu

  hist_gbound_kernel<<<EGRID + NGRID_GB, 256, 0, stream>>>(ei, deg, batch, gstart);
  scan1_kernel<<<SCAN_NB, 1024, 0, stream>>>(deg, rowptr, bsum);
  scan23_kernel<<<SCAN_NB, 1024, 0, stream>>>(deg, bsum, rowptr, cursor);
  scatter_kernel<<<EGRID, 256, 0, stream>>>(ei, cursor, esrc);

  const int ngrid64 = (N_NODESC + 63) / 64;
  enc_kernel<<<ngrid64, 128, 0, stream>>>(x, aW1, ab1, ag, abe, aW2, ab2,
                                          oW1, ob1, og, obe, oW2, ob2,
                                          ninW, ninb, Ha);
  unsigned short* cur = Ha;
  unsigned short* nxt = Hc;
  for (int l = 0; l < 3; ++l) {
    conv_fused_kernel<<<ngrid64, 256, 0, stream>>>(
        cur, rowptr, esrc, eps + l,
        cW1 + l*HIDC*HIDC, cb1 + l*HIDC, cg + l*HIDC, cbe + l*HIDC,
        cW2 + l*HIDC*HIDC, cb2 + l*HIDC, lng + l*HIDC, lnb + l*HIDC,
        nxt);
    unsigned short* tmp = cur; cur = nxt; nxt = tmp;
  }
  // after 3 layers, cur == Hc holds the final H
  gate_mfma_kernel<<<ngrid64, 256, 0, stream>>>(cur, gW1, gb1, gg, gbe, gW2, gb2,
                                                batch, gateb, gmaxu);
  pool_kernel<<<N_GRAPHSC * POOL_SPLIT, 256, 0, stream>>>(cur, gateb, gstart, gmaxu, S, denom);
  head_kernel<<<N_GRAPHSC, 64, 0, stream>>>(S, denom, hW1, hb1, hg, hbe, hW2, hb2,
                                            (float*)d_out);
}